// Round 11
// baseline (1015.736 us; speedup 1.0000x reference)
//
#include <hip/hip_runtime.h>
#include <hip/hip_bf16.h>
#include <math.h>
#include <stddef.h>

typedef unsigned int u32;
typedef unsigned short u16;
typedef unsigned long long u64;

#define NRAYS 8192      // N_BATCH * N_RAYS
#define NSAMP 262144    // NRAYS * 32

// ---- strict float32 ops (block FMA contraction, numpy-per-op rounding) ----
__device__ __forceinline__ float fa(float a,float b){ return __fadd_rn(a,b); }
__device__ __forceinline__ float fs(float a,float b){ return __fsub_rn(a,b); }
__device__ __forceinline__ float fm(float a,float b){ return __fmul_rn(a,b); }
__device__ __forceinline__ float fdv(float a,float b){ return __fdiv_rn(a,b); }

// ---- fast double exp: |rel err| < ~2^-45, branch-light (march + density path) ----
__device__ __forceinline__ double exp_d(double x){
  const double LOG2E  = 1.4426950408889634074;
  const double LN2_HI = 6.93147180369123816490e-01;
  const double LN2_LO = 1.90821492927058770002e-10;
  double kd = rint(x * LOG2E);
  if (kd >  200.0) return INFINITY;
  if (kd < -200.0) return 0.0;
  int k = (int)kd;
  double r = fma(-kd, LN2_HI, x);
  r = fma(-kd, LN2_LO, r);
  double p = 1.0/39916800.0;
  p = fma(p, r, 1.0/3628800.0);
  p = fma(p, r, 1.0/362880.0);
  p = fma(p, r, 1.0/40320.0);
  p = fma(p, r, 1.0/5040.0);
  p = fma(p, r, 1.0/720.0);
  p = fma(p, r, 1.0/120.0);
  p = fma(p, r, 1.0/24.0);
  p = fma(p, r, 1.0/6.0);
  p = fma(p, r, 0.5);
  p = fma(p, r, 1.0);
  p = fma(p, r, 1.0);
  u64 sb = ((u64)(k + 1023)) << 52;
  return p * __longlong_as_double((long long)sb);
}
__device__ __forceinline__ float exf(float x){ return (float)exp_d((double)x); }
__device__ __forceinline__ float sigm(float x){   // exact-path stepwise f32 sigmoid (density head)
  if (x >= 0.f){ float e = exf(-x); return fdv(1.f, fa(1.f, e)); }
  float e = exf(x); return fdv(e, fa(1.f, e));
}
// fast sigmoid for the rgb head only (abs tolerance 5.6e-2; bf16-quantized anyway)
__device__ __forceinline__ float sigm_fast(float x){
  return 1.f/(1.f + __expf(-x));
}
__device__ __forceinline__ u16 f2b(float f){
  u32 x = __float_as_uint(f);
  return (u16)((x + 0x7fffu + ((x>>16)&1u)) >> 16);   // RNE
}
// monotone float<->u32 key (handles negatives) for atomic min/max
__device__ __forceinline__ u32 fenc(float f){ u32 b=__float_as_uint(f); return (b&0x80000000u)? ~b : (b|0x80000000u); }
__device__ __forceinline__ float fdec(u32 k){ u32 b=(k&0x80000000u)? (k^0x80000000u) : ~k; return __uint_as_float(b); }

// ---------------- init: global min/max of hit depths, scalar slots, W1 transpose ----------------
__global__ void k_init(const float* __restrict__ hmin, const float* __restrict__ hmax,
                       const float* __restrict__ W1, float* __restrict__ scal,
                       float* __restrict__ W1t){
  __shared__ float smn[256], smx[256];
  int t = threadIdx.x;
  float mn = 1e30f, mx = -1e30f;
  for (int i=t;i<NRAYS;i+=256){ mn=fminf(mn,hmin[i]); mx=fmaxf(mx,hmax[i]); }
  smn[t]=mn; smx[t]=mx; __syncthreads();
  for(int s=128;s>0;s>>=1){
    if(t<s){ smn[t]=fminf(smn[t],smn[t+s]); smx[t]=fmaxf(smx[t],smx[t+s]); }
    __syncthreads();
  }
  if(t==0){
    scal[0]=smn[0]; scal[1]=smx[0];
    ((u32*)scal)[2]=0xFFFFFFFFu;  // dmin key (atomicMin on monotone key)
    ((u32*)scal)[3]=0u;           // dmax key (atomicMax)
  }
  for(int i=t;i<2048;i+=256){ int j=i>>5, c=i&31; W1t[i]=W1[c*64+j]; }  // W1t[j*32+c]
}

// ---------------- transpose planes (N,3,C,H,W) f32 -> (N*3,H,W,C) f32 ----------------
__global__ void __launch_bounds__(256) k_tr(const float* __restrict__ pl, float* __restrict__ pt){
  int t = blockIdx.x*256 + threadIdx.x;     // 0 .. 3145727
  int x  = t & 255;
  int c4 = ((t>>8)&7)<<2;
  int y  = (t>>11)&255;
  int np = t>>19;                            // 0..5
  const float* ip = pl + (((size_t)(np*32+c4))<<16) + (y<<8) + x;
  float4 o;
  o.x = ip[0];
  o.y = ip[65536];
  o.z = ip[131072];
  o.w = ip[196608];
  *reinterpret_cast<float4*>(pt + ((((size_t)(np<<8|y))<<8|x)<<5) + c4) = o;
}

// ---------------- point evaluation (sampling + decoder), strict f32 ----------------
// 2 THREADS PER POINT: both replicate the gather (identical addresses -> broadcast,
// r9's low-FETCH per-plane corner order preserved); decoder j-loop split in half
// (thread h does j in [32h,32h+32)), partials combined pairwise via shfl_xor
// (j-split class verified passing in round 8). Grid 2048 blocks -> 8 blocks/CU.
template<int PHASE>
__global__ void __launch_bounds__(256) k_eval(
  const float* __restrict__ pt, const float* __restrict__ ro, const float* __restrict__ rd,
  const float* __restrict__ hmin, const float* __restrict__ hmax,
  const float* __restrict__ jitter, const int* __restrict__ hitmask,
  const float* __restrict__ W1t, const float* __restrict__ b1,
  const float* __restrict__ W2, const float* __restrict__ b2,
  const float* __restrict__ sb, float* __restrict__ scal,
  float* __restrict__ dep, float* __restrict__ dens_out, u16* __restrict__ rgb_out,
  float* __restrict__ out_psdf)
{
  int tid = blockIdx.x*256 + threadIdx.x;   // 0..524287
  int pid = tid >> 1;                        // point 0..262143
  int hf  = tid & 1;                         // j-half
  int ray = pid >> 5;
  int s   = pid & 31;
  int n   = ray >> 12;
  int msk = hitmask[ray];

  float d;
  if (PHASE==0){
    float hmn = msk ? hmin[ray] : scal[0];
    float hmx = msk ? hmax[ray] : scal[1];
    float span = fs(hmx, hmn);
    float jit  = jitter[pid];
    float base = (float)((double)s * (1.0/31.0));   // np.linspace f64 arange*step -> f32 cast
    if (s==31) base = 1.0f;
    float t1 = fdv(fm(jit, span), 32.0f);
    d = fa(fm(fa(base, t1), span), hmn);
    if (hf==0) dep[pid] = d;
    float dm=d, dM=d;   // duplicates across the pair don't affect min/max
#pragma unroll
    for (int m=1;m<64;m<<=1){ dm=fminf(dm,__shfl_xor(dm,m)); dM=fmaxf(dM,__shfl_xor(dM,m)); }
    if ((threadIdx.x & 63)==0){
      atomicMin(((u32*)scal)+2, fenc(dm));
      atomicMax(((u32*)scal)+3, fenc(dM));
    }
  } else {
    d = dep[pid];
  }

  float ox=ro[ray*3+0], oy=ro[ray*3+1], oz=ro[ray*3+2];
  float dx=rd[ray*3+0], dy=rd[ray*3+1], dz=rd[ray*3+2];
  float px = fa(ox, fm(d,dx)), py = fa(oy, fm(d,dy)), pz = fa(oz, fm(d,dz));
  float nrm = __fsqrt_rn(fa(fa(fm(px,px),fm(py,py)),fm(pz,pz)));
  float tsdf = fs(nrm, 0.5f);
  const float sc2 = (float)(2.0/6.0);
  float cx=fm(px,sc2), cy=fm(py,sc2), cz=fm(pz,sc2);

  float feat[32];
#pragma unroll
  for(int c=0;c<32;c++) feat[c]=0.f;

#pragma unroll
  for (int p=0;p<3;p++){
    float u = (p==2)?cz:cx;                  // plane0:(x,y) plane1:(x,z) plane2:(z,y)
    float v = (p==1)?cz:cy;
    float fx = fs(fm(fa(u,1.f),128.f),0.5f); // (u+1)*128-0.5 per-op
    float fy = fs(fm(fa(v,1.f),128.f),0.5f);
    float x0f = floorf(fx), y0f = floorf(fy);
    float wx = fs(fx,x0f), wy = fs(fy,y0f);
    float ax0 = fs(1.f,wx), ax1 = wx, ay0 = fs(1.f,wy), ay1 = wy;
    int x0, y0;
    { // saturating cast (wild coords can exceed int range semantics; floor first)
      x0 = (x0f >= 2.1e9f) ? 2147483647 : ((x0f <= -2.1e9f) ? (-2147483647-1) : (int)x0f);
      y0 = (y0f >= 2.1e9f) ? 2147483647 : ((y0f <= -2.1e9f) ? (-2147483647-1) : (int)y0f);
    }
    int x1=x0+1, y1=y0+1;
    bool vx0 = (x0>=0 && x0<256), vx1 = (x1>=0 && x1<256);
    bool vy0 = (y0>=0 && y0<256), vy1 = (y1>=0 && y1<256);
    bool ok00 = vx0&&vy0, ok01 = vx1&&vy0, ok10 = vx0&&vy1, ok11 = vx1&&vy1;
    int cx0=min(max(x0,0),255), cx1=min(max(x1,0),255);
    int cy0=min(max(y0,0),255), cy1=min(max(y1,0),255);
    int npl = n*3+p;
    size_t pb = ((size_t)npl)<<16;
    const float4* t00 = (const float4*)(pt + ((pb + (cy0<<8) + cx0)<<5));
    const float4* t01 = (const float4*)(pt + ((pb + (cy0<<8) + cx1)<<5));
    const float4* t10 = (const float4*)(pt + ((pb + (cy1<<8) + cx0)<<5));
    const float4* t11 = (const float4*)(pt + ((pb + (cy1<<8) + cx1)<<5));
#pragma unroll
    for(int q=0;q<8;q++){
      float4 v00 = t00[q], v01 = t01[q], v10 = t10[q], v11 = t11[q];
      float e0,e1,e2,e3, t_;
#define CORNER_SUM(FLD, OUTI) \
      e0 = ok00 ? v00.FLD : 0.f; e1 = ok01 ? v01.FLD : 0.f; \
      e2 = ok10 ? v10.FLD : 0.f; e3 = ok11 ? v11.FLD : 0.f; \
      t_ = fa(fa(fa(fm(fm(e0,ax0),ay0), fm(fm(e1,ax1),ay0)), fm(fm(e2,ax0),ay1)), fm(fm(e3,ax1),ay1)); \
      feat[q*4+OUTI] = fa(feat[q*4+OUTI], t_);
      CORNER_SUM(x,0) CORNER_SUM(y,1) CORNER_SUM(z,2) CORNER_SUM(w,3)
#undef CORNER_SUM
    }
  }
#pragma unroll
  for(int c=0;c<32;c++) feat[c] = fdv(feat[c], 3.0f);   // np.mean: (f0+f1)+f2 then /3

  // decoder half: thread hf handles j in [32*hf, 32*hf+32), sequential within
  float opart[33];
#pragma unroll
  for(int k=0;k<33;k++) opart[k]=0.f;
  {
    const float* w1b = W1t + (hf<<10);     // hf*32 rows * 32
    const float* b1b = b1 + (hf<<5);
    const float* w2b = W2 + (hf<<5)*33;
#pragma unroll 2
    for(int jj=0;jj<32;jj++){
      float a = 0.f;
      const float* wr = w1b + jj*32;
#pragma unroll
      for(int c=0;c<32;c++) a = fmaf(feat[c], wr[c], a);
      a = fa(a, b1b[jj]);
      // native-HW stable softplus: v_exp_f32 + v_log_f32 (r9-verified)
      float h = fa(fmaxf(a,0.f), __logf(fa(1.f, __expf(-fabsf(a)))));
      const float* w2r = w2b + jj*33;
#pragma unroll
      for(int k=0;k<33;k++) opart[k] = fmaf(h, w2r[k], opart[k]);
    }
  }
  // pairwise combine across the 2-thread pair (j-split class verified in r8)
  float o[33];
#pragma unroll
  for(int k=0;k<33;k++){
    float t_ = fa(opart[k], __shfl_xor(opart[k],1));
    o[k] = fa(t_, b2[k]);
  }

  float beta = fmaxf(sb[0], 0.002f);
  float raw = o[0];
  float sg = fa(raw, tsdf);
  if (hf==0){
    out_psdf[((size_t)n<<18) + ((size_t)PHASE<<17) + (size_t)(ray&4095)*32 + s] = raw;  // unmasked
    dens_out[pid] = msk ? fdv(sigm(fdv(-sg, beta)), beta) : 0.f;   // exact path (chaotic cdf chain)
  }

  // rgb head: thread hf writes channels hf*16..hf*16+15 (2x uint4, 64B/point contiguous)
  u16 rv[16];
#pragma unroll
  for(int c=0;c<16;c++){
    float r = msk ? fs(fm(sigm_fast(o[hf*16+c+1]), 1.002f), 0.001f) : 0.f;  // fast path
    rv[c]=f2b(r);
  }
  uint4* op = (uint4*)(rgb_out + (size_t)pid*32 + hf*16);
#pragma unroll
  for(int q=0;q<2;q++){
    uint4 w;
    w.x = (u32)rv[q*8+0] | ((u32)rv[q*8+1]<<16);
    w.y = (u32)rv[q*8+2] | ((u32)rv[q*8+3]<<16);
    w.z = (u32)rv[q*8+4] | ((u32)rv[q*8+5]<<16);
    w.w = (u32)rv[q*8+6] | ((u32)rv[q*8+7]<<16);
    op[q]=w;
  }
}

// ---------------- coarse march + importance sampling (strict f32, thread per ray) ----------------
__global__ void __launch_bounds__(64) k_imp(
  const float* __restrict__ dc, const float* __restrict__ dens,
  const float* __restrict__ u_imp, float* __restrict__ df, float* __restrict__ scal)
{
  __shared__ float scdf[64][30];
  __shared__ float szm [64][30];
  int tid = threadIdx.x;
  int ray = blockIdx.x*64 + tid;   // 0..8191
  float w[31];
  float dprev = dc[ray*32+0];
  float sprev = dens[ray*32+0];
  float T = 1.f;
#pragma unroll
  for(int i=0;i<31;i++){
    float dn = dc[ray*32+i+1];
    float sn = dens[ray*32+i+1];
    if (i<30) szm[tid][i] = fm(0.5f, fa(dprev,dn));
    float delta = fs(dn,dprev);
    float dm = fm(0.5f, fa(sprev,sn));
    float al = fs(1.f, exf(-fm(dm,delta)));
    w[i] = fm(al,T);
    T = fm(T, fa(fs(1.f,al), 1e-10f));
    dprev=dn; sprev=sn;
  }
  // pdf weights: w_sm[j]=0.5*(m[j]+m[j+1])+0.01 (j=1..29), +EPS
  float pdfw[29];
#pragma unroll
  for(int i=0;i<29;i++){
    float m1 = fmaxf(w[i],w[i+1]), m2 = fmaxf(w[i+1],w[i+2]);
    pdfw[i] = fa(fa(fm(0.5f, fa(m1,m2)), 0.01f), 1e-5f);
  }
  // np.sum pairwise (n=29): 8 accumulators, 2 blocked adds, tree, 5 sequential tail
  float sum;
  {
    float r[8];
#pragma unroll
    for(int j=0;j<8;j++) r[j]=pdfw[j];
#pragma unroll
    for(int j=0;j<8;j++) r[j]=fa(r[j],pdfw[8+j]);
#pragma unroll
    for(int j=0;j<8;j++) r[j]=fa(r[j],pdfw[16+j]);
    sum = fa(fa(fa(r[0],r[1]),fa(r[2],r[3])), fa(fa(r[4],r[5]),fa(r[6],r[7])));
#pragma unroll
    for(int i=24;i<29;i++) sum = fa(sum, pdfw[i]);
  }
  // cdf: sequential cumsum of pdf (per-element f32 division)
  {
    float cacc = 0.f;
    scdf[tid][0] = 0.f;
#pragma unroll
    for(int i=1;i<30;i++){
      cacc = fa(cacc, fdv(pdfw[i-1], sum));
      scdf[tid][i] = cacc;
    }
  }

  float fmn=1e30f, fmx=-1e30f;
  for(int k=0;k<32;k++){
    float u = u_imp[ray*32+k];
    // np.searchsorted(cdf, u, 'right') = bisect_right (binary, regardless of monotonicity)
    int lo=0, hi=30;
    while(lo<hi){
      int mid=(lo+hi)>>1;
      if (scdf[tid][mid] <= u) lo = mid+1; else hi = mid;
    }
    int ind = lo;                 // in [1,30]
    int below = ind-1;            // in [0,29]
    int above = (ind>29)?29:ind;  // in [0,29]
    float cdf0 = scdf[tid][below];
    float cdf1 = scdf[tid][above];
    float b0   = szm [tid][below];
    float b1v  = szm [tid][above];
    float den = fs(cdf1,cdf0);
    if((double)den < 1e-5) den = 1.f;      // EPS compare in f64 (python const)
    float sres = fa(b0, fm(fdv(fs(u,cdf0),den), fs(b1v,b0)));
    df[ray*32+k]=sres;
    fmn=fminf(fmn,sres); fmx=fmaxf(fmx,sres);
  }
#pragma unroll
  for(int m=1;m<64;m<<=1){ fmn=fminf(fmn,__shfl_xor(fmn,m)); fmx=fmaxf(fmx,__shfl_xor(fmx,m)); }
  if(tid==0){
    atomicMin(((u32*)scal)+2, fenc(fmn));
    atomicMax(((u32*)scal)+3, fenc(fmx));
  }
}

// ---------------- stable sort (64) + final ray march, strict f32 (wave per ray) ----------------
__global__ void __launch_bounds__(256) k_final(
  const float* __restrict__ dc, const float* __restrict__ df,
  const float* __restrict__ densc, const float* __restrict__ densf,
  const u16* __restrict__ rgbc, const u16* __restrict__ rgbf,
  const float* __restrict__ scal,
  float* __restrict__ out_rgb, float* __restrict__ out_depth, float* __restrict__ out_w)
{
  __shared__ float ssd[4][64];
  __shared__ float ssn[4][64];
  __shared__ int   sp [4][64];
  __shared__ float swv[4][64];   // per-interval weight
  __shared__ float swz[4][64];   // per-interval weight*z_mid
  int wid = threadIdx.x>>6, lane = threadIdx.x&63;
  int ray = blockIdx.x*4 + wid;

  float myd = (lane<32)? dc[ray*32+lane]    : df[ray*32+lane-32];
  float myn = (lane<32)? densc[ray*32+lane] : densf[ray*32+lane-32];
  ssd[wid][lane]=myd; __syncthreads();
  int rk=0;
#pragma unroll 8
  for(int j=0;j<64;j++){
    float dj = ssd[wid][j];
    rk += (dj<myd || (dj==myd && j<lane)) ? 1:0;     // stable argsort rank
  }
  __syncthreads();
  ssd[wid][rk]=myd; ssn[wid][rk]=myn; sp[wid][rk]=lane;
  __syncthreads();

  float T=1.f, accr=0.f;
  int j0 = sp[wid][0];
  float cprev = 0.f;
  if (lane<32){
    const u16* cb = (j0<32)? (rgbc+((size_t)ray*32+j0)*32) : (rgbf+((size_t)ray*32+(j0-32))*32);
    cprev = __uint_as_float(((u32)cb[lane])<<16);
  }
  float d0 = ssd[wid][0], n0 = ssn[wid][0];
  for(int s2=0;s2<63;s2++){
    float d1 = ssd[wid][s2+1], n1 = ssn[wid][s2+1];
    float delta = fs(d1,d0);
    float dm = fm(0.5f, fa(n0,n1));
    float al = fs(1.f, exf(-fm(dm,delta)));
    float wv = fm(al,T);
    T = fm(T, fa(fs(1.f,al), 1e-10f));
    if (lane==s2){ swv[wid][s2]=wv; swz[wid][s2]=fm(wv, fm(0.5f, fa(d0,d1))); }
    int j1 = sp[wid][s2+1];
    float cnext = 0.f;
    if (lane<32){
      const u16* cb = (j1<32)? (rgbc+((size_t)ray*32+j1)*32) : (rgbf+((size_t)ray*32+(j1-32))*32);
      cnext = __uint_as_float(((u32)cb[lane])<<16);
    }
    // comp_rgb: strided axis-2 reduce -> SEQUENTIAL accumulation (numpy)
    accr = fa(accr, fm(wv, fm(0.5f, fa(cprev,cnext))));
    cprev=cnext; d0=d1; n0=n1;
  }
  __syncthreads();
  if(lane<63) out_w[(size_t)ray*63+lane]=swv[wid][lane];
  if(lane<32) out_rgb[(size_t)ray*32+lane]=fs(fm(accr,2.f),1.f);
  if(lane==0){
    // np.sum pairwise (n=63, contiguous): r[j]=sum_k a[8k+j] k=0..6; tree; tail 56..62
    float wsum, zsum;
    {
      float r[8], rz[8];
#pragma unroll
      for(int j=0;j<8;j++){ r[j]=swv[wid][j]; rz[j]=swz[wid][j]; }
      for(int i=8;i<56;i+=8)
#pragma unroll
        for(int j=0;j<8;j++){ r[j]=fa(r[j],swv[wid][i+j]); rz[j]=fa(rz[j],swz[wid][i+j]); }
      wsum = fa(fa(fa(r[0],r[1]),fa(r[2],r[3])), fa(fa(r[4],r[5]),fa(r[6],r[7])));
      zsum = fa(fa(fa(rz[0],rz[1]),fa(rz[2],rz[3])), fa(fa(rz[4],rz[5]),fa(rz[6],rz[7])));
      for(int i=56;i<63;i++){ wsum=fa(wsum,swv[wid][i]); zsum=fa(zsum,swz[wid][i]); }
    }
    float depv = fdv(zsum, wsum);
    if (isnan(depv)) depv = INFINITY;    // nan_to_num(nan=inf)
    float lo = fdec(((const u32*)scal)[2]);
    float hi = fdec(((const u32*)scal)[3]);
    depv = fminf(fmaxf(depv,lo),hi);     // clip to global all_d min/max
    out_depth[ray]=depv;
  }
}

extern "C" void kernel_launch(void* const* d_in, const int* in_sizes, int n_in,
                              void* d_out, int out_size, void* d_ws, size_t ws_size,
                              hipStream_t stream) {
  const float* planes = (const float*)d_in[0];
  const float* ro     = (const float*)d_in[1];
  const float* rdp    = (const float*)d_in[2];
  const float* hmin   = (const float*)d_in[3];
  const float* hmax   = (const float*)d_in[4];
  const float* jitter = (const float*)d_in[5];
  const float* uimp   = (const float*)d_in[6];
  const float* W1     = (const float*)d_in[7];
  const float* b1     = (const float*)d_in[8];
  const float* W2     = (const float*)d_in[9];
  const float* b2     = (const float*)d_in[10];
  const float* sb     = (const float*)d_in[11];
  const int*   hmk    = (const int*)d_in[12];
  float* out = (float*)d_out;
  char* ws = (char*)d_ws;

  size_t off=0;
  auto alloc=[&](size_t bytes){ size_t o=off; off=(off+bytes+255)&~(size_t)255; return o; };
  float* scal = (float*)(ws+alloc(64));
  float* W1t  = (float*)(ws+alloc(2048*4));
  float* pt   = (float*)(ws+alloc((size_t)12582912*4));
  float* dco  = (float*)(ws+alloc((size_t)NSAMP*4));
  float* dfi  = (float*)(ws+alloc((size_t)NSAMP*4));
  float* dnc  = (float*)(ws+alloc((size_t)NSAMP*4));
  float* dnf  = (float*)(ws+alloc((size_t)NSAMP*4));
  u16*   rgc  = (u16*)  (ws+alloc((size_t)NSAMP*32*2));
  u16*   rgf  = (u16*)  (ws+alloc((size_t)NSAMP*32*2));
  (void)in_sizes; (void)n_in; (void)out_size; (void)ws_size;

  float* out_rgb  = out;
  float* out_dep  = out + 262144;
  float* out_w    = out + 270336;
  float* out_psdf = out + 786432;

  k_init<<<dim3(1),dim3(256),0,stream>>>(hmin,hmax,W1,scal,W1t);
  k_tr<<<dim3(12288),dim3(256),0,stream>>>(planes, pt);
  k_eval<0><<<dim3(2048),dim3(256),0,stream>>>(pt,ro,rdp,hmin,hmax,jitter,hmk,W1t,b1,W2,b2,sb,scal,dco,dnc,rgc,out_psdf);
  k_imp<<<dim3(128),dim3(64),0,stream>>>(dco,dnc,uimp,dfi,scal);
  k_eval<1><<<dim3(2048),dim3(256),0,stream>>>(pt,ro,rdp,hmin,hmax,jitter,hmk,W1t,b1,W2,b2,sb,scal,dfi,dnf,rgf,out_psdf);
  k_final<<<dim3(2048),dim3(256),0,stream>>>(dco,dfi,dnc,dnf,rgc,rgf,scal,out_rgb,out_dep,out_w);
}

// Round 12
// 681.778 us; speedup vs baseline: 1.4898x; 1.4898x over previous
//
#include <hip/hip_runtime.h>
#include <hip/hip_bf16.h>
#include <math.h>
#include <stddef.h>

typedef unsigned int u32;
typedef unsigned short u16;
typedef unsigned long long u64;

#define NRAYS 8192      // N_BATCH * N_RAYS
#define NSAMP 262144    // NRAYS * 32

// ---- strict float32 ops (block FMA contraction, numpy-per-op rounding) ----
__device__ __forceinline__ float fa(float a,float b){ return __fadd_rn(a,b); }
__device__ __forceinline__ float fs(float a,float b){ return __fsub_rn(a,b); }
__device__ __forceinline__ float fm(float a,float b){ return __fmul_rn(a,b); }
__device__ __forceinline__ float fdv(float a,float b){ return __fdiv_rn(a,b); }

// ---- fast double exp: |rel err| < ~2^-45, branch-light (march + density path) ----
__device__ __forceinline__ double exp_d(double x){
  const double LOG2E  = 1.4426950408889634074;
  const double LN2_HI = 6.93147180369123816490e-01;
  const double LN2_LO = 1.90821492927058770002e-10;
  double kd = rint(x * LOG2E);
  if (kd >  200.0) return INFINITY;
  if (kd < -200.0) return 0.0;
  int k = (int)kd;
  double r = fma(-kd, LN2_HI, x);
  r = fma(-kd, LN2_LO, r);
  double p = 1.0/39916800.0;
  p = fma(p, r, 1.0/3628800.0);
  p = fma(p, r, 1.0/362880.0);
  p = fma(p, r, 1.0/40320.0);
  p = fma(p, r, 1.0/5040.0);
  p = fma(p, r, 1.0/720.0);
  p = fma(p, r, 1.0/120.0);
  p = fma(p, r, 1.0/24.0);
  p = fma(p, r, 1.0/6.0);
  p = fma(p, r, 0.5);
  p = fma(p, r, 1.0);
  p = fma(p, r, 1.0);
  u64 sb = ((u64)(k + 1023)) << 52;
  return p * __longlong_as_double((long long)sb);
}
__device__ __forceinline__ float exf(float x){ return (float)exp_d((double)x); }
__device__ __forceinline__ float sigm(float x){   // exact-path stepwise f32 sigmoid (density head)
  if (x >= 0.f){ float e = exf(-x); return fdv(1.f, fa(1.f, e)); }
  float e = exf(x); return fdv(e, fa(1.f, e));
}
// fast sigmoid for the rgb head only (abs tolerance 5.6e-2; bf16-quantized anyway)
__device__ __forceinline__ float sigm_fast(float x){
  return 1.f/(1.f + __expf(-x));
}
__device__ __forceinline__ u16 f2b(float f){
  u32 x = __float_as_uint(f);
  return (u16)((x + 0x7fffu + ((x>>16)&1u)) >> 16);   // RNE
}
// monotone float<->u32 key (handles negatives) for atomic min/max
__device__ __forceinline__ u32 fenc(float f){ u32 b=__float_as_uint(f); return (b&0x80000000u)? ~b : (b|0x80000000u); }
__device__ __forceinline__ float fdec(u32 k){ u32 b=(k&0x80000000u)? (k^0x80000000u) : ~k; return __uint_as_float(b); }

// ---------------- init: global min/max of hit depths, scalar slots, W1 transpose ----------------
__global__ void k_init(const float* __restrict__ hmin, const float* __restrict__ hmax,
                       const float* __restrict__ W1, float* __restrict__ scal,
                       float* __restrict__ W1t){
  __shared__ float smn[256], smx[256];
  int t = threadIdx.x;
  float mn = 1e30f, mx = -1e30f;
  for (int i=t;i<NRAYS;i+=256){ mn=fminf(mn,hmin[i]); mx=fmaxf(mx,hmax[i]); }
  smn[t]=mn; smx[t]=mx; __syncthreads();
  for(int s=128;s>0;s>>=1){
    if(t<s){ smn[t]=fminf(smn[t],smn[t+s]); smx[t]=fmaxf(smx[t],smx[t+s]); }
    __syncthreads();
  }
  if(t==0){
    scal[0]=smn[0]; scal[1]=smx[0];
    ((u32*)scal)[2]=0xFFFFFFFFu;  // dmin key (atomicMin on monotone key)
    ((u32*)scal)[3]=0u;           // dmax key (atomicMax)
  }
  for(int i=t;i<2048;i+=256){ int j=i>>5, c=i&31; W1t[i]=W1[c*64+j]; }  // W1t[j*32+c]
}

// ---------------- transpose planes (N,3,C,H,W) f32 -> (N*3,H,W,C) f32 ----------------
__global__ void __launch_bounds__(256) k_tr(const float* __restrict__ pl, float* __restrict__ pt){
  int t = blockIdx.x*256 + threadIdx.x;     // 0 .. 3145727
  int x  = t & 255;
  int c4 = ((t>>8)&7)<<2;
  int y  = (t>>11)&255;
  int np = t>>19;                            // 0..5
  const float* ip = pl + (((size_t)(np*32+c4))<<16) + (y<<8) + x;
  float4 o;
  o.x = ip[0];
  o.y = ip[65536];
  o.z = ip[131072];
  o.w = ip[196608];
  *reinterpret_cast<float4*>(pt + ((((size_t)(np<<8|y))<<8|x)<<5) + c4) = o;
}

// ---------------- SAMPLE: tri-plane gather -> feat[32] in workspace ----------------
// 2 threads/point, thread hf owns channels [16hf,16hf+16): same cache lines as full-texel
// (one 128B line per corner), half the per-thread loads, low VGPR -> 8 waves/SIMD.
// Arithmetic bit-identical to the r9-verified build (r8-verified channel-split class).
template<int PHASE>
__global__ void __launch_bounds__(256) k_sample(
  const float* __restrict__ pt, const float* __restrict__ ro, const float* __restrict__ rd,
  const float* __restrict__ hmin, const float* __restrict__ hmax,
  const float* __restrict__ jitter, const int* __restrict__ hitmask,
  float* __restrict__ scal, float* __restrict__ dep, float* __restrict__ feat_ws)
{
  int tid = blockIdx.x*256 + threadIdx.x;   // 0..524287
  int pid = tid >> 1;                        // point 0..262143
  int hf  = tid & 1;                         // channel half
  int ray = pid >> 5;
  int s   = pid & 31;
  int n   = ray >> 12;
  int msk = hitmask[ray];

  float d;
  if (PHASE==0){
    float hmn = msk ? hmin[ray] : scal[0];
    float hmx = msk ? hmax[ray] : scal[1];
    float span = fs(hmx, hmn);
    float jit  = jitter[pid];
    float base = (float)((double)s * (1.0/31.0));   // np.linspace f64 arange*step -> f32 cast
    if (s==31) base = 1.0f;
    float t1 = fdv(fm(jit, span), 32.0f);
    d = fa(fm(fa(base, t1), span), hmn);
    if (hf==0) dep[pid] = d;
    float dm=d, dM=d;   // duplicates across the pair don't change min/max
#pragma unroll
    for (int m=1;m<64;m<<=1){ dm=fminf(dm,__shfl_xor(dm,m)); dM=fmaxf(dM,__shfl_xor(dM,m)); }
    if ((threadIdx.x & 63)==0){
      atomicMin(((u32*)scal)+2, fenc(dm));
      atomicMax(((u32*)scal)+3, fenc(dM));
    }
  } else {
    d = dep[pid];
  }

  float ox=ro[ray*3+0], oy=ro[ray*3+1], oz=ro[ray*3+2];
  float dx=rd[ray*3+0], dy=rd[ray*3+1], dz=rd[ray*3+2];
  float px = fa(ox, fm(d,dx)), py = fa(oy, fm(d,dy)), pz = fa(oz, fm(d,dz));
  const float sc2 = (float)(2.0/6.0);
  float cx=fm(px,sc2), cy=fm(py,sc2), cz=fm(pz,sc2);

  float feat[16];    // this thread's 16 channels
#pragma unroll
  for(int c=0;c<16;c++) feat[c]=0.f;

#pragma unroll
  for (int p=0;p<3;p++){
    float u = (p==2)?cz:cx;                  // plane0:(x,y) plane1:(x,z) plane2:(z,y)
    float v = (p==1)?cz:cy;
    float fx = fs(fm(fa(u,1.f),128.f),0.5f); // (u+1)*128-0.5 per-op
    float fy = fs(fm(fa(v,1.f),128.f),0.5f);
    float x0f = floorf(fx), y0f = floorf(fy);
    float wx = fs(fx,x0f), wy = fs(fy,y0f);
    float ax0 = fs(1.f,wx), ax1 = wx, ay0 = fs(1.f,wy), ay1 = wy;
    int x0, y0;
    { // saturating cast (wild coords can exceed int range semantics; floor first)
      x0 = (x0f >= 2.1e9f) ? 2147483647 : ((x0f <= -2.1e9f) ? (-2147483647-1) : (int)x0f);
      y0 = (y0f >= 2.1e9f) ? 2147483647 : ((y0f <= -2.1e9f) ? (-2147483647-1) : (int)y0f);
    }
    int x1=x0+1, y1=y0+1;
    bool vx0 = (x0>=0 && x0<256), vx1 = (x1>=0 && x1<256);
    bool vy0 = (y0>=0 && y0<256), vy1 = (y1>=0 && y1<256);
    bool ok00 = vx0&&vy0, ok01 = vx1&&vy0, ok10 = vx0&&vy1, ok11 = vx1&&vy1;
    int cx0=min(max(x0,0),255), cx1=min(max(x1,0),255);
    int cy0=min(max(y0,0),255), cy1=min(max(y1,0),255);
    int npl = n*3+p;
    size_t pb = ((size_t)npl)<<16;
    int qof = hf<<4;   // float offset of this thread's 16 channels within the texel
    const float4* t00 = (const float4*)(pt + ((pb + (cy0<<8) + cx0)<<5) + qof);
    const float4* t01 = (const float4*)(pt + ((pb + (cy0<<8) + cx1)<<5) + qof);
    const float4* t10 = (const float4*)(pt + ((pb + (cy1<<8) + cx0)<<5) + qof);
    const float4* t11 = (const float4*)(pt + ((pb + (cy1<<8) + cx1)<<5) + qof);
#pragma unroll
    for(int q=0;q<4;q++){
      float4 v00 = t00[q], v01 = t01[q], v10 = t10[q], v11 = t11[q];
      float e0,e1,e2,e3, t_;
#define CORNER_SUM(FLD, OUTI) \
      e0 = ok00 ? v00.FLD : 0.f; e1 = ok01 ? v01.FLD : 0.f; \
      e2 = ok10 ? v10.FLD : 0.f; e3 = ok11 ? v11.FLD : 0.f; \
      t_ = fa(fa(fa(fm(fm(e0,ax0),ay0), fm(fm(e1,ax1),ay0)), fm(fm(e2,ax0),ay1)), fm(fm(e3,ax1),ay1)); \
      feat[q*4+OUTI] = fa(feat[q*4+OUTI], t_);
      CORNER_SUM(x,0) CORNER_SUM(y,1) CORNER_SUM(z,2) CORNER_SUM(w,3)
#undef CORNER_SUM
    }
  }
  float4* fw = (float4*)(feat_ws + ((size_t)pid<<5) + (hf<<4));
#pragma unroll
  for(int q=0;q<4;q++){
    float4 o4;
    o4.x = fdv(feat[q*4+0], 3.0f);   // np.mean: (f0+f1)+f2 then /3
    o4.y = fdv(feat[q*4+1], 3.0f);
    o4.z = fdv(feat[q*4+2], 3.0f);
    o4.w = fdv(feat[q*4+3], 3.0f);
    fw[q] = o4;
  }
}

// ---------------- DECODE: feat -> MLP -> density/psdf/rgb (r9 decoder verbatim) ----------------
template<int PHASE>
__global__ void __launch_bounds__(256) k_decode(
  const float* __restrict__ feat_ws, const float* __restrict__ ro, const float* __restrict__ rd,
  const int* __restrict__ hitmask,
  const float* __restrict__ W1t, const float* __restrict__ b1,
  const float* __restrict__ W2, const float* __restrict__ b2,
  const float* __restrict__ sb,
  const float* __restrict__ dep, float* __restrict__ dens_out, u16* __restrict__ rgb_out,
  float* __restrict__ out_psdf)
{
  int idx = blockIdx.x*256 + threadIdx.x;   // 0..262143
  int ray = idx >> 5;
  int s   = idx & 31;
  int n   = ray >> 12;
  int msk = hitmask[ray];
  float d = dep[idx];

  float ox=ro[ray*3+0], oy=ro[ray*3+1], oz=ro[ray*3+2];
  float dx=rd[ray*3+0], dy=rd[ray*3+1], dz=rd[ray*3+2];
  float px = fa(ox, fm(d,dx)), py = fa(oy, fm(d,dy)), pz = fa(oz, fm(d,dz));
  float nrm = __fsqrt_rn(fa(fa(fm(px,px),fm(py,py)),fm(pz,pz)));
  float tsdf = fs(nrm, 0.5f);

  float feat[32];
  {
    const float4* fr = (const float4*)(feat_ws + ((size_t)idx<<5));
#pragma unroll
    for(int q=0;q<8;q++){
      float4 v = fr[q];
      feat[q*4+0]=v.x; feat[q*4+1]=v.y; feat[q*4+2]=v.z; feat[q*4+3]=v.w;
    }
  }

  // decoder: h = softplus(feat@W1+b1); o = h@W2+b2 (sequential chain = r5/r6/r9-verified order)
  float o[33];
#pragma unroll
  for(int k=0;k<33;k++) o[k]=0.f;
#pragma unroll 2
  for(int j=0;j<64;j++){
    float a = 0.f;
#pragma unroll
    for(int c=0;c<32;c++) a = fmaf(feat[c], W1t[j*32+c], a);
    a = fa(a, b1[j]);
    // native-HW stable softplus: v_exp_f32 + v_log_f32 (r9-verified)
    float h = fa(fmaxf(a,0.f), __logf(fa(1.f, __expf(-fabsf(a)))));
#pragma unroll
    for(int k=0;k<33;k++) o[k] = fmaf(h, W2[j*33+k], o[k]);
  }
#pragma unroll
  for(int k=0;k<33;k++) o[k] = fa(o[k], b2[k]);

  float beta = fmaxf(sb[0], 0.002f);
  float raw = o[0];
  out_psdf[((size_t)n<<18) + ((size_t)PHASE<<17) + (size_t)(ray&4095)*32 + s] = raw;  // unmasked
  float sg = fa(raw, tsdf);
  float dens = msk ? fdv(sigm(fdv(-sg, beta)), beta) : 0.f;   // exact path (chaotic cdf chain)
  dens_out[idx]=dens;

  u16 rv[32];
#pragma unroll
  for(int c=0;c<32;c++){
    float r = msk ? fs(fm(sigm_fast(o[c+1]), 1.002f), 0.001f) : 0.f;  // fast path, abs tol 5.6e-2
    rv[c]=f2b(r);
  }
  uint4* op = (uint4*)(rgb_out + (size_t)idx*32);
#pragma unroll
  for(int q=0;q<4;q++){
    uint4 w;
    w.x = (u32)rv[q*8+0] | ((u32)rv[q*8+1]<<16);
    w.y = (u32)rv[q*8+2] | ((u32)rv[q*8+3]<<16);
    w.z = (u32)rv[q*8+4] | ((u32)rv[q*8+5]<<16);
    w.w = (u32)rv[q*8+6] | ((u32)rv[q*8+7]<<16);
    op[q]=w;
  }
}

// ---------------- coarse march + importance sampling (strict f32, thread per ray) ----------------
__global__ void __launch_bounds__(64) k_imp(
  const float* __restrict__ dc, const float* __restrict__ dens,
  const float* __restrict__ u_imp, float* __restrict__ df, float* __restrict__ scal)
{
  __shared__ float scdf[64][30];
  __shared__ float szm [64][30];
  int tid = threadIdx.x;
  int ray = blockIdx.x*64 + tid;   // 0..8191
  float w[31];
  float dprev = dc[ray*32+0];
  float sprev = dens[ray*32+0];
  float T = 1.f;
#pragma unroll
  for(int i=0;i<31;i++){
    float dn = dc[ray*32+i+1];
    float sn = dens[ray*32+i+1];
    if (i<30) szm[tid][i] = fm(0.5f, fa(dprev,dn));
    float delta = fs(dn,dprev);
    float dm = fm(0.5f, fa(sprev,sn));
    float al = fs(1.f, exf(-fm(dm,delta)));
    w[i] = fm(al,T);
    T = fm(T, fa(fs(1.f,al), 1e-10f));
    dprev=dn; sprev=sn;
  }
  // pdf weights: w_sm[j]=0.5*(m[j]+m[j+1])+0.01 (j=1..29), +EPS
  float pdfw[29];
#pragma unroll
  for(int i=0;i<29;i++){
    float m1 = fmaxf(w[i],w[i+1]), m2 = fmaxf(w[i+1],w[i+2]);
    pdfw[i] = fa(fa(fm(0.5f, fa(m1,m2)), 0.01f), 1e-5f);
  }
  // np.sum pairwise (n=29): 8 accumulators, 2 blocked adds, tree, 5 sequential tail
  float sum;
  {
    float r[8];
#pragma unroll
    for(int j=0;j<8;j++) r[j]=pdfw[j];
#pragma unroll
    for(int j=0;j<8;j++) r[j]=fa(r[j],pdfw[8+j]);
#pragma unroll
    for(int j=0;j<8;j++) r[j]=fa(r[j],pdfw[16+j]);
    sum = fa(fa(fa(r[0],r[1]),fa(r[2],r[3])), fa(fa(r[4],r[5]),fa(r[6],r[7])));
#pragma unroll
    for(int i=24;i<29;i++) sum = fa(sum, pdfw[i]);
  }
  // cdf: sequential cumsum of pdf (per-element f32 division)
  {
    float cacc = 0.f;
    scdf[tid][0] = 0.f;
#pragma unroll
    for(int i=1;i<30;i++){
      cacc = fa(cacc, fdv(pdfw[i-1], sum));
      scdf[tid][i] = cacc;
    }
  }

  float fmn=1e30f, fmx=-1e30f;
  for(int k=0;k<32;k++){
    float u = u_imp[ray*32+k];
    // np.searchsorted(cdf, u, 'right') = bisect_right (binary, regardless of monotonicity)
    int lo=0, hi=30;
    while(lo<hi){
      int mid=(lo+hi)>>1;
      if (scdf[tid][mid] <= u) lo = mid+1; else hi = mid;
    }
    int ind = lo;                 // in [1,30]
    int below = ind-1;            // in [0,29]
    int above = (ind>29)?29:ind;  // in [0,29]
    float cdf0 = scdf[tid][below];
    float cdf1 = scdf[tid][above];
    float b0   = szm [tid][below];
    float b1v  = szm [tid][above];
    float den = fs(cdf1,cdf0);
    if((double)den < 1e-5) den = 1.f;      // EPS compare in f64 (python const)
    float sres = fa(b0, fm(fdv(fs(u,cdf0),den), fs(b1v,b0)));
    df[ray*32+k]=sres;
    fmn=fminf(fmn,sres); fmx=fmaxf(fmx,sres);
  }
#pragma unroll
  for(int m=1;m<64;m<<=1){ fmn=fminf(fmn,__shfl_xor(fmn,m)); fmx=fmaxf(fmx,__shfl_xor(fmx,m)); }
  if(tid==0){
    atomicMin(((u32*)scal)+2, fenc(fmn));
    atomicMax(((u32*)scal)+3, fenc(fmx));
  }
}

// ---------------- stable sort (64) + final ray march, strict f32 (wave per ray) ----------------
__global__ void __launch_bounds__(256) k_final(
  const float* __restrict__ dc, const float* __restrict__ df,
  const float* __restrict__ densc, const float* __restrict__ densf,
  const u16* __restrict__ rgbc, const u16* __restrict__ rgbf,
  const float* __restrict__ scal,
  float* __restrict__ out_rgb, float* __restrict__ out_depth, float* __restrict__ out_w)
{
  __shared__ float ssd[4][64];
  __shared__ float ssn[4][64];
  __shared__ int   sp [4][64];
  __shared__ float swv[4][64];   // per-interval weight
  __shared__ float swz[4][64];   // per-interval weight*z_mid
  int wid = threadIdx.x>>6, lane = threadIdx.x&63;
  int ray = blockIdx.x*4 + wid;

  float myd = (lane<32)? dc[ray*32+lane]    : df[ray*32+lane-32];
  float myn = (lane<32)? densc[ray*32+lane] : densf[ray*32+lane-32];
  ssd[wid][lane]=myd; __syncthreads();
  int rk=0;
#pragma unroll 8
  for(int j=0;j<64;j++){
    float dj = ssd[wid][j];
    rk += (dj<myd || (dj==myd && j<lane)) ? 1:0;     // stable argsort rank
  }
  __syncthreads();
  ssd[wid][rk]=myd; ssn[wid][rk]=myn; sp[wid][rk]=lane;
  __syncthreads();

  float T=1.f, accr=0.f;
  int j0 = sp[wid][0];
  float cprev = 0.f;
  if (lane<32){
    const u16* cb = (j0<32)? (rgbc+((size_t)ray*32+j0)*32) : (rgbf+((size_t)ray*32+(j0-32))*32);
    cprev = __uint_as_float(((u32)cb[lane])<<16);
  }
  float d0 = ssd[wid][0], n0 = ssn[wid][0];
  for(int s2=0;s2<63;s2++){
    float d1 = ssd[wid][s2+1], n1 = ssn[wid][s2+1];
    float delta = fs(d1,d0);
    float dm = fm(0.5f, fa(n0,n1));
    float al = fs(1.f, exf(-fm(dm,delta)));
    float wv = fm(al,T);
    T = fm(T, fa(fs(1.f,al), 1e-10f));
    if (lane==s2){ swv[wid][s2]=wv; swz[wid][s2]=fm(wv, fm(0.5f, fa(d0,d1))); }
    int j1 = sp[wid][s2+1];
    float cnext = 0.f;
    if (lane<32){
      const u16* cb = (j1<32)? (rgbc+((size_t)ray*32+j1)*32) : (rgbf+((size_t)ray*32+(j1-32))*32);
      cnext = __uint_as_float(((u32)cb[lane])<<16);
    }
    // comp_rgb: strided axis-2 reduce -> SEQUENTIAL accumulation (numpy)
    accr = fa(accr, fm(wv, fm(0.5f, fa(cprev,cnext))));
    cprev=cnext; d0=d1; n0=n1;
  }
  __syncthreads();
  if(lane<63) out_w[(size_t)ray*63+lane]=swv[wid][lane];
  if(lane<32) out_rgb[(size_t)ray*32+lane]=fs(fm(accr,2.f),1.f);
  if(lane==0){
    // np.sum pairwise (n=63, contiguous): r[j]=sum_k a[8k+j] k=0..6; tree; tail 56..62
    float wsum, zsum;
    {
      float r[8], rz[8];
#pragma unroll
      for(int j=0;j<8;j++){ r[j]=swv[wid][j]; rz[j]=swz[wid][j]; }
      for(int i=8;i<56;i+=8)
#pragma unroll
        for(int j=0;j<8;j++){ r[j]=fa(r[j],swv[wid][i+j]); rz[j]=fa(rz[j],swz[wid][i+j]); }
      wsum = fa(fa(fa(r[0],r[1]),fa(r[2],r[3])), fa(fa(r[4],r[5]),fa(r[6],r[7])));
      zsum = fa(fa(fa(rz[0],rz[1]),fa(rz[2],rz[3])), fa(fa(rz[4],rz[5]),fa(rz[6],rz[7])));
      for(int i=56;i<63;i++){ wsum=fa(wsum,swv[wid][i]); zsum=fa(zsum,swz[wid][i]); }
    }
    float depv = fdv(zsum, wsum);
    if (isnan(depv)) depv = INFINITY;    // nan_to_num(nan=inf)
    float lo = fdec(((const u32*)scal)[2]);
    float hi = fdec(((const u32*)scal)[3]);
    depv = fminf(fmaxf(depv,lo),hi);     // clip to global all_d min/max
    out_depth[ray]=depv;
  }
}

extern "C" void kernel_launch(void* const* d_in, const int* in_sizes, int n_in,
                              void* d_out, int out_size, void* d_ws, size_t ws_size,
                              hipStream_t stream) {
  const float* planes = (const float*)d_in[0];
  const float* ro     = (const float*)d_in[1];
  const float* rdp    = (const float*)d_in[2];
  const float* hmin   = (const float*)d_in[3];
  const float* hmax   = (const float*)d_in[4];
  const float* jitter = (const float*)d_in[5];
  const float* uimp   = (const float*)d_in[6];
  const float* W1     = (const float*)d_in[7];
  const float* b1     = (const float*)d_in[8];
  const float* W2     = (const float*)d_in[9];
  const float* b2     = (const float*)d_in[10];
  const float* sb     = (const float*)d_in[11];
  const int*   hmk    = (const int*)d_in[12];
  float* out = (float*)d_out;
  char* ws = (char*)d_ws;

  size_t off=0;
  auto alloc=[&](size_t bytes){ size_t o=off; off=(off+bytes+255)&~(size_t)255; return o; };
  float* scal = (float*)(ws+alloc(64));
  float* W1t  = (float*)(ws+alloc(2048*4));
  float* pt   = (float*)(ws+alloc((size_t)12582912*4));
  float* featw= (float*)(ws+alloc((size_t)NSAMP*32*4));   // 32 MB feat staging (reused per phase)
  float* dco  = (float*)(ws+alloc((size_t)NSAMP*4));
  float* dfi  = (float*)(ws+alloc((size_t)NSAMP*4));
  float* dnc  = (float*)(ws+alloc((size_t)NSAMP*4));
  float* dnf  = (float*)(ws+alloc((size_t)NSAMP*4));
  u16*   rgc  = (u16*)  (ws+alloc((size_t)NSAMP*32*2));
  u16*   rgf  = (u16*)  (ws+alloc((size_t)NSAMP*32*2));
  (void)in_sizes; (void)n_in; (void)out_size; (void)ws_size;

  float* out_rgb  = out;
  float* out_dep  = out + 262144;
  float* out_w    = out + 270336;
  float* out_psdf = out + 786432;

  k_init<<<dim3(1),dim3(256),0,stream>>>(hmin,hmax,W1,scal,W1t);
  k_tr<<<dim3(12288),dim3(256),0,stream>>>(planes, pt);
  k_sample<0><<<dim3(2048),dim3(256),0,stream>>>(pt,ro,rdp,hmin,hmax,jitter,hmk,scal,dco,featw);
  k_decode<0><<<dim3(1024),dim3(256),0,stream>>>(featw,ro,rdp,hmk,W1t,b1,W2,b2,sb,dco,dnc,rgc,out_psdf);
  k_imp<<<dim3(128),dim3(64),0,stream>>>(dco,dnc,uimp,dfi,scal);
  k_sample<1><<<dim3(2048),dim3(256),0,stream>>>(pt,ro,rdp,hmin,hmax,jitter,hmk,scal,dfi,featw);
  k_decode<1><<<dim3(1024),dim3(256),0,stream>>>(featw,ro,rdp,hmk,W1t,b1,W2,b2,sb,dfi,dnf,rgf,out_psdf);
  k_final<<<dim3(2048),dim3(256),0,stream>>>(dco,dfi,dnc,dnf,rgc,rgf,scal,out_rgb,out_dep,out_w);
}

// Round 13
// 650.832 us; speedup vs baseline: 1.5607x; 1.0475x over previous
//
#include <hip/hip_runtime.h>
#include <hip/hip_bf16.h>
#include <math.h>
#include <stddef.h>

typedef unsigned int u32;
typedef unsigned short u16;
typedef unsigned long long u64;

#define NRAYS 8192      // N_BATCH * N_RAYS
#define NSAMP 262144    // NRAYS * 32

// ---- strict float32 ops (block FMA contraction, numpy-per-op rounding) ----
__device__ __forceinline__ float fa(float a,float b){ return __fadd_rn(a,b); }
__device__ __forceinline__ float fs(float a,float b){ return __fsub_rn(a,b); }
__device__ __forceinline__ float fm(float a,float b){ return __fmul_rn(a,b); }
__device__ __forceinline__ float fdv(float a,float b){ return __fdiv_rn(a,b); }

// ---- fast double exp: |rel err| < ~2^-45, branch-light (march + density path) ----
__device__ __forceinline__ double exp_d(double x){
  const double LOG2E  = 1.4426950408889634074;
  const double LN2_HI = 6.93147180369123816490e-01;
  const double LN2_LO = 1.90821492927058770002e-10;
  double kd = rint(x * LOG2E);
  if (kd >  200.0) return INFINITY;
  if (kd < -200.0) return 0.0;
  int k = (int)kd;
  double r = fma(-kd, LN2_HI, x);
  r = fma(-kd, LN2_LO, r);
  double p = 1.0/39916800.0;
  p = fma(p, r, 1.0/3628800.0);
  p = fma(p, r, 1.0/362880.0);
  p = fma(p, r, 1.0/40320.0);
  p = fma(p, r, 1.0/5040.0);
  p = fma(p, r, 1.0/720.0);
  p = fma(p, r, 1.0/120.0);
  p = fma(p, r, 1.0/24.0);
  p = fma(p, r, 1.0/6.0);
  p = fma(p, r, 0.5);
  p = fma(p, r, 1.0);
  p = fma(p, r, 1.0);
  u64 sb = ((u64)(k + 1023)) << 52;
  return p * __longlong_as_double((long long)sb);
}
__device__ __forceinline__ float exf(float x){ return (float)exp_d((double)x); }
__device__ __forceinline__ float sigm(float x){   // exact-path stepwise f32 sigmoid (density head)
  if (x >= 0.f){ float e = exf(-x); return fdv(1.f, fa(1.f, e)); }
  float e = exf(x); return fdv(e, fa(1.f, e));
}
// fast sigmoid for the rgb head only (abs tolerance 5.6e-2; bf16-quantized anyway)
__device__ __forceinline__ float sigm_fast(float x){
  return 1.f/(1.f + __expf(-x));
}
__device__ __forceinline__ u16 f2b(float f){
  u32 x = __float_as_uint(f);
  return (u16)((x + 0x7fffu + ((x>>16)&1u)) >> 16);   // RNE
}
// monotone float<->u32 key (handles negatives) for atomic min/max
__device__ __forceinline__ u32 fenc(float f){ u32 b=__float_as_uint(f); return (b&0x80000000u)? ~b : (b|0x80000000u); }
__device__ __forceinline__ float fdec(u32 k){ u32 b=(k&0x80000000u)? (k^0x80000000u) : ~k; return __uint_as_float(b); }

// ---------------- init: global min/max of hit depths, scalar slots, W1 transpose ----------------
__global__ void k_init(const float* __restrict__ hmin, const float* __restrict__ hmax,
                       const float* __restrict__ W1, float* __restrict__ scal,
                       float* __restrict__ W1t){
  __shared__ float smn[256], smx[256];
  int t = threadIdx.x;
  float mn = 1e30f, mx = -1e30f;
  for (int i=t;i<NRAYS;i+=256){ mn=fminf(mn,hmin[i]); mx=fmaxf(mx,hmax[i]); }
  smn[t]=mn; smx[t]=mx; __syncthreads();
  for(int s=128;s>0;s>>=1){
    if(t<s){ smn[t]=fminf(smn[t],smn[t+s]); smx[t]=fmaxf(smx[t],smx[t+s]); }
    __syncthreads();
  }
  if(t==0){
    scal[0]=smn[0]; scal[1]=smx[0];
    ((u32*)scal)[2]=0xFFFFFFFFu;  // dmin key (atomicMin on monotone key)
    ((u32*)scal)[3]=0u;           // dmax key (atomicMax)
  }
  for(int i=t;i<2048;i+=256){ int j=i>>5, c=i&31; W1t[i]=W1[c*64+j]; }  // W1t[j*32+c]
}

// ---------------- transpose planes (N,3,C,H,W) f32 -> (N*3,H,W,C) f32 ----------------
__global__ void __launch_bounds__(256) k_tr(const float* __restrict__ pl, float* __restrict__ pt){
  int t = blockIdx.x*256 + threadIdx.x;     // 0 .. 3145727
  int x  = t & 255;
  int c4 = ((t>>8)&7)<<2;
  int y  = (t>>11)&255;
  int np = t>>19;                            // 0..5
  const float* ip = pl + (((size_t)(np*32+c4))<<16) + (y<<8) + x;
  float4 o;
  o.x = ip[0];
  o.y = ip[65536];
  o.z = ip[131072];
  o.w = ip[196608];
  *reinterpret_cast<float4*>(pt + ((((size_t)(np<<8|y))<<8|x)<<5) + c4) = o;
}

// ---------------- point evaluation (sampling + decoder), strict f32 ----------------
// 2 THREADS PER POINT, split along OUTPUT k: thread h accumulates o[k] for
// k in [16h, 16h+17) (h=0: sigma + rgb 0..15; h=1: rgb 15..31, o[0] unused).
// Gather + dot + softplus duplicated (identical addresses/ops -> L1 broadcast,
// bit-identical h). NO cross-lane ops on o -> o[17] stays AGPR-eligible ->
// no spill (r11/r12 lesson). Grid 2048 blocks = 8 blocks/CU, 2x waves vs r9.
template<int PHASE>
__global__ void __launch_bounds__(256) k_eval(
  const float* __restrict__ pt, const float* __restrict__ ro, const float* __restrict__ rd,
  const float* __restrict__ hmin, const float* __restrict__ hmax,
  const float* __restrict__ jitter, const int* __restrict__ hitmask,
  const float* __restrict__ W1t, const float* __restrict__ b1,
  const float* __restrict__ W2, const float* __restrict__ b2,
  const float* __restrict__ sb, float* __restrict__ scal,
  float* __restrict__ dep, float* __restrict__ dens_out, u16* __restrict__ rgb_out,
  float* __restrict__ out_psdf)
{
  int tid = blockIdx.x*256 + threadIdx.x;   // 0..524287
  int pid = tid >> 1;                        // point 0..262143
  int kh  = tid & 1;                         // output-half
  int ray = pid >> 5;
  int s   = pid & 31;
  int n   = ray >> 12;
  int msk = hitmask[ray];

  float d;
  if (PHASE==0){
    float hmn = msk ? hmin[ray] : scal[0];
    float hmx = msk ? hmax[ray] : scal[1];
    float span = fs(hmx, hmn);
    float jit  = jitter[pid];
    float base = (float)((double)s * (1.0/31.0));   // np.linspace f64 arange*step -> f32 cast
    if (s==31) base = 1.0f;
    float t1 = fdv(fm(jit, span), 32.0f);
    d = fa(fm(fa(base, t1), span), hmn);
    if (kh==0) dep[pid] = d;
    float dm=d, dM=d;   // duplicates across the pair don't change min/max
#pragma unroll
    for (int m=1;m<64;m<<=1){ dm=fminf(dm,__shfl_xor(dm,m)); dM=fmaxf(dM,__shfl_xor(dM,m)); }
    if ((threadIdx.x & 63)==0){
      atomicMin(((u32*)scal)+2, fenc(dm));
      atomicMax(((u32*)scal)+3, fenc(dM));
    }
  } else {
    d = dep[pid];
  }

  float ox=ro[ray*3+0], oy=ro[ray*3+1], oz=ro[ray*3+2];
  float dx=rd[ray*3+0], dy=rd[ray*3+1], dz=rd[ray*3+2];
  float px = fa(ox, fm(d,dx)), py = fa(oy, fm(d,dy)), pz = fa(oz, fm(d,dz));
  float nrm = __fsqrt_rn(fa(fa(fm(px,px),fm(py,py)),fm(pz,pz)));
  float tsdf = fs(nrm, 0.5f);
  const float sc2 = (float)(2.0/6.0);
  float cx=fm(px,sc2), cy=fm(py,sc2), cz=fm(pz,sc2);

  float feat[32];
#pragma unroll
  for(int c=0;c<32;c++) feat[c]=0.f;

#pragma unroll
  for (int p=0;p<3;p++){
    float u = (p==2)?cz:cx;                  // plane0:(x,y) plane1:(x,z) plane2:(z,y)
    float v = (p==1)?cz:cy;
    float fx = fs(fm(fa(u,1.f),128.f),0.5f); // (u+1)*128-0.5 per-op
    float fy = fs(fm(fa(v,1.f),128.f),0.5f);
    float x0f = floorf(fx), y0f = floorf(fy);
    float wx = fs(fx,x0f), wy = fs(fy,y0f);
    float ax0 = fs(1.f,wx), ax1 = wx, ay0 = fs(1.f,wy), ay1 = wy;
    int x0, y0;
    { // saturating cast (wild coords can exceed int range semantics; floor first)
      x0 = (x0f >= 2.1e9f) ? 2147483647 : ((x0f <= -2.1e9f) ? (-2147483647-1) : (int)x0f);
      y0 = (y0f >= 2.1e9f) ? 2147483647 : ((y0f <= -2.1e9f) ? (-2147483647-1) : (int)y0f);
    }
    int x1=x0+1, y1=y0+1;
    bool vx0 = (x0>=0 && x0<256), vx1 = (x1>=0 && x1<256);
    bool vy0 = (y0>=0 && y0<256), vy1 = (y1>=0 && y1<256);
    bool ok00 = vx0&&vy0, ok01 = vx1&&vy0, ok10 = vx0&&vy1, ok11 = vx1&&vy1;
    int cx0=min(max(x0,0),255), cx1=min(max(x1,0),255);
    int cy0=min(max(y0,0),255), cy1=min(max(y1,0),255);
    int npl = n*3+p;
    size_t pb = ((size_t)npl)<<16;
    const float4* t00 = (const float4*)(pt + ((pb + (cy0<<8) + cx0)<<5));
    const float4* t01 = (const float4*)(pt + ((pb + (cy0<<8) + cx1)<<5));
    const float4* t10 = (const float4*)(pt + ((pb + (cy1<<8) + cx0)<<5));
    const float4* t11 = (const float4*)(pt + ((pb + (cy1<<8) + cx1)<<5));
#pragma unroll
    for(int q=0;q<8;q++){
      float4 v00 = t00[q], v01 = t01[q], v10 = t10[q], v11 = t11[q];
      float e0,e1,e2,e3, t_;
#define CORNER_SUM(FLD, OUTI) \
      e0 = ok00 ? v00.FLD : 0.f; e1 = ok01 ? v01.FLD : 0.f; \
      e2 = ok10 ? v10.FLD : 0.f; e3 = ok11 ? v11.FLD : 0.f; \
      t_ = fa(fa(fa(fm(fm(e0,ax0),ay0), fm(fm(e1,ax1),ay0)), fm(fm(e2,ax0),ay1)), fm(fm(e3,ax1),ay1)); \
      feat[q*4+OUTI] = fa(feat[q*4+OUTI], t_);
      CORNER_SUM(x,0) CORNER_SUM(y,1) CORNER_SUM(z,2) CORNER_SUM(w,3)
#undef CORNER_SUM
    }
  }
#pragma unroll
  for(int c=0;c<32;c++) feat[c] = fdv(feat[c], 3.0f);   // np.mean: (f0+f1)+f2 then /3

  // decoder: this thread's 17 output columns, base KB = kh*16.
  // h computed identically on both threads (bit-identical to r9); per-k fmaf
  // chain unchanged -> outputs bit-identical to the r9-verified build.
  const int KB = kh << 4;
  float o[17];
#pragma unroll
  for(int k=0;k<17;k++) o[k]=0.f;
#pragma unroll 2
  for(int j=0;j<64;j++){
    float a = 0.f;
#pragma unroll
    for(int c=0;c<32;c++) a = fmaf(feat[c], W1t[j*32+c], a);
    a = fa(a, b1[j]);
    // native-HW stable softplus: v_exp_f32 + v_log_f32 (r9-verified)
    float h = fa(fmaxf(a,0.f), __logf(fa(1.f, __expf(-fabsf(a)))));
    const float* w2r = W2 + j*33 + KB;
#pragma unroll
    for(int k=0;k<17;k++) o[k] = fmaf(h, w2r[k], o[k]);
  }
#pragma unroll
  for(int k=0;k<17;k++) o[k] = fa(o[k], b2[KB+k]);

  float beta = fmaxf(sb[0], 0.002f);
  if (kh==0){
    float raw = o[0];
    out_psdf[((size_t)n<<18) + ((size_t)PHASE<<17) + (size_t)(ray&4095)*32 + s] = raw;  // unmasked
    float sg = fa(raw, tsdf);
    dens_out[pid] = msk ? fdv(sigm(fdv(-sg, beta)), beta) : 0.f;   // exact path (chaotic cdf chain)
  }

  // rgb head: thread kh writes channels [16kh,16kh+16) from o[1..16]
  // (kh=1: o[1..16] = k 17..32 = rgb c 16..31; its o[0] (k=16) is unused)
  u16 rv[16];
#pragma unroll
  for(int c=0;c<16;c++){
    float r = msk ? fs(fm(sigm_fast(o[c+1]), 1.002f), 0.001f) : 0.f;  // fast path, abs tol 5.6e-2
    rv[c]=f2b(r);
  }
  uint4* op = (uint4*)(rgb_out + (size_t)pid*32 + (KB));
#pragma unroll
  for(int q=0;q<2;q++){
    uint4 w;
    w.x = (u32)rv[q*8+0] | ((u32)rv[q*8+1]<<16);
    w.y = (u32)rv[q*8+2] | ((u32)rv[q*8+3]<<16);
    w.z = (u32)rv[q*8+4] | ((u32)rv[q*8+5]<<16);
    w.w = (u32)rv[q*8+6] | ((u32)rv[q*8+7]<<16);
    op[q]=w;
  }
}

// ---------------- coarse march + importance sampling (strict f32, thread per ray) ----------------
__global__ void __launch_bounds__(64) k_imp(
  const float* __restrict__ dc, const float* __restrict__ dens,
  const float* __restrict__ u_imp, float* __restrict__ df, float* __restrict__ scal)
{
  __shared__ float scdf[64][30];
  __shared__ float szm [64][30];
  int tid = threadIdx.x;
  int ray = blockIdx.x*64 + tid;   // 0..8191
  float w[31];
  float dprev = dc[ray*32+0];
  float sprev = dens[ray*32+0];
  float T = 1.f;
#pragma unroll
  for(int i=0;i<31;i++){
    float dn = dc[ray*32+i+1];
    float sn = dens[ray*32+i+1];
    if (i<30) szm[tid][i] = fm(0.5f, fa(dprev,dn));
    float delta = fs(dn,dprev);
    float dm = fm(0.5f, fa(sprev,sn));
    float al = fs(1.f, exf(-fm(dm,delta)));
    w[i] = fm(al,T);
    T = fm(T, fa(fs(1.f,al), 1e-10f));
    dprev=dn; sprev=sn;
  }
  // pdf weights: w_sm[j]=0.5*(m[j]+m[j+1])+0.01 (j=1..29), +EPS
  float pdfw[29];
#pragma unroll
  for(int i=0;i<29;i++){
    float m1 = fmaxf(w[i],w[i+1]), m2 = fmaxf(w[i+1],w[i+2]);
    pdfw[i] = fa(fa(fm(0.5f, fa(m1,m2)), 0.01f), 1e-5f);
  }
  // np.sum pairwise (n=29): 8 accumulators, 2 blocked adds, tree, 5 sequential tail
  float sum;
  {
    float r[8];
#pragma unroll
    for(int j=0;j<8;j++) r[j]=pdfw[j];
#pragma unroll
    for(int j=0;j<8;j++) r[j]=fa(r[j],pdfw[8+j]);
#pragma unroll
    for(int j=0;j<8;j++) r[j]=fa(r[j],pdfw[16+j]);
    sum = fa(fa(fa(r[0],r[1]),fa(r[2],r[3])), fa(fa(r[4],r[5]),fa(r[6],r[7])));
#pragma unroll
    for(int i=24;i<29;i++) sum = fa(sum, pdfw[i]);
  }
  // cdf: sequential cumsum of pdf (per-element f32 division)
  {
    float cacc = 0.f;
    scdf[tid][0] = 0.f;
#pragma unroll
    for(int i=1;i<30;i++){
      cacc = fa(cacc, fdv(pdfw[i-1], sum));
      scdf[tid][i] = cacc;
    }
  }

  float fmn=1e30f, fmx=-1e30f;
  for(int k=0;k<32;k++){
    float u = u_imp[ray*32+k];
    // np.searchsorted(cdf, u, 'right') = bisect_right (binary, regardless of monotonicity)
    int lo=0, hi=30;
    while(lo<hi){
      int mid=(lo+hi)>>1;
      if (scdf[tid][mid] <= u) lo = mid+1; else hi = mid;
    }
    int ind = lo;                 // in [1,30]
    int below = ind-1;            // in [0,29]
    int above = (ind>29)?29:ind;  // in [0,29]
    float cdf0 = scdf[tid][below];
    float cdf1 = scdf[tid][above];
    float b0   = szm [tid][below];
    float b1v  = szm [tid][above];
    float den = fs(cdf1,cdf0);
    if((double)den < 1e-5) den = 1.f;      // EPS compare in f64 (python const)
    float sres = fa(b0, fm(fdv(fs(u,cdf0),den), fs(b1v,b0)));
    df[ray*32+k]=sres;
    fmn=fminf(fmn,sres); fmx=fmaxf(fmx,sres);
  }
#pragma unroll
  for(int m=1;m<64;m<<=1){ fmn=fminf(fmn,__shfl_xor(fmn,m)); fmx=fmaxf(fmx,__shfl_xor(fmx,m)); }
  if(tid==0){
    atomicMin(((u32*)scal)+2, fenc(fmn));
    atomicMax(((u32*)scal)+3, fenc(fmx));
  }
}

// ---------------- stable sort (64) + final ray march, strict f32 (wave per ray) ----------------
__global__ void __launch_bounds__(256) k_final(
  const float* __restrict__ dc, const float* __restrict__ df,
  const float* __restrict__ densc, const float* __restrict__ densf,
  const u16* __restrict__ rgbc, const u16* __restrict__ rgbf,
  const float* __restrict__ scal,
  float* __restrict__ out_rgb, float* __restrict__ out_depth, float* __restrict__ out_w)
{
  __shared__ float ssd[4][64];
  __shared__ float ssn[4][64];
  __shared__ int   sp [4][64];
  __shared__ float swv[4][64];   // per-interval weight
  __shared__ float swz[4][64];   // per-interval weight*z_mid
  int wid = threadIdx.x>>6, lane = threadIdx.x&63;
  int ray = blockIdx.x*4 + wid;

  float myd = (lane<32)? dc[ray*32+lane]    : df[ray*32+lane-32];
  float myn = (lane<32)? densc[ray*32+lane] : densf[ray*32+lane-32];
  ssd[wid][lane]=myd; __syncthreads();
  int rk=0;
#pragma unroll 8
  for(int j=0;j<64;j++){
    float dj = ssd[wid][j];
    rk += (dj<myd || (dj==myd && j<lane)) ? 1:0;     // stable argsort rank
  }
  __syncthreads();
  ssd[wid][rk]=myd; ssn[wid][rk]=myn; sp[wid][rk]=lane;
  __syncthreads();

  float T=1.f, accr=0.f;
  int j0 = sp[wid][0];
  float cprev = 0.f;
  if (lane<32){
    const u16* cb = (j0<32)? (rgbc+((size_t)ray*32+j0)*32) : (rgbf+((size_t)ray*32+(j0-32))*32);
    cprev = __uint_as_float(((u32)cb[lane])<<16);
  }
  float d0 = ssd[wid][0], n0 = ssn[wid][0];
  for(int s2=0;s2<63;s2++){
    float d1 = ssd[wid][s2+1], n1 = ssn[wid][s2+1];
    float delta = fs(d1,d0);
    float dm = fm(0.5f, fa(n0,n1));
    float al = fs(1.f, exf(-fm(dm,delta)));
    float wv = fm(al,T);
    T = fm(T, fa(fs(1.f,al), 1e-10f));
    if (lane==s2){ swv[wid][s2]=wv; swz[wid][s2]=fm(wv, fm(0.5f, fa(d0,d1))); }
    int j1 = sp[wid][s2+1];
    float cnext = 0.f;
    if (lane<32){
      const u16* cb = (j1<32)? (rgbc+((size_t)ray*32+j1)*32) : (rgbf+((size_t)ray*32+(j1-32))*32);
      cnext = __uint_as_float(((u32)cb[lane])<<16);
    }
    // comp_rgb: strided axis-2 reduce -> SEQUENTIAL accumulation (numpy)
    accr = fa(accr, fm(wv, fm(0.5f, fa(cprev,cnext))));
    cprev=cnext; d0=d1; n0=n1;
  }
  __syncthreads();
  if(lane<63) out_w[(size_t)ray*63+lane]=swv[wid][lane];
  if(lane<32) out_rgb[(size_t)ray*32+lane]=fs(fm(accr,2.f),1.f);
  if(lane==0){
    // np.sum pairwise (n=63, contiguous): r[j]=sum_k a[8k+j] k=0..6; tree; tail 56..62
    float wsum, zsum;
    {
      float r[8], rz[8];
#pragma unroll
      for(int j=0;j<8;j++){ r[j]=swv[wid][j]; rz[j]=swz[wid][j]; }
      for(int i=8;i<56;i+=8)
#pragma unroll
        for(int j=0;j<8;j++){ r[j]=fa(r[j],swv[wid][i+j]); rz[j]=fa(rz[j],swz[wid][i+j]); }
      wsum = fa(fa(fa(r[0],r[1]),fa(r[2],r[3])), fa(fa(r[4],r[5]),fa(r[6],r[7])));
      zsum = fa(fa(fa(rz[0],rz[1]),fa(rz[2],rz[3])), fa(fa(rz[4],rz[5]),fa(rz[6],rz[7])));
      for(int i=56;i<63;i++){ wsum=fa(wsum,swv[wid][i]); zsum=fa(zsum,swz[wid][i]); }
    }
    float depv = fdv(zsum, wsum);
    if (isnan(depv)) depv = INFINITY;    // nan_to_num(nan=inf)
    float lo = fdec(((const u32*)scal)[2]);
    float hi = fdec(((const u32*)scal)[3]);
    depv = fminf(fmaxf(depv,lo),hi);     // clip to global all_d min/max
    out_depth[ray]=depv;
  }
}

extern "C" void kernel_launch(void* const* d_in, const int* in_sizes, int n_in,
                              void* d_out, int out_size, void* d_ws, size_t ws_size,
                              hipStream_t stream) {
  const float* planes = (const float*)d_in[0];
  const float* ro     = (const float*)d_in[1];
  const float* rdp    = (const float*)d_in[2];
  const float* hmin   = (const float*)d_in[3];
  const float* hmax   = (const float*)d_in[4];
  const float* jitter = (const float*)d_in[5];
  const float* uimp   = (const float*)d_in[6];
  const float* W1     = (const float*)d_in[7];
  const float* b1     = (const float*)d_in[8];
  const float* W2     = (const float*)d_in[9];
  const float* b2     = (const float*)d_in[10];
  const float* sb     = (const float*)d_in[11];
  const int*   hmk    = (const int*)d_in[12];
  float* out = (float*)d_out;
  char* ws = (char*)d_ws;

  size_t off=0;
  auto alloc=[&](size_t bytes){ size_t o=off; off=(off+bytes+255)&~(size_t)255; return o; };
  float* scal = (float*)(ws+alloc(64));
  float* W1t  = (float*)(ws+alloc(2048*4));
  float* pt   = (float*)(ws+alloc((size_t)12582912*4));
  float* dco  = (float*)(ws+alloc((size_t)NSAMP*4));
  float* dfi  = (float*)(ws+alloc((size_t)NSAMP*4));
  float* dnc  = (float*)(ws+alloc((size_t)NSAMP*4));
  float* dnf  = (float*)(ws+alloc((size_t)NSAMP*4));
  u16*   rgc  = (u16*)  (ws+alloc((size_t)NSAMP*32*2));
  u16*   rgf  = (u16*)  (ws+alloc((size_t)NSAMP*32*2));
  (void)in_sizes; (void)n_in; (void)out_size; (void)ws_size;

  float* out_rgb  = out;
  float* out_dep  = out + 262144;
  float* out_w    = out + 270336;
  float* out_psdf = out + 786432;

  k_init<<<dim3(1),dim3(256),0,stream>>>(hmin,hmax,W1,scal,W1t);
  k_tr<<<dim3(12288),dim3(256),0,stream>>>(planes, pt);
  k_eval<0><<<dim3(2048),dim3(256),0,stream>>>(pt,ro,rdp,hmin,hmax,jitter,hmk,W1t,b1,W2,b2,sb,scal,dco,dnc,rgc,out_psdf);
  k_imp<<<dim3(128),dim3(64),0,stream>>>(dco,dnc,uimp,dfi,scal);
  k_eval<1><<<dim3(2048),dim3(256),0,stream>>>(pt,ro,rdp,hmin,hmax,jitter,hmk,W1t,b1,W2,b2,sb,scal,dfi,dnf,rgf,out_psdf);
  k_final<<<dim3(2048),dim3(256),0,stream>>>(dco,dfi,dnc,dnf,rgc,rgf,scal,out_rgb,out_dep,out_w);
}

// Round 14
// 569.427 us; speedup vs baseline: 1.7838x; 1.1430x over previous
//
#include <hip/hip_runtime.h>
#include <hip/hip_bf16.h>
#include <math.h>
#include <stddef.h>

typedef unsigned int u32;
typedef unsigned short u16;
typedef unsigned long long u64;

#define NRAYS 8192      // N_BATCH * N_RAYS
#define NSAMP 262144    // NRAYS * 32

// ---- strict float32 ops (block FMA contraction, numpy-per-op rounding) ----
__device__ __forceinline__ float fa(float a,float b){ return __fadd_rn(a,b); }
__device__ __forceinline__ float fs(float a,float b){ return __fsub_rn(a,b); }
__device__ __forceinline__ float fm(float a,float b){ return __fmul_rn(a,b); }
__device__ __forceinline__ float fdv(float a,float b){ return __fdiv_rn(a,b); }

// ---- fast double exp: |rel err| < ~2^-45, branch-light (march + density path) ----
__device__ __forceinline__ double exp_d(double x){
  const double LOG2E  = 1.4426950408889634074;
  const double LN2_HI = 6.93147180369123816490e-01;
  const double LN2_LO = 1.90821492927058770002e-10;
  double kd = rint(x * LOG2E);
  if (kd >  200.0) return INFINITY;
  if (kd < -200.0) return 0.0;
  int k = (int)kd;
  double r = fma(-kd, LN2_HI, x);
  r = fma(-kd, LN2_LO, r);
  double p = 1.0/39916800.0;
  p = fma(p, r, 1.0/3628800.0);
  p = fma(p, r, 1.0/362880.0);
  p = fma(p, r, 1.0/40320.0);
  p = fma(p, r, 1.0/5040.0);
  p = fma(p, r, 1.0/720.0);
  p = fma(p, r, 1.0/120.0);
  p = fma(p, r, 1.0/24.0);
  p = fma(p, r, 1.0/6.0);
  p = fma(p, r, 0.5);
  p = fma(p, r, 1.0);
  p = fma(p, r, 1.0);
  u64 sb = ((u64)(k + 1023)) << 52;
  return p * __longlong_as_double((long long)sb);
}
__device__ __forceinline__ float exf(float x){ return (float)exp_d((double)x); }
__device__ __forceinline__ float sigm(float x){   // exact-path stepwise f32 sigmoid (density head)
  if (x >= 0.f){ float e = exf(-x); return fdv(1.f, fa(1.f, e)); }
  float e = exf(x); return fdv(e, fa(1.f, e));
}
// fast sigmoid for the rgb head only (abs tolerance 5.6e-2; bf16-quantized anyway)
__device__ __forceinline__ float sigm_fast(float x){
  return 1.f/(1.f + __expf(-x));
}
__device__ __forceinline__ u16 f2b(float f){
  u32 x = __float_as_uint(f);
  return (u16)((x + 0x7fffu + ((x>>16)&1u)) >> 16);   // RNE
}
// monotone float<->u32 key (handles negatives) for atomic min/max
__device__ __forceinline__ u32 fenc(float f){ u32 b=__float_as_uint(f); return (b&0x80000000u)? ~b : (b|0x80000000u); }
__device__ __forceinline__ float fdec(u32 k){ u32 b=(k&0x80000000u)? (k^0x80000000u) : ~k; return __uint_as_float(b); }

// ---------------- init: global min/max of hit depths, scalar slots, W1 transpose ----------------
__global__ void k_init(const float* __restrict__ hmin, const float* __restrict__ hmax,
                       const float* __restrict__ W1, float* __restrict__ scal,
                       float* __restrict__ W1t){
  __shared__ float smn[256], smx[256];
  int t = threadIdx.x;
  float mn = 1e30f, mx = -1e30f;
  for (int i=t;i<NRAYS;i+=256){ mn=fminf(mn,hmin[i]); mx=fmaxf(mx,hmax[i]); }
  smn[t]=mn; smx[t]=mx; __syncthreads();
  for(int s=128;s>0;s>>=1){
    if(t<s){ smn[t]=fminf(smn[t],smn[t+s]); smx[t]=fmaxf(smx[t],smx[t+s]); }
    __syncthreads();
  }
  if(t==0){
    scal[0]=smn[0]; scal[1]=smx[0];
    ((u32*)scal)[2]=0xFFFFFFFFu;  // dmin key (atomicMin on monotone key)
    ((u32*)scal)[3]=0u;           // dmax key (atomicMax)
  }
  for(int i=t;i<2048;i+=256){ int j=i>>5, c=i&31; W1t[i]=W1[c*64+j]; }  // W1t[j*32+c]
}

// ---------------- direction-Morton ray sort (locality permutation; pure reorder) ----------------
__device__ __forceinline__ u32 part3(u32 v){   // spread 10 bits to every 3rd bit
  v &= 0x3FFu;
  v = (v | (v<<16)) & 0x30000FFu;
  v = (v | (v<<8))  & 0x300F00Fu;
  v = (v | (v<<4))  & 0x30C30C3u;
  v = (v | (v<<2))  & 0x9249249u;
  return v;
}
__global__ void __launch_bounds__(1024) k_sort(const float* __restrict__ rd, u32* __restrict__ perm){
  __shared__ u64 buf[NRAYS];
  int t = threadIdx.x;
  for (int i=t;i<NRAYS;i+=1024){
    float x = rd[i*3+0], y = rd[i*3+1], z = rd[i*3+2];
    u32 kx = (u32)fminf(fmaxf((x+1.f)*511.5f,0.f),1023.f);
    u32 ky = (u32)fminf(fmaxf((y+1.f)*511.5f,0.f),1023.f);
    u32 kz = (u32)fminf(fmaxf((z+1.f)*511.5f,0.f),1023.f);
    u32 m = (part3(kx)<<2) | (part3(ky)<<1) | part3(kz);   // 30 bits
    u32 key = ((u32)(i>>12)<<30) | m;   // batch id on top: keep n=0 / n=1 separate
    buf[i] = ((u64)key<<32) | (u32)i;
  }
  __syncthreads();
  // bitonic sort, deterministic (ray id in low bits breaks ties -> total order)
  for (int k=2;k<=NRAYS;k<<=1){
    for (int j=k>>1;j>0;j>>=1){
      for (int i=t;i<NRAYS;i+=1024){
        int ixj = i ^ j;
        if (ixj > i){
          u64 a = buf[i], b = buf[ixj];
          bool up = ((i & k) == 0);
          if ((up && a > b) || (!up && a < b)){ buf[i]=b; buf[ixj]=a; }
        }
      }
      __syncthreads();
    }
  }
  for (int i=t;i<NRAYS;i+=1024) perm[i] = (u32)(buf[i] & 0xFFFFFFFFu);
}

// ---------------- transpose planes (N,3,C,H,W) f32 -> (N*3,H,W,C) f32 ----------------
__global__ void __launch_bounds__(256) k_tr(const float* __restrict__ pl, float* __restrict__ pt){
  int t = blockIdx.x*256 + threadIdx.x;     // 0 .. 3145727
  int x  = t & 255;
  int c4 = ((t>>8)&7)<<2;
  int y  = (t>>11)&255;
  int np = t>>19;                            // 0..5
  const float* ip = pl + (((size_t)(np*32+c4))<<16) + (y<<8) + x;
  float4 o;
  o.x = ip[0];
  o.y = ip[65536];
  o.z = ip[131072];
  o.w = ip[196608];
  *reinterpret_cast<float4*>(pt + ((((size_t)(np<<8|y))<<8|x)<<5) + c4) = o;
}

// ---------------- point evaluation (sampling + decoder), strict f32 ----------------
// r9-verified 202us shape (1 thread/point, VGPR 56, no spill) + ray permutation:
// this thread processes SORTED ray slot rayp -> original ray perm[rayp]. All
// input/output arrays indexed by ORIGINAL ray id -> results bit-identical to r9;
// only the wave->texel access pattern changes (direction-coherent -> L2 reuse).
template<int PHASE>
__global__ void __launch_bounds__(256) k_eval(
  const float* __restrict__ pt, const float* __restrict__ ro, const float* __restrict__ rd,
  const float* __restrict__ hmin, const float* __restrict__ hmax,
  const float* __restrict__ jitter, const int* __restrict__ hitmask,
  const u32* __restrict__ perm,
  const float* __restrict__ W1t, const float* __restrict__ b1,
  const float* __restrict__ W2, const float* __restrict__ b2,
  const float* __restrict__ sb, float* __restrict__ scal,
  float* __restrict__ dep, float* __restrict__ dens_out, u16* __restrict__ rgb_out,
  float* __restrict__ out_psdf)
{
  // XCD-aware bijective chunk swizzle (nwg=1024, 1024%8==0): XCD x gets a
  // contiguous 128-block chunk of the sorted ray order -> per-XCD L2 locality.
  int bid = blockIdx.x;
  int swz = (bid & 7)*128 + (bid >> 3);
  int pidl = swz*256 + threadIdx.x;          // position in SORTED order
  int rayp = pidl >> 5;
  int s    = pidl & 31;
  int ray  = (int)perm[rayp];                // original ray id
  int pid  = (ray<<5) | s;                   // original point id (all I/O)
  int n    = ray >> 12;
  int msk  = hitmask[ray];

  float d;
  if (PHASE==0){
    float hmn = msk ? hmin[ray] : scal[0];
    float hmx = msk ? hmax[ray] : scal[1];
    float span = fs(hmx, hmn);
    float jit  = jitter[pid];
    float base = (float)((double)s * (1.0/31.0));   // np.linspace f64 arange*step -> f32 cast
    if (s==31) base = 1.0f;
    float t1 = fdv(fm(jit, span), 32.0f);
    d = fa(fm(fa(base, t1), span), hmn);
    dep[pid] = d;
    float dm=d, dM=d;   // wave reduce; lane->ray mapping irrelevant for global min/max
#pragma unroll
    for (int m=1;m<64;m<<=1){ dm=fminf(dm,__shfl_xor(dm,m)); dM=fmaxf(dM,__shfl_xor(dM,m)); }
    if ((threadIdx.x & 63)==0){
      atomicMin(((u32*)scal)+2, fenc(dm));
      atomicMax(((u32*)scal)+3, fenc(dM));
    }
  } else {
    d = dep[pid];
  }

  float ox=ro[ray*3+0], oy=ro[ray*3+1], oz=ro[ray*3+2];
  float dx=rd[ray*3+0], dy=rd[ray*3+1], dz=rd[ray*3+2];
  float px = fa(ox, fm(d,dx)), py = fa(oy, fm(d,dy)), pz = fa(oz, fm(d,dz));
  float nrm = __fsqrt_rn(fa(fa(fm(px,px),fm(py,py)),fm(pz,pz)));
  float tsdf = fs(nrm, 0.5f);
  const float sc2 = (float)(2.0/6.0);
  float cx=fm(px,sc2), cy=fm(py,sc2), cz=fm(pz,sc2);

  float feat[32];
#pragma unroll
  for(int c=0;c<32;c++) feat[c]=0.f;

#pragma unroll
  for (int p=0;p<3;p++){
    float u = (p==2)?cz:cx;                  // plane0:(x,y) plane1:(x,z) plane2:(z,y)
    float v = (p==1)?cz:cy;
    float fx = fs(fm(fa(u,1.f),128.f),0.5f); // (u+1)*128-0.5 per-op
    float fy = fs(fm(fa(v,1.f),128.f),0.5f);
    float x0f = floorf(fx), y0f = floorf(fy);
    float wx = fs(fx,x0f), wy = fs(fy,y0f);
    float ax0 = fs(1.f,wx), ax1 = wx, ay0 = fs(1.f,wy), ay1 = wy;
    int x0, y0;
    { // saturating cast (wild coords can exceed int range semantics; floor first)
      x0 = (x0f >= 2.1e9f) ? 2147483647 : ((x0f <= -2.1e9f) ? (-2147483647-1) : (int)x0f);
      y0 = (y0f >= 2.1e9f) ? 2147483647 : ((y0f <= -2.1e9f) ? (-2147483647-1) : (int)y0f);
    }
    int x1=x0+1, y1=y0+1;
    bool vx0 = (x0>=0 && x0<256), vx1 = (x1>=0 && x1<256);
    bool vy0 = (y0>=0 && y0<256), vy1 = (y1>=0 && y1<256);
    bool ok00 = vx0&&vy0, ok01 = vx1&&vy0, ok10 = vx0&&vy1, ok11 = vx1&&vy1;
    int cx0=min(max(x0,0),255), cx1=min(max(x1,0),255);
    int cy0=min(max(y0,0),255), cy1=min(max(y1,0),255);
    int npl = n*3+p;
    size_t pb = ((size_t)npl)<<16;
    const float4* t00 = (const float4*)(pt + ((pb + (cy0<<8) + cx0)<<5));
    const float4* t01 = (const float4*)(pt + ((pb + (cy0<<8) + cx1)<<5));
    const float4* t10 = (const float4*)(pt + ((pb + (cy1<<8) + cx0)<<5));
    const float4* t11 = (const float4*)(pt + ((pb + (cy1<<8) + cx1)<<5));
#pragma unroll
    for(int q=0;q<8;q++){
      float4 v00 = t00[q], v01 = t01[q], v10 = t10[q], v11 = t11[q];
      float e0,e1,e2,e3, t_;
#define CORNER_SUM(FLD, OUTI) \
      e0 = ok00 ? v00.FLD : 0.f; e1 = ok01 ? v01.FLD : 0.f; \
      e2 = ok10 ? v10.FLD : 0.f; e3 = ok11 ? v11.FLD : 0.f; \
      t_ = fa(fa(fa(fm(fm(e0,ax0),ay0), fm(fm(e1,ax1),ay0)), fm(fm(e2,ax0),ay1)), fm(fm(e3,ax1),ay1)); \
      feat[q*4+OUTI] = fa(feat[q*4+OUTI], t_);
      CORNER_SUM(x,0) CORNER_SUM(y,1) CORNER_SUM(z,2) CORNER_SUM(w,3)
#undef CORNER_SUM
    }
  }
#pragma unroll
  for(int c=0;c<32;c++) feat[c] = fdv(feat[c], 3.0f);   // np.mean: (f0+f1)+f2 then /3

  // decoder: h = softplus(feat@W1+b1); o = h@W2+b2 (sequential chain = r5/r6/r9-verified order)
  float o[33];
#pragma unroll
  for(int k=0;k<33;k++) o[k]=0.f;
#pragma unroll 2
  for(int j=0;j<64;j++){
    float a = 0.f;
#pragma unroll
    for(int c=0;c<32;c++) a = fmaf(feat[c], W1t[j*32+c], a);
    a = fa(a, b1[j]);
    // native-HW stable softplus: v_exp_f32 + v_log_f32 (r9-verified)
    float h = fa(fmaxf(a,0.f), __logf(fa(1.f, __expf(-fabsf(a)))));
#pragma unroll
    for(int k=0;k<33;k++) o[k] = fmaf(h, W2[j*33+k], o[k]);
  }
#pragma unroll
  for(int k=0;k<33;k++) o[k] = fa(o[k], b2[k]);

  float beta = fmaxf(sb[0], 0.002f);
  float raw = o[0];
  out_psdf[((size_t)n<<18) + ((size_t)PHASE<<17) + (size_t)(ray&4095)*32 + s] = raw;  // unmasked
  float sg = fa(raw, tsdf);
  float dens = msk ? fdv(sigm(fdv(-sg, beta)), beta) : 0.f;   // exact path (chaotic cdf chain)
  dens_out[pid]=dens;

  u16 rv[32];
#pragma unroll
  for(int c=0;c<32;c++){
    float r = msk ? fs(fm(sigm_fast(o[c+1]), 1.002f), 0.001f) : 0.f;  // fast path, abs tol 5.6e-2
    rv[c]=f2b(r);
  }
  uint4* op = (uint4*)(rgb_out + (size_t)pid*32);
#pragma unroll
  for(int q=0;q<4;q++){
    uint4 w;
    w.x = (u32)rv[q*8+0] | ((u32)rv[q*8+1]<<16);
    w.y = (u32)rv[q*8+2] | ((u32)rv[q*8+3]<<16);
    w.z = (u32)rv[q*8+4] | ((u32)rv[q*8+5]<<16);
    w.w = (u32)rv[q*8+6] | ((u32)rv[q*8+7]<<16);
    op[q]=w;
  }
}

// ---------------- coarse march + importance sampling (strict f32, thread per ray) ----------------
__global__ void __launch_bounds__(64) k_imp(
  const float* __restrict__ dc, const float* __restrict__ dens,
  const float* __restrict__ u_imp, float* __restrict__ df, float* __restrict__ scal)
{
  __shared__ float scdf[64][30];
  __shared__ float szm [64][30];
  int tid = threadIdx.x;
  int ray = blockIdx.x*64 + tid;   // 0..8191
  float w[31];
  float dprev = dc[ray*32+0];
  float sprev = dens[ray*32+0];
  float T = 1.f;
#pragma unroll
  for(int i=0;i<31;i++){
    float dn = dc[ray*32+i+1];
    float sn = dens[ray*32+i+1];
    if (i<30) szm[tid][i] = fm(0.5f, fa(dprev,dn));
    float delta = fs(dn,dprev);
    float dm = fm(0.5f, fa(sprev,sn));
    float al = fs(1.f, exf(-fm(dm,delta)));
    w[i] = fm(al,T);
    T = fm(T, fa(fs(1.f,al), 1e-10f));
    dprev=dn; sprev=sn;
  }
  // pdf weights: w_sm[j]=0.5*(m[j]+m[j+1])+0.01 (j=1..29), +EPS
  float pdfw[29];
#pragma unroll
  for(int i=0;i<29;i++){
    float m1 = fmaxf(w[i],w[i+1]), m2 = fmaxf(w[i+1],w[i+2]);
    pdfw[i] = fa(fa(fm(0.5f, fa(m1,m2)), 0.01f), 1e-5f);
  }
  // np.sum pairwise (n=29): 8 accumulators, 2 blocked adds, tree, 5 sequential tail
  float sum;
  {
    float r[8];
#pragma unroll
    for(int j=0;j<8;j++) r[j]=pdfw[j];
#pragma unroll
    for(int j=0;j<8;j++) r[j]=fa(r[j],pdfw[8+j]);
#pragma unroll
    for(int j=0;j<8;j++) r[j]=fa(r[j],pdfw[16+j]);
    sum = fa(fa(fa(r[0],r[1]),fa(r[2],r[3])), fa(fa(r[4],r[5]),fa(r[6],r[7])));
#pragma unroll
    for(int i=24;i<29;i++) sum = fa(sum, pdfw[i]);
  }
  // cdf: sequential cumsum of pdf (per-element f32 division)
  {
    float cacc = 0.f;
    scdf[tid][0] = 0.f;
#pragma unroll
    for(int i=1;i<30;i++){
      cacc = fa(cacc, fdv(pdfw[i-1], sum));
      scdf[tid][i] = cacc;
    }
  }

  float fmn=1e30f, fmx=-1e30f;
  for(int k=0;k<32;k++){
    float u = u_imp[ray*32+k];
    // np.searchsorted(cdf, u, 'right') = bisect_right (binary, regardless of monotonicity)
    int lo=0, hi=30;
    while(lo<hi){
      int mid=(lo+hi)>>1;
      if (scdf[tid][mid] <= u) lo = mid+1; else hi = mid;
    }
    int ind = lo;                 // in [1,30]
    int below = ind-1;            // in [0,29]
    int above = (ind>29)?29:ind;  // in [0,29]
    float cdf0 = scdf[tid][below];
    float cdf1 = scdf[tid][above];
    float b0   = szm [tid][below];
    float b1v  = szm [tid][above];
    float den = fs(cdf1,cdf0);
    if((double)den < 1e-5) den = 1.f;      // EPS compare in f64 (python const)
    float sres = fa(b0, fm(fdv(fs(u,cdf0),den), fs(b1v,b0)));
    df[ray*32+k]=sres;
    fmn=fminf(fmn,sres); fmx=fmaxf(fmx,sres);
  }
#pragma unroll
  for(int m=1;m<64;m<<=1){ fmn=fminf(fmn,__shfl_xor(fmn,m)); fmx=fmaxf(fmx,__shfl_xor(fmx,m)); }
  if(tid==0){
    atomicMin(((u32*)scal)+2, fenc(fmn));
    atomicMax(((u32*)scal)+3, fenc(fmx));
  }
}

// ---------------- stable sort (64) + final ray march, strict f32 (wave per ray) ----------------
__global__ void __launch_bounds__(256) k_final(
  const float* __restrict__ dc, const float* __restrict__ df,
  const float* __restrict__ densc, const float* __restrict__ densf,
  const u16* __restrict__ rgbc, const u16* __restrict__ rgbf,
  const float* __restrict__ scal,
  float* __restrict__ out_rgb, float* __restrict__ out_depth, float* __restrict__ out_w)
{
  __shared__ float ssd[4][64];
  __shared__ float ssn[4][64];
  __shared__ int   sp [4][64];
  __shared__ float swv[4][64];   // per-interval weight
  __shared__ float swz2[4][64];  // per-interval weight*z_mid
  int wid = threadIdx.x>>6, lane = threadIdx.x&63;
  int ray = blockIdx.x*4 + wid;

  float myd = (lane<32)? dc[ray*32+lane]    : df[ray*32+lane-32];
  float myn = (lane<32)? densc[ray*32+lane] : densf[ray*32+lane-32];
  ssd[wid][lane]=myd; __syncthreads();
  int rk=0;
#pragma unroll 8
  for(int j=0;j<64;j++){
    float dj = ssd[wid][j];
    rk += (dj<myd || (dj==myd && j<lane)) ? 1:0;     // stable argsort rank
  }
  __syncthreads();
  ssd[wid][rk]=myd; ssn[wid][rk]=myn; sp[wid][rk]=lane;
  __syncthreads();

  float T=1.f, accr=0.f;
  int j0 = sp[wid][0];
  float cprev = 0.f;
  if (lane<32){
    const u16* cb = (j0<32)? (rgbc+((size_t)ray*32+j0)*32) : (rgbf+((size_t)ray*32+(j0-32))*32);
    cprev = __uint_as_float(((u32)cb[lane])<<16);
  }
  float d0 = ssd[wid][0], n0 = ssn[wid][0];
  for(int s2=0;s2<63;s2++){
    float d1 = ssd[wid][s2+1], n1 = ssn[wid][s2+1];
    float delta = fs(d1,d0);
    float dm = fm(0.5f, fa(n0,n1));
    float al = fs(1.f, exf(-fm(dm,delta)));
    float wv = fm(al,T);
    T = fm(T, fa(fs(1.f,al), 1e-10f));
    if (lane==s2){ swv[wid][s2]=wv; swz2[wid][s2]=fm(wv, fm(0.5f, fa(d0,d1))); }
    int j1 = sp[wid][s2+1];
    float cnext = 0.f;
    if (lane<32){
      const u16* cb = (j1<32)? (rgbc+((size_t)ray*32+j1)*32) : (rgbf+((size_t)ray*32+(j1-32))*32);
      cnext = __uint_as_float(((u32)cb[lane])<<16);
    }
    // comp_rgb: strided axis-2 reduce -> SEQUENTIAL accumulation (numpy)
    accr = fa(accr, fm(wv, fm(0.5f, fa(cprev,cnext))));
    cprev=cnext; d0=d1; n0=n1;
  }
  __syncthreads();
  if(lane<63) out_w[(size_t)ray*63+lane]=swv[wid][lane];
  if(lane<32) out_rgb[(size_t)ray*32+lane]=fs(fm(accr,2.f),1.f);
  if(lane==0){
    // np.sum pairwise (n=63, contiguous): r[j]=sum_k a[8k+j] k=0..6; tree; tail 56..62
    float wsum, zsum;
    {
      float r[8], rz[8];
#pragma unroll
      for(int j=0;j<8;j++){ r[j]=swv[wid][j]; rz[j]=swz2[wid][j]; }
      for(int i=8;i<56;i+=8)
#pragma unroll
        for(int j=0;j<8;j++){ r[j]=fa(r[j],swv[wid][i+j]); rz[j]=fa(rz[j],swz2[wid][i+j]); }
      wsum = fa(fa(fa(r[0],r[1]),fa(r[2],r[3])), fa(fa(r[4],r[5]),fa(r[6],r[7])));
      zsum = fa(fa(fa(rz[0],rz[1]),fa(rz[2],rz[3])), fa(fa(rz[4],rz[5]),fa(rz[6],rz[7])));
      for(int i=56;i<63;i++){ wsum=fa(wsum,swv[wid][i]); zsum=fa(zsum,swz2[wid][i]); }
    }
    float depv = fdv(zsum, wsum);
    if (isnan(depv)) depv = INFINITY;    // nan_to_num(nan=inf)
    float lo = fdec(((const u32*)scal)[2]);
    float hi = fdec(((const u32*)scal)[3]);
    depv = fminf(fmaxf(depv,lo),hi);     // clip to global all_d min/max
    out_depth[ray]=depv;
  }
}

extern "C" void kernel_launch(void* const* d_in, const int* in_sizes, int n_in,
                              void* d_out, int out_size, void* d_ws, size_t ws_size,
                              hipStream_t stream) {
  const float* planes = (const float*)d_in[0];
  const float* ro     = (const float*)d_in[1];
  const float* rdp    = (const float*)d_in[2];
  const float* hmin   = (const float*)d_in[3];
  const float* hmax   = (const float*)d_in[4];
  const float* jitter = (const float*)d_in[5];
  const float* uimp   = (const float*)d_in[6];
  const float* W1     = (const float*)d_in[7];
  const float* b1     = (const float*)d_in[8];
  const float* W2     = (const float*)d_in[9];
  const float* b2     = (const float*)d_in[10];
  const float* sb     = (const float*)d_in[11];
  const int*   hmk    = (const int*)d_in[12];
  float* out = (float*)d_out;
  char* ws = (char*)d_ws;

  size_t off=0;
  auto alloc=[&](size_t bytes){ size_t o=off; off=(off+bytes+255)&~(size_t)255; return o; };
  float* scal = (float*)(ws+alloc(64));
  float* W1t  = (float*)(ws+alloc(2048*4));
  u32*   perm = (u32*)  (ws+alloc(NRAYS*4));
  float* pt   = (float*)(ws+alloc((size_t)12582912*4));
  float* dco  = (float*)(ws+alloc((size_t)NSAMP*4));
  float* dfi  = (float*)(ws+alloc((size_t)NSAMP*4));
  float* dnc  = (float*)(ws+alloc((size_t)NSAMP*4));
  float* dnf  = (float*)(ws+alloc((size_t)NSAMP*4));
  u16*   rgc  = (u16*)  (ws+alloc((size_t)NSAMP*32*2));
  u16*   rgf  = (u16*)  (ws+alloc((size_t)NSAMP*32*2));
  (void)in_sizes; (void)n_in; (void)out_size; (void)ws_size;

  float* out_rgb  = out;
  float* out_dep  = out + 262144;
  float* out_w    = out + 270336;
  float* out_psdf = out + 786432;

  k_init<<<dim3(1),dim3(256),0,stream>>>(hmin,hmax,W1,scal,W1t);
  k_sort<<<dim3(1),dim3(1024),0,stream>>>(rdp, perm);
  k_tr<<<dim3(12288),dim3(256),0,stream>>>(planes, pt);
  k_eval<0><<<dim3(1024),dim3(256),0,stream>>>(pt,ro,rdp,hmin,hmax,jitter,hmk,perm,W1t,b1,W2,b2,sb,scal,dco,dnc,rgc,out_psdf);
  k_imp<<<dim3(128),dim3(64),0,stream>>>(dco,dnc,uimp,dfi,scal);
  k_eval<1><<<dim3(1024),dim3(256),0,stream>>>(pt,ro,rdp,hmin,hmax,jitter,hmk,perm,W1t,b1,W2,b2,sb,scal,dfi,dnf,rgf,out_psdf);
  k_final<<<dim3(2048),dim3(256),0,stream>>>(dco,dfi,dnc,dnf,rgc,rgf,scal,out_rgb,out_dep,out_w);
}

// Round 15
// 467.463 us; speedup vs baseline: 2.1729x; 1.2181x over previous
//
#include <hip/hip_runtime.h>
#include <hip/hip_bf16.h>
#include <math.h>
#include <stddef.h>

typedef unsigned int u32;
typedef unsigned short u16;
typedef unsigned long long u64;

#define NRAYS 8192      // N_BATCH * N_RAYS
#define NSAMP 262144    // NRAYS * 32

// ---- strict float32 ops (block FMA contraction, numpy-per-op rounding) ----
__device__ __forceinline__ float fa(float a,float b){ return __fadd_rn(a,b); }
__device__ __forceinline__ float fs(float a,float b){ return __fsub_rn(a,b); }
__device__ __forceinline__ float fm(float a,float b){ return __fmul_rn(a,b); }
__device__ __forceinline__ float fdv(float a,float b){ return __fdiv_rn(a,b); }

// ---- fast double exp: |rel err| < ~2^-45, branch-light (march + density path) ----
__device__ __forceinline__ double exp_d(double x){
  const double LOG2E  = 1.4426950408889634074;
  const double LN2_HI = 6.93147180369123816490e-01;
  const double LN2_LO = 1.90821492927058770002e-10;
  double kd = rint(x * LOG2E);
  if (kd >  200.0) return INFINITY;
  if (kd < -200.0) return 0.0;
  int k = (int)kd;
  double r = fma(-kd, LN2_HI, x);
  r = fma(-kd, LN2_LO, r);
  double p = 1.0/39916800.0;
  p = fma(p, r, 1.0/3628800.0);
  p = fma(p, r, 1.0/362880.0);
  p = fma(p, r, 1.0/40320.0);
  p = fma(p, r, 1.0/5040.0);
  p = fma(p, r, 1.0/720.0);
  p = fma(p, r, 1.0/120.0);
  p = fma(p, r, 1.0/24.0);
  p = fma(p, r, 1.0/6.0);
  p = fma(p, r, 0.5);
  p = fma(p, r, 1.0);
  p = fma(p, r, 1.0);
  u64 sb = ((u64)(k + 1023)) << 52;
  return p * __longlong_as_double((long long)sb);
}
__device__ __forceinline__ float exf(float x){ return (float)exp_d((double)x); }
__device__ __forceinline__ float sigm(float x){   // exact-path stepwise f32 sigmoid (density head)
  if (x >= 0.f){ float e = exf(-x); return fdv(1.f, fa(1.f, e)); }
  float e = exf(x); return fdv(e, fa(1.f, e));
}
// fast sigmoid for the rgb head only (abs tolerance 5.6e-2; bf16-quantized anyway)
__device__ __forceinline__ float sigm_fast(float x){
  return 1.f/(1.f + __expf(-x));
}
__device__ __forceinline__ u16 f2b(float f){
  u32 x = __float_as_uint(f);
  return (u16)((x + 0x7fffu + ((x>>16)&1u)) >> 16);   // RNE
}
// monotone float<->u32 key (handles negatives) for atomic min/max
__device__ __forceinline__ u32 fenc(float f){ u32 b=__float_as_uint(f); return (b&0x80000000u)? ~b : (b|0x80000000u); }
__device__ __forceinline__ float fdec(u32 k){ u32 b=(k&0x80000000u)? (k^0x80000000u) : ~k; return __uint_as_float(b); }

// ---------------- init: global min/max of hit depths, scalar slots, W1 transpose ----------------
__global__ void k_init(const float* __restrict__ hmin, const float* __restrict__ hmax,
                       const float* __restrict__ W1, float* __restrict__ scal,
                       float* __restrict__ W1t){
  __shared__ float smn[256], smx[256];
  int t = threadIdx.x;
  float mn = 1e30f, mx = -1e30f;
  for (int i=t;i<NRAYS;i+=256){ mn=fminf(mn,hmin[i]); mx=fmaxf(mx,hmax[i]); }
  smn[t]=mn; smx[t]=mx; __syncthreads();
  for(int s=128;s>0;s>>=1){
    if(t<s){ smn[t]=fminf(smn[t],smn[t+s]); smx[t]=fmaxf(smx[t],smx[t+s]); }
    __syncthreads();
  }
  if(t==0){
    scal[0]=smn[0]; scal[1]=smx[0];
    ((u32*)scal)[2]=0xFFFFFFFFu;  // dmin key (atomicMin on monotone key)
    ((u32*)scal)[3]=0u;           // dmax key (atomicMax)
  }
  for(int i=t;i<2048;i+=256){ int j=i>>5, c=i&31; W1t[i]=W1[c*64+j]; }  // W1t[j*32+c]
}

// ---------------- transpose planes (N,3,C,H,W) f32 -> (N*3,H,W,C) f32 ----------------
__global__ void __launch_bounds__(256) k_tr(const float* __restrict__ pl, float* __restrict__ pt){
  int t = blockIdx.x*256 + threadIdx.x;     // 0 .. 3145727
  int x  = t & 255;
  int c4 = ((t>>8)&7)<<2;
  int y  = (t>>11)&255;
  int np = t>>19;                            // 0..5
  const float* ip = pl + (((size_t)(np*32+c4))<<16) + (y<<8) + x;
  float4 o;
  o.x = ip[0];
  o.y = ip[65536];
  o.z = ip[131072];
  o.w = ip[196608];
  *reinterpret_cast<float4*>(pt + ((((size_t)(np<<8|y))<<8|x)<<5) + c4) = o;
}

// ---------------- point evaluation (sampling + decoder), strict f32 ----------------
// r9-verified 202us shape (1 thread/point, sequential j, no spill) + WEIGHTS IN LDS:
// W1t+W2+b1+b2 (16.8KB) cycled per point-iteration thrashes the 16KB scalar K$
// (the invariant bottleneck across r5-r14); staging them in LDS once per block
// moves the stream to the 128B/cyc LDS pipe (uniform addr -> broadcast, no conflict).
// Same bits, same op order -> outputs bit-identical.
template<int PHASE>
__global__ void __launch_bounds__(256) k_eval(
  const float* __restrict__ pt, const float* __restrict__ ro, const float* __restrict__ rd,
  const float* __restrict__ hmin, const float* __restrict__ hmax,
  const float* __restrict__ jitter, const int* __restrict__ hitmask,
  const float* __restrict__ W1t, const float* __restrict__ b1,
  const float* __restrict__ W2, const float* __restrict__ b2,
  const float* __restrict__ sb, float* __restrict__ scal,
  float* __restrict__ dep, float* __restrict__ dens_out, u16* __restrict__ rgb_out,
  float* __restrict__ out_psdf)
{
  __shared__ float sW1[2048];
  __shared__ float sW2[2112];
  __shared__ float sb1[64];
  __shared__ float sb2[33];
  {
    int t = threadIdx.x;
    for(int i=t;i<2048;i+=256) sW1[i]=W1t[i];
    for(int i=t;i<2112;i+=256) sW2[i]=W2[i];
    if(t<64) sb1[t]=b1[t];
    if(t<33) sb2[t]=b2[t];
  }
  __syncthreads();

  int idx = blockIdx.x*256 + threadIdx.x;   // 0..262143
  int ray = idx >> 5;
  int s   = idx & 31;
  int n   = ray >> 12;
  int msk = hitmask[ray];

  float d;
  if (PHASE==0){
    float hmn = msk ? hmin[ray] : scal[0];
    float hmx = msk ? hmax[ray] : scal[1];
    float span = fs(hmx, hmn);
    float jit  = jitter[idx];
    float base = (float)((double)s * (1.0/31.0));   // np.linspace f64 arange*step -> f32 cast
    if (s==31) base = 1.0f;
    float t1 = fdv(fm(jit, span), 32.0f);
    d = fa(fm(fa(base, t1), span), hmn);
    dep[idx] = d;
    float dm=d, dM=d;
#pragma unroll
    for (int m=1;m<64;m<<=1){ dm=fminf(dm,__shfl_xor(dm,m)); dM=fmaxf(dM,__shfl_xor(dM,m)); }
    if ((threadIdx.x & 63)==0){
      atomicMin(((u32*)scal)+2, fenc(dm));
      atomicMax(((u32*)scal)+3, fenc(dM));
    }
  } else {
    d = dep[idx];
  }

  float ox=ro[ray*3+0], oy=ro[ray*3+1], oz=ro[ray*3+2];
  float dx=rd[ray*3+0], dy=rd[ray*3+1], dz=rd[ray*3+2];
  float px = fa(ox, fm(d,dx)), py = fa(oy, fm(d,dy)), pz = fa(oz, fm(d,dz));
  float nrm = __fsqrt_rn(fa(fa(fm(px,px),fm(py,py)),fm(pz,pz)));
  float tsdf = fs(nrm, 0.5f);
  const float sc2 = (float)(2.0/6.0);
  float cx=fm(px,sc2), cy=fm(py,sc2), cz=fm(pz,sc2);

  float feat[32];
#pragma unroll
  for(int c=0;c<32;c++) feat[c]=0.f;

#pragma unroll
  for (int p=0;p<3;p++){
    float u = (p==2)?cz:cx;                  // plane0:(x,y) plane1:(x,z) plane2:(z,y)
    float v = (p==1)?cz:cy;
    float fx = fs(fm(fa(u,1.f),128.f),0.5f); // (u+1)*128-0.5 per-op
    float fy = fs(fm(fa(v,1.f),128.f),0.5f);
    float x0f = floorf(fx), y0f = floorf(fy);
    float wx = fs(fx,x0f), wy = fs(fy,y0f);
    float ax0 = fs(1.f,wx), ax1 = wx, ay0 = fs(1.f,wy), ay1 = wy;
    int x0, y0;
    { // saturating cast (wild coords can exceed int range semantics; floor first)
      x0 = (x0f >= 2.1e9f) ? 2147483647 : ((x0f <= -2.1e9f) ? (-2147483647-1) : (int)x0f);
      y0 = (y0f >= 2.1e9f) ? 2147483647 : ((y0f <= -2.1e9f) ? (-2147483647-1) : (int)y0f);
    }
    int x1=x0+1, y1=y0+1;
    bool vx0 = (x0>=0 && x0<256), vx1 = (x1>=0 && x1<256);
    bool vy0 = (y0>=0 && y0<256), vy1 = (y1>=0 && y1<256);
    bool ok00 = vx0&&vy0, ok01 = vx1&&vy0, ok10 = vx0&&vy1, ok11 = vx1&&vy1;
    int cx0=min(max(x0,0),255), cx1=min(max(x1,0),255);
    int cy0=min(max(y0,0),255), cy1=min(max(y1,0),255);
    int npl = n*3+p;
    size_t pb = ((size_t)npl)<<16;
    const float4* t00 = (const float4*)(pt + ((pb + (cy0<<8) + cx0)<<5));
    const float4* t01 = (const float4*)(pt + ((pb + (cy0<<8) + cx1)<<5));
    const float4* t10 = (const float4*)(pt + ((pb + (cy1<<8) + cx0)<<5));
    const float4* t11 = (const float4*)(pt + ((pb + (cy1<<8) + cx1)<<5));
#pragma unroll
    for(int q=0;q<8;q++){
      float4 v00 = t00[q], v01 = t01[q], v10 = t10[q], v11 = t11[q];
      float e0,e1,e2,e3, t_;
#define CORNER_SUM(FLD, OUTI) \
      e0 = ok00 ? v00.FLD : 0.f; e1 = ok01 ? v01.FLD : 0.f; \
      e2 = ok10 ? v10.FLD : 0.f; e3 = ok11 ? v11.FLD : 0.f; \
      t_ = fa(fa(fa(fm(fm(e0,ax0),ay0), fm(fm(e1,ax1),ay0)), fm(fm(e2,ax0),ay1)), fm(fm(e3,ax1),ay1)); \
      feat[q*4+OUTI] = fa(feat[q*4+OUTI], t_);
      CORNER_SUM(x,0) CORNER_SUM(y,1) CORNER_SUM(z,2) CORNER_SUM(w,3)
#undef CORNER_SUM
    }
  }
#pragma unroll
  for(int c=0;c<32;c++) feat[c] = fdv(feat[c], 3.0f);   // np.mean: (f0+f1)+f2 then /3

  // decoder from LDS: h = softplus(feat@W1+b1); o = h@W2+b2 (r9-verified op order)
  float o[33];
#pragma unroll
  for(int k=0;k<33;k++) o[k]=0.f;
#pragma unroll 2
  for(int j=0;j<64;j++){
    float a = 0.f;
    const float* wr = sW1 + j*32;
#pragma unroll
    for(int c=0;c<32;c++) a = fmaf(feat[c], wr[c], a);
    a = fa(a, sb1[j]);
    // native-HW stable softplus: v_exp_f32 + v_log_f32 (r9-verified)
    float h = fa(fmaxf(a,0.f), __logf(fa(1.f, __expf(-fabsf(a)))));
    const float* w2r = sW2 + j*33;
#pragma unroll
    for(int k=0;k<33;k++) o[k] = fmaf(h, w2r[k], o[k]);
  }
#pragma unroll
  for(int k=0;k<33;k++) o[k] = fa(o[k], sb2[k]);

  float beta = fmaxf(sb[0], 0.002f);
  float raw = o[0];
  out_psdf[((size_t)n<<18) + ((size_t)PHASE<<17) + (size_t)(ray&4095)*32 + s] = raw;  // unmasked
  float sg = fa(raw, tsdf);
  float dens = msk ? fdv(sigm(fdv(-sg, beta)), beta) : 0.f;   // exact path (chaotic cdf chain)
  dens_out[idx]=dens;

  u16 rv[32];
#pragma unroll
  for(int c=0;c<32;c++){
    float r = msk ? fs(fm(sigm_fast(o[c+1]), 1.002f), 0.001f) : 0.f;  // fast path, abs tol 5.6e-2
    rv[c]=f2b(r);
  }
  uint4* op = (uint4*)(rgb_out + (size_t)idx*32);
#pragma unroll
  for(int q=0;q<4;q++){
    uint4 w;
    w.x = (u32)rv[q*8+0] | ((u32)rv[q*8+1]<<16);
    w.y = (u32)rv[q*8+2] | ((u32)rv[q*8+3]<<16);
    w.z = (u32)rv[q*8+4] | ((u32)rv[q*8+5]<<16);
    w.w = (u32)rv[q*8+6] | ((u32)rv[q*8+7]<<16);
    op[q]=w;
  }
}

// ---------------- coarse march + importance sampling (strict f32, thread per ray) ----------------
__global__ void __launch_bounds__(64) k_imp(
  const float* __restrict__ dc, const float* __restrict__ dens,
  const float* __restrict__ u_imp, float* __restrict__ df, float* __restrict__ scal)
{
  __shared__ float scdf[64][30];
  __shared__ float szm [64][30];
  int tid = threadIdx.x;
  int ray = blockIdx.x*64 + tid;   // 0..8191
  float w[31];
  float dprev = dc[ray*32+0];
  float sprev = dens[ray*32+0];
  float T = 1.f;
#pragma unroll
  for(int i=0;i<31;i++){
    float dn = dc[ray*32+i+1];
    float sn = dens[ray*32+i+1];
    if (i<30) szm[tid][i] = fm(0.5f, fa(dprev,dn));
    float delta = fs(dn,dprev);
    float dm = fm(0.5f, fa(sprev,sn));
    float al = fs(1.f, exf(-fm(dm,delta)));
    w[i] = fm(al,T);
    T = fm(T, fa(fs(1.f,al), 1e-10f));
    dprev=dn; sprev=sn;
  }
  // pdf weights: w_sm[j]=0.5*(m[j]+m[j+1])+0.01 (j=1..29), +EPS
  float pdfw[29];
#pragma unroll
  for(int i=0;i<29;i++){
    float m1 = fmaxf(w[i],w[i+1]), m2 = fmaxf(w[i+1],w[i+2]);
    pdfw[i] = fa(fa(fm(0.5f, fa(m1,m2)), 0.01f), 1e-5f);
  }
  // np.sum pairwise (n=29): 8 accumulators, 2 blocked adds, tree, 5 sequential tail
  float sum;
  {
    float r[8];
#pragma unroll
    for(int j=0;j<8;j++) r[j]=pdfw[j];
#pragma unroll
    for(int j=0;j<8;j++) r[j]=fa(r[j],pdfw[8+j]);
#pragma unroll
    for(int j=0;j<8;j++) r[j]=fa(r[j],pdfw[16+j]);
    sum = fa(fa(fa(r[0],r[1]),fa(r[2],r[3])), fa(fa(r[4],r[5]),fa(r[6],r[7])));
#pragma unroll
    for(int i=24;i<29;i++) sum = fa(sum, pdfw[i]);
  }
  // cdf: sequential cumsum of pdf (per-element f32 division)
  {
    float cacc = 0.f;
    scdf[tid][0] = 0.f;
#pragma unroll
    for(int i=1;i<30;i++){
      cacc = fa(cacc, fdv(pdfw[i-1], sum));
      scdf[tid][i] = cacc;
    }
  }

  float fmn=1e30f, fmx=-1e30f;
  for(int k=0;k<32;k++){
    float u = u_imp[ray*32+k];
    // np.searchsorted(cdf, u, 'right') = bisect_right (binary, regardless of monotonicity)
    int lo=0, hi=30;
    while(lo<hi){
      int mid=(lo+hi)>>1;
      if (scdf[tid][mid] <= u) lo = mid+1; else hi = mid;
    }
    int ind = lo;                 // in [1,30]
    int below = ind-1;            // in [0,29]
    int above = (ind>29)?29:ind;  // in [0,29]
    float cdf0 = scdf[tid][below];
    float cdf1 = scdf[tid][above];
    float b0   = szm [tid][below];
    float b1v  = szm [tid][above];
    float den = fs(cdf1,cdf0);
    if((double)den < 1e-5) den = 1.f;      // EPS compare in f64 (python const)
    float sres = fa(b0, fm(fdv(fs(u,cdf0),den), fs(b1v,b0)));
    df[ray*32+k]=sres;
    fmn=fminf(fmn,sres); fmx=fmaxf(fmx,sres);
  }
#pragma unroll
  for(int m=1;m<64;m<<=1){ fmn=fminf(fmn,__shfl_xor(fmn,m)); fmx=fmaxf(fmx,__shfl_xor(fmx,m)); }
  if(tid==0){
    atomicMin(((u32*)scal)+2, fenc(fmn));
    atomicMax(((u32*)scal)+3, fenc(fmx));
  }
}

// ---------------- stable sort (64) + final ray march, strict f32 (wave per ray) ----------------
__global__ void __launch_bounds__(256) k_final(
  const float* __restrict__ dc, const float* __restrict__ df,
  const float* __restrict__ densc, const float* __restrict__ densf,
  const u16* __restrict__ rgbc, const u16* __restrict__ rgbf,
  const float* __restrict__ scal,
  float* __restrict__ out_rgb, float* __restrict__ out_depth, float* __restrict__ out_w)
{
  __shared__ float ssd[4][64];
  __shared__ float ssn[4][64];
  __shared__ int   sp [4][64];
  __shared__ float swv[4][64];   // per-interval weight
  __shared__ float swz[4][64];   // per-interval weight*z_mid
  int wid = threadIdx.x>>6, lane = threadIdx.x&63;
  int ray = blockIdx.x*4 + wid;

  float myd = (lane<32)? dc[ray*32+lane]    : df[ray*32+lane-32];
  float myn = (lane<32)? densc[ray*32+lane] : densf[ray*32+lane-32];
  ssd[wid][lane]=myd; __syncthreads();
  int rk=0;
#pragma unroll 8
  for(int j=0;j<64;j++){
    float dj = ssd[wid][j];
    rk += (dj<myd || (dj==myd && j<lane)) ? 1:0;     // stable argsort rank
  }
  __syncthreads();
  ssd[wid][rk]=myd; ssn[wid][rk]=myn; sp[wid][rk]=lane;
  __syncthreads();

  float T=1.f, accr=0.f;
  int j0 = sp[wid][0];
  float cprev = 0.f;
  if (lane<32){
    const u16* cb = (j0<32)? (rgbc+((size_t)ray*32+j0)*32) : (rgbf+((size_t)ray*32+(j0-32))*32);
    cprev = __uint_as_float(((u32)cb[lane])<<16);
  }
  float d0 = ssd[wid][0], n0 = ssn[wid][0];
  for(int s2=0;s2<63;s2++){
    float d1 = ssd[wid][s2+1], n1 = ssn[wid][s2+1];
    float delta = fs(d1,d0);
    float dm = fm(0.5f, fa(n0,n1));
    float al = fs(1.f, exf(-fm(dm,delta)));
    float wv = fm(al,T);
    T = fm(T, fa(fs(1.f,al), 1e-10f));
    if (lane==s2){ swv[wid][s2]=wv; swz[wid][s2]=fm(wv, fm(0.5f, fa(d0,d1))); }
    int j1 = sp[wid][s2+1];
    float cnext = 0.f;
    if (lane<32){
      const u16* cb = (j1<32)? (rgbc+((size_t)ray*32+j1)*32) : (rgbf+((size_t)ray*32+(j1-32))*32);
      cnext = __uint_as_float(((u32)cb[lane])<<16);
    }
    // comp_rgb: strided axis-2 reduce -> SEQUENTIAL accumulation (numpy)
    accr = fa(accr, fm(wv, fm(0.5f, fa(cprev,cnext))));
    cprev=cnext; d0=d1; n0=n1;
  }
  __syncthreads();
  if(lane<63) out_w[(size_t)ray*63+lane]=swv[wid][lane];
  if(lane<32) out_rgb[(size_t)ray*32+lane]=fs(fm(accr,2.f),1.f);
  if(lane==0){
    // np.sum pairwise (n=63, contiguous): r[j]=sum_k a[8k+j] k=0..6; tree; tail 56..62
    float wsum, zsum;
    {
      float r[8], rz[8];
#pragma unroll
      for(int j=0;j<8;j++){ r[j]=swv[wid][j]; rz[j]=swz[wid][j]; }
      for(int i=8;i<56;i+=8)
#pragma unroll
        for(int j=0;j<8;j++){ r[j]=fa(r[j],swv[wid][i+j]); rz[j]=fa(rz[j],swz[wid][i+j]); }
      wsum = fa(fa(fa(r[0],r[1]),fa(r[2],r[3])), fa(fa(r[4],r[5]),fa(r[6],r[7])));
      zsum = fa(fa(fa(rz[0],rz[1]),fa(rz[2],rz[3])), fa(fa(rz[4],rz[5]),fa(rz[6],rz[7])));
      for(int i=56;i<63;i++){ wsum=fa(wsum,swv[wid][i]); zsum=fa(zsum,swz[wid][i]); }
    }
    float depv = fdv(zsum, wsum);
    if (isnan(depv)) depv = INFINITY;    // nan_to_num(nan=inf)
    float lo = fdec(((const u32*)scal)[2]);
    float hi = fdec(((const u32*)scal)[3]);
    depv = fminf(fmaxf(depv,lo),hi);     // clip to global all_d min/max
    out_depth[ray]=depv;
  }
}

extern "C" void kernel_launch(void* const* d_in, const int* in_sizes, int n_in,
                              void* d_out, int out_size, void* d_ws, size_t ws_size,
                              hipStream_t stream) {
  const float* planes = (const float*)d_in[0];
  const float* ro     = (const float*)d_in[1];
  const float* rdp    = (const float*)d_in[2];
  const float* hmin   = (const float*)d_in[3];
  const float* hmax   = (const float*)d_in[4];
  const float* jitter = (const float*)d_in[5];
  const float* uimp   = (const float*)d_in[6];
  const float* W1     = (const float*)d_in[7];
  const float* b1     = (const float*)d_in[8];
  const float* W2     = (const float*)d_in[9];
  const float* b2     = (const float*)d_in[10];
  const float* sb     = (const float*)d_in[11];
  const int*   hmk    = (const int*)d_in[12];
  float* out = (float*)d_out;
  char* ws = (char*)d_ws;

  size_t off=0;
  auto alloc=[&](size_t bytes){ size_t o=off; off=(off+bytes+255)&~(size_t)255; return o; };
  float* scal = (float*)(ws+alloc(64));
  float* W1t  = (float*)(ws+alloc(2048*4));
  float* pt   = (float*)(ws+alloc((size_t)12582912*4));
  float* dco  = (float*)(ws+alloc((size_t)NSAMP*4));
  float* dfi  = (float*)(ws+alloc((size_t)NSAMP*4));
  float* dnc  = (float*)(ws+alloc((size_t)NSAMP*4));
  float* dnf  = (float*)(ws+alloc((size_t)NSAMP*4));
  u16*   rgc  = (u16*)  (ws+alloc((size_t)NSAMP*32*2));
  u16*   rgf  = (u16*)  (ws+alloc((size_t)NSAMP*32*2));
  (void)in_sizes; (void)n_in; (void)out_size; (void)ws_size;

  float* out_rgb  = out;
  float* out_dep  = out + 262144;
  float* out_w    = out + 270336;
  float* out_psdf = out + 786432;

  k_init<<<dim3(1),dim3(256),0,stream>>>(hmin,hmax,W1,scal,W1t);
  k_tr<<<dim3(12288),dim3(256),0,stream>>>(planes, pt);
  k_eval<0><<<dim3(1024),dim3(256),0,stream>>>(pt,ro,rdp,hmin,hmax,jitter,hmk,W1t,b1,W2,b2,sb,scal,dco,dnc,rgc,out_psdf);
  k_imp<<<dim3(128),dim3(64),0,stream>>>(dco,dnc,uimp,dfi,scal);
  k_eval<1><<<dim3(1024),dim3(256),0,stream>>>(pt,ro,rdp,hmin,hmax,jitter,hmk,W1t,b1,W2,b2,sb,scal,dfi,dnf,rgf,out_psdf);
  k_final<<<dim3(2048),dim3(256),0,stream>>>(dco,dfi,dnc,dnf,rgc,rgf,scal,out_rgb,out_dep,out_w);
}

// Round 16
// 424.540 us; speedup vs baseline: 2.3926x; 1.1011x over previous
//
#include <hip/hip_runtime.h>
#include <hip/hip_bf16.h>
#include <math.h>
#include <stddef.h>

typedef unsigned int u32;
typedef unsigned short u16;
typedef unsigned long long u64;

#define NRAYS 8192      // N_BATCH * N_RAYS
#define NSAMP 262144    // NRAYS * 32

// ---- strict float32 ops (block FMA contraction, numpy-per-op rounding) ----
__device__ __forceinline__ float fa(float a,float b){ return __fadd_rn(a,b); }
__device__ __forceinline__ float fs(float a,float b){ return __fsub_rn(a,b); }
__device__ __forceinline__ float fm(float a,float b){ return __fmul_rn(a,b); }
__device__ __forceinline__ float fdv(float a,float b){ return __fdiv_rn(a,b); }

// ---- fast double exp: |rel err| < ~2^-45, branch-light (march + density path) ----
__device__ __forceinline__ double exp_d(double x){
  const double LOG2E  = 1.4426950408889634074;
  const double LN2_HI = 6.93147180369123816490e-01;
  const double LN2_LO = 1.90821492927058770002e-10;
  double kd = rint(x * LOG2E);
  if (kd >  200.0) return INFINITY;
  if (kd < -200.0) return 0.0;
  int k = (int)kd;
  double r = fma(-kd, LN2_HI, x);
  r = fma(-kd, LN2_LO, r);
  double p = 1.0/39916800.0;
  p = fma(p, r, 1.0/3628800.0);
  p = fma(p, r, 1.0/362880.0);
  p = fma(p, r, 1.0/40320.0);
  p = fma(p, r, 1.0/5040.0);
  p = fma(p, r, 1.0/720.0);
  p = fma(p, r, 1.0/120.0);
  p = fma(p, r, 1.0/24.0);
  p = fma(p, r, 1.0/6.0);
  p = fma(p, r, 0.5);
  p = fma(p, r, 1.0);
  p = fma(p, r, 1.0);
  u64 sb = ((u64)(k + 1023)) << 52;
  return p * __longlong_as_double((long long)sb);
}
__device__ __forceinline__ float exf(float x){ return (float)exp_d((double)x); }
__device__ __forceinline__ float sigm(float x){   // exact-path stepwise f32 sigmoid (density head)
  if (x >= 0.f){ float e = exf(-x); return fdv(1.f, fa(1.f, e)); }
  float e = exf(x); return fdv(e, fa(1.f, e));
}
// fast sigmoid for the rgb head only (abs tolerance 5.6e-2; bf16-quantized anyway)
__device__ __forceinline__ float sigm_fast(float x){
  return 1.f/(1.f + __expf(-x));
}
__device__ __forceinline__ u16 f2b(float f){
  u32 x = __float_as_uint(f);
  return (u16)((x + 0x7fffu + ((x>>16)&1u)) >> 16);   // RNE
}
// monotone float<->u32 key (handles negatives) for atomic min/max
__device__ __forceinline__ u32 fenc(float f){ u32 b=__float_as_uint(f); return (b&0x80000000u)? ~b : (b|0x80000000u); }
__device__ __forceinline__ float fdec(u32 k){ u32 b=(k&0x80000000u)? (k^0x80000000u) : ~k; return __uint_as_float(b); }

// ---------------- init: global min/max of hit depths, scalar slots, W1 transpose ----------------
__global__ void k_init(const float* __restrict__ hmin, const float* __restrict__ hmax,
                       const float* __restrict__ W1, float* __restrict__ scal,
                       float* __restrict__ W1t){
  __shared__ float smn[256], smx[256];
  int t = threadIdx.x;
  float mn = 1e30f, mx = -1e30f;
  for (int i=t;i<NRAYS;i+=256){ mn=fminf(mn,hmin[i]); mx=fmaxf(mx,hmax[i]); }
  smn[t]=mn; smx[t]=mx; __syncthreads();
  for(int s=128;s>0;s>>=1){
    if(t<s){ smn[t]=fminf(smn[t],smn[t+s]); smx[t]=fmaxf(smx[t],smx[t+s]); }
    __syncthreads();
  }
  if(t==0){
    scal[0]=smn[0]; scal[1]=smx[0];
    ((u32*)scal)[2]=0xFFFFFFFFu;  // dmin key (atomicMin on monotone key)
    ((u32*)scal)[3]=0u;           // dmax key (atomicMax)
  }
  for(int i=t;i<2048;i+=256){ int j=i>>5, c=i&31; W1t[i]=W1[c*64+j]; }  // W1t[j*32+c]
}

// ---------------- transpose planes (N,3,C,H,W) f32 -> (N*3,H,W,C) f32 ----------------
__global__ void __launch_bounds__(256) k_tr(const float* __restrict__ pl, float* __restrict__ pt){
  int t = blockIdx.x*256 + threadIdx.x;     // 0 .. 3145727
  int x  = t & 255;
  int c4 = ((t>>8)&7)<<2;
  int y  = (t>>11)&255;
  int np = t>>19;                            // 0..5
  const float* ip = pl + (((size_t)(np*32+c4))<<16) + (y<<8) + x;
  float4 o;
  o.x = ip[0];
  o.y = ip[65536];
  o.z = ip[131072];
  o.w = ip[196608];
  *reinterpret_cast<float4*>(pt + ((((size_t)(np<<8|y))<<8|x)<<5) + c4) = o;
}

// ---------------- point evaluation (sampling + decoder), strict f32 ----------------
// WAVE-COOPERATIVE GATHER: wave's 64 points gathered in 8 rounds; lane (pg,q)
// loads 16B chunk q of each corner texel of point pg -> lanes 0-7 span one
// texel's contiguous 128B -> ~16 cache lines per wave-load instead of 64
// (divergent-lane request cost was the r5-r15-invariant bottleneck).
// Chunk math = bit-identical CORNER_SUM (same plane order); feat passes through
// LDS exactly; decoder = r9-verified shape (global weights, o[33] AGPR-eligible).
template<int PHASE>
__global__ void __launch_bounds__(256) k_eval(
  const float* __restrict__ pt, const float* __restrict__ ro, const float* __restrict__ rd,
  const float* __restrict__ hmin, const float* __restrict__ hmax,
  const float* __restrict__ jitter, const int* __restrict__ hitmask,
  const float* __restrict__ W1t, const float* __restrict__ b1,
  const float* __restrict__ W2, const float* __restrict__ b2,
  const float* __restrict__ sb, float* __restrict__ scal,
  float* __restrict__ dep, float* __restrict__ dens_out, u16* __restrict__ rgb_out,
  float* __restrict__ out_psdf)
{
  __shared__ float sfeat[4][64][33];   // stride 33: conflict-free b32 access
  int tid = threadIdx.x;
  int wid = tid>>6, lane = tid&63;
  int blockbase = blockIdx.x*256;
  int wavebase  = blockbase + (wid<<6);
  int idx = blockbase + tid;           // own point 0..262143
  int ray = idx >> 5;
  int s   = idx & 31;
  int n   = ray >> 12;
  int msk = hitmask[ray];

  // ---- Phase A: own-point depth (r9 exact), dep store, global min/max ----
  float d;
  if (PHASE==0){
    float hmn = msk ? hmin[ray] : scal[0];
    float hmx = msk ? hmax[ray] : scal[1];
    float span = fs(hmx, hmn);
    float jit  = jitter[idx];
    float base = (float)((double)s * (1.0/31.0));   // np.linspace f64 arange*step -> f32 cast
    if (s==31) base = 1.0f;
    float t1 = fdv(fm(jit, span), 32.0f);
    d = fa(fm(fa(base, t1), span), hmn);
    dep[idx] = d;
    float dm=d, dM=d;
#pragma unroll
    for (int m=1;m<64;m<<=1){ dm=fminf(dm,__shfl_xor(dm,m)); dM=fmaxf(dM,__shfl_xor(dM,m)); }
    if ((tid & 63)==0){
      atomicMin(((u32*)scal)+2, fenc(dm));
      atomicMax(((u32*)scal)+3, fenc(dM));
    }
  } else {
    d = dep[idx];
  }

  // own-point tsdf (kept live through the gather; 1 VGPR)
  float tsdf;
  {
    float ox=ro[ray*3+0], oy=ro[ray*3+1], oz=ro[ray*3+2];
    float dx=rd[ray*3+0], dy=rd[ray*3+1], dz=rd[ray*3+2];
    float px = fa(ox, fm(d,dx)), py = fa(oy, fm(d,dy)), pz = fa(oz, fm(d,dz));
    float nrm = __fsqrt_rn(fa(fa(fm(px,px),fm(py,py)),fm(pz,pz)));
    tsdf = fs(nrm, 0.5f);
  }

  // ---- Phase B: cooperative gather, 8 rounds x 8 points, lane=(pg,q) ----
  const float sc2 = (float)(2.0/6.0);
  int pg = lane >> 3;      // point within round
  int q  = lane & 7;       // 4-channel chunk
#pragma unroll 1
  for (int r=0;r<8;r++){
    int p2   = wavebase + r*8 + pg;
    int ray2 = p2 >> 5;
    int s2   = p2 & 31;
    int n2   = ray2 >> 12;
    float d2;
    if (PHASE==0){
      // recompute (identical formula -> identical bits; avoids RAW-through-memory)
      int msk2 = hitmask[ray2];
      float hmn = msk2 ? hmin[ray2] : scal[0];
      float hmx = msk2 ? hmax[ray2] : scal[1];
      float span = fs(hmx, hmn);
      float jit  = jitter[p2];
      float base = (float)((double)s2 * (1.0/31.0));
      if (s2==31) base = 1.0f;
      float t1 = fdv(fm(jit, span), 32.0f);
      d2 = fa(fm(fa(base, t1), span), hmn);
    } else {
      d2 = dep[p2];   // input array (dfi), no hazard
    }
    float ox=ro[ray2*3+0], oy=ro[ray2*3+1], oz=ro[ray2*3+2];
    float dx=rd[ray2*3+0], dy=rd[ray2*3+1], dz=rd[ray2*3+2];
    float px = fa(ox, fm(d2,dx)), py = fa(oy, fm(d2,dy)), pz = fa(oz, fm(d2,dz));
    float cx=fm(px,sc2), cy=fm(py,sc2), cz=fm(pz,sc2);

    float fchunk[4];
#pragma unroll
    for(int i=0;i<4;i++) fchunk[i]=0.f;

#pragma unroll
    for (int p=0;p<3;p++){
      float u = (p==2)?cz:cx;                  // plane0:(x,y) plane1:(x,z) plane2:(z,y)
      float v = (p==1)?cz:cy;
      float fx = fs(fm(fa(u,1.f),128.f),0.5f); // (u+1)*128-0.5 per-op
      float fy = fs(fm(fa(v,1.f),128.f),0.5f);
      float x0f = floorf(fx), y0f = floorf(fy);
      float wx = fs(fx,x0f), wy = fs(fy,y0f);
      float ax0 = fs(1.f,wx), ax1 = wx, ay0 = fs(1.f,wy), ay1 = wy;
      int x0, y0;
      { // saturating cast
        x0 = (x0f >= 2.1e9f) ? 2147483647 : ((x0f <= -2.1e9f) ? (-2147483647-1) : (int)x0f);
        y0 = (y0f >= 2.1e9f) ? 2147483647 : ((y0f <= -2.1e9f) ? (-2147483647-1) : (int)y0f);
      }
      int x1=x0+1, y1=y0+1;
      bool vx0 = (x0>=0 && x0<256), vx1 = (x1>=0 && x1<256);
      bool vy0 = (y0>=0 && y0<256), vy1 = (y1>=0 && y1<256);
      bool ok00 = vx0&&vy0, ok01 = vx1&&vy0, ok10 = vx0&&vy1, ok11 = vx1&&vy1;
      int cx0=min(max(x0,0),255), cx1=min(max(x1,0),255);
      int cy0=min(max(y0,0),255), cy1=min(max(y1,0),255);
      size_t pb = ((size_t)(n2*3+p))<<16;
      int qo = q<<2;   // chunk float offset within texel
      const float4* t00 = (const float4*)(pt + ((pb + (cy0<<8) + cx0)<<5) + qo);
      const float4* t01 = (const float4*)(pt + ((pb + (cy0<<8) + cx1)<<5) + qo);
      const float4* t10 = (const float4*)(pt + ((pb + (cy1<<8) + cx0)<<5) + qo);
      const float4* t11 = (const float4*)(pt + ((pb + (cy1<<8) + cx1)<<5) + qo);
      float4 v00 = *t00, v01 = *t01, v10 = *t10, v11 = *t11;
      float e0,e1,e2,e3, t_;
#define CORNER_SUM(FLD, OUTI) \
      e0 = ok00 ? v00.FLD : 0.f; e1 = ok01 ? v01.FLD : 0.f; \
      e2 = ok10 ? v10.FLD : 0.f; e3 = ok11 ? v11.FLD : 0.f; \
      t_ = fa(fa(fa(fm(fm(e0,ax0),ay0), fm(fm(e1,ax1),ay0)), fm(fm(e2,ax0),ay1)), fm(fm(e3,ax1),ay1)); \
      fchunk[OUTI] = fa(fchunk[OUTI], t_);
      CORNER_SUM(x,0) CORNER_SUM(y,1) CORNER_SUM(z,2) CORNER_SUM(w,3)
#undef CORNER_SUM
    }
    int pidx = r*8 + pg;
#pragma unroll
    for(int i=0;i<4;i++)
      sfeat[wid][pidx][q*4+i] = fdv(fchunk[i], 3.0f);   // np.mean: (f0+f1)+f2 then /3
  }
  __syncthreads();

  // ---- Phase C: own feat from LDS (stride-33 -> 2-way alias, free) + r9 decoder ----
  float feat[32];
#pragma unroll
  for(int c=0;c<32;c++) feat[c] = sfeat[wid][lane][c];

  float o[33];
#pragma unroll
  for(int k=0;k<33;k++) o[k]=0.f;
#pragma unroll 2
  for(int j=0;j<64;j++){
    float a = 0.f;
#pragma unroll
    for(int c=0;c<32;c++) a = fmaf(feat[c], W1t[j*32+c], a);
    a = fa(a, b1[j]);
    // native-HW stable softplus: v_exp_f32 + v_log_f32 (r9-verified)
    float h = fa(fmaxf(a,0.f), __logf(fa(1.f, __expf(-fabsf(a)))));
#pragma unroll
    for(int k=0;k<33;k++) o[k] = fmaf(h, W2[j*33+k], o[k]);
  }
#pragma unroll
  for(int k=0;k<33;k++) o[k] = fa(o[k], b2[k]);

  float beta = fmaxf(sb[0], 0.002f);
  float raw = o[0];
  out_psdf[((size_t)n<<18) + ((size_t)PHASE<<17) + (size_t)(ray&4095)*32 + s] = raw;  // unmasked
  float sg = fa(raw, tsdf);
  float dens = msk ? fdv(sigm(fdv(-sg, beta)), beta) : 0.f;   // exact path (chaotic cdf chain)
  dens_out[idx]=dens;

  u16 rv[32];
#pragma unroll
  for(int c=0;c<32;c++){
    float r = msk ? fs(fm(sigm_fast(o[c+1]), 1.002f), 0.001f) : 0.f;  // fast path, abs tol 5.6e-2
    rv[c]=f2b(r);
  }
  uint4* op = (uint4*)(rgb_out + (size_t)idx*32);
#pragma unroll
  for(int q2=0;q2<4;q2++){
    uint4 w;
    w.x = (u32)rv[q2*8+0] | ((u32)rv[q2*8+1]<<16);
    w.y = (u32)rv[q2*8+2] | ((u32)rv[q2*8+3]<<16);
    w.z = (u32)rv[q2*8+4] | ((u32)rv[q2*8+5]<<16);
    w.w = (u32)rv[q2*8+6] | ((u32)rv[q2*8+7]<<16);
    op[q2]=w;
  }
}

// ---------------- coarse march + importance sampling (strict f32, thread per ray) ----------------
__global__ void __launch_bounds__(64) k_imp(
  const float* __restrict__ dc, const float* __restrict__ dens,
  const float* __restrict__ u_imp, float* __restrict__ df, float* __restrict__ scal)
{
  __shared__ float scdf[64][30];
  __shared__ float szm [64][30];
  int tid = threadIdx.x;
  int ray = blockIdx.x*64 + tid;   // 0..8191
  float w[31];
  float dprev = dc[ray*32+0];
  float sprev = dens[ray*32+0];
  float T = 1.f;
#pragma unroll
  for(int i=0;i<31;i++){
    float dn = dc[ray*32+i+1];
    float sn = dens[ray*32+i+1];
    if (i<30) szm[tid][i] = fm(0.5f, fa(dprev,dn));
    float delta = fs(dn,dprev);
    float dm = fm(0.5f, fa(sprev,sn));
    float al = fs(1.f, exf(-fm(dm,delta)));
    w[i] = fm(al,T);
    T = fm(T, fa(fs(1.f,al), 1e-10f));
    dprev=dn; sprev=sn;
  }
  // pdf weights: w_sm[j]=0.5*(m[j]+m[j+1])+0.01 (j=1..29), +EPS
  float pdfw[29];
#pragma unroll
  for(int i=0;i<29;i++){
    float m1 = fmaxf(w[i],w[i+1]), m2 = fmaxf(w[i+1],w[i+2]);
    pdfw[i] = fa(fa(fm(0.5f, fa(m1,m2)), 0.01f), 1e-5f);
  }
  // np.sum pairwise (n=29): 8 accumulators, 2 blocked adds, tree, 5 sequential tail
  float sum;
  {
    float r[8];
#pragma unroll
    for(int j=0;j<8;j++) r[j]=pdfw[j];
#pragma unroll
    for(int j=0;j<8;j++) r[j]=fa(r[j],pdfw[8+j]);
#pragma unroll
    for(int j=0;j<8;j++) r[j]=fa(r[j],pdfw[16+j]);
    sum = fa(fa(fa(r[0],r[1]),fa(r[2],r[3])), fa(fa(r[4],r[5]),fa(r[6],r[7])));
#pragma unroll
    for(int i=24;i<29;i++) sum = fa(sum, pdfw[i]);
  }
  // cdf: sequential cumsum of pdf (per-element f32 division)
  {
    float cacc = 0.f;
    scdf[tid][0] = 0.f;
#pragma unroll
    for(int i=1;i<30;i++){
      cacc = fa(cacc, fdv(pdfw[i-1], sum));
      scdf[tid][i] = cacc;
    }
  }

  float fmn=1e30f, fmx=-1e30f;
  for(int k=0;k<32;k++){
    float u = u_imp[ray*32+k];
    // np.searchsorted(cdf, u, 'right') = bisect_right (binary, regardless of monotonicity)
    int lo=0, hi=30;
    while(lo<hi){
      int mid=(lo+hi)>>1;
      if (scdf[tid][mid] <= u) lo = mid+1; else hi = mid;
    }
    int ind = lo;                 // in [1,30]
    int below = ind-1;            // in [0,29]
    int above = (ind>29)?29:ind;  // in [0,29]
    float cdf0 = scdf[tid][below];
    float cdf1 = scdf[tid][above];
    float b0   = szm [tid][below];
    float b1v  = szm [tid][above];
    float den = fs(cdf1,cdf0);
    if((double)den < 1e-5) den = 1.f;      // EPS compare in f64 (python const)
    float sres = fa(b0, fm(fdv(fs(u,cdf0),den), fs(b1v,b0)));
    df[ray*32+k]=sres;
    fmn=fminf(fmn,sres); fmx=fmaxf(fmx,sres);
  }
#pragma unroll
  for(int m=1;m<64;m<<=1){ fmn=fminf(fmn,__shfl_xor(fmn,m)); fmx=fmaxf(fmx,__shfl_xor(fmx,m)); }
  if(tid==0){
    atomicMin(((u32*)scal)+2, fenc(fmn));
    atomicMax(((u32*)scal)+3, fenc(fmx));
  }
}

// ---------------- stable sort (64) + final ray march, strict f32 (wave per ray) ----------------
__global__ void __launch_bounds__(256) k_final(
  const float* __restrict__ dc, const float* __restrict__ df,
  const float* __restrict__ densc, const float* __restrict__ densf,
  const u16* __restrict__ rgbc, const u16* __restrict__ rgbf,
  const float* __restrict__ scal,
  float* __restrict__ out_rgb, float* __restrict__ out_depth, float* __restrict__ out_w)
{
  __shared__ float ssd[4][64];
  __shared__ float ssn[4][64];
  __shared__ int   sp [4][64];
  __shared__ float swv[4][64];   // per-interval weight
  __shared__ float swz[4][64];   // per-interval weight*z_mid
  int wid = threadIdx.x>>6, lane = threadIdx.x&63;
  int ray = blockIdx.x*4 + wid;

  float myd = (lane<32)? dc[ray*32+lane]    : df[ray*32+lane-32];
  float myn = (lane<32)? densc[ray*32+lane] : densf[ray*32+lane-32];
  ssd[wid][lane]=myd; __syncthreads();
  int rk=0;
#pragma unroll 8
  for(int j=0;j<64;j++){
    float dj = ssd[wid][j];
    rk += (dj<myd || (dj==myd && j<lane)) ? 1:0;     // stable argsort rank
  }
  __syncthreads();
  ssd[wid][rk]=myd; ssn[wid][rk]=myn; sp[wid][rk]=lane;
  __syncthreads();

  float T=1.f, accr=0.f;
  int j0 = sp[wid][0];
  float cprev = 0.f;
  if (lane<32){
    const u16* cb = (j0<32)? (rgbc+((size_t)ray*32+j0)*32) : (rgbf+((size_t)ray*32+(j0-32))*32);
    cprev = __uint_as_float(((u32)cb[lane])<<16);
  }
  float d0 = ssd[wid][0], n0 = ssn[wid][0];
  for(int s2=0;s2<63;s2++){
    float d1 = ssd[wid][s2+1], n1 = ssn[wid][s2+1];
    float delta = fs(d1,d0);
    float dm = fm(0.5f, fa(n0,n1));
    float al = fs(1.f, exf(-fm(dm,delta)));
    float wv = fm(al,T);
    T = fm(T, fa(fs(1.f,al), 1e-10f));
    if (lane==s2){ swv[wid][s2]=wv; swz[wid][s2]=fm(wv, fm(0.5f, fa(d0,d1))); }
    int j1 = sp[wid][s2+1];
    float cnext = 0.f;
    if (lane<32){
      const u16* cb = (j1<32)? (rgbc+((size_t)ray*32+j1)*32) : (rgbf+((size_t)ray*32+(j1-32))*32);
      cnext = __uint_as_float(((u32)cb[lane])<<16);
    }
    // comp_rgb: strided axis-2 reduce -> SEQUENTIAL accumulation (numpy)
    accr = fa(accr, fm(wv, fm(0.5f, fa(cprev,cnext))));
    cprev=cnext; d0=d1; n0=n1;
  }
  __syncthreads();
  if(lane<63) out_w[(size_t)ray*63+lane]=swv[wid][lane];
  if(lane<32) out_rgb[(size_t)ray*32+lane]=fs(fm(accr,2.f),1.f);
  if(lane==0){
    // np.sum pairwise (n=63, contiguous): r[j]=sum_k a[8k+j] k=0..6; tree; tail 56..62
    float wsum, zsum;
    {
      float r[8], rz[8];
#pragma unroll
      for(int j=0;j<8;j++){ r[j]=swv[wid][j]; rz[j]=swz[wid][j]; }
      for(int i=8;i<56;i+=8)
#pragma unroll
        for(int j=0;j<8;j++){ r[j]=fa(r[j],swv[wid][i+j]); rz[j]=fa(rz[j],swz[wid][i+j]); }
      wsum = fa(fa(fa(r[0],r[1]),fa(r[2],r[3])), fa(fa(r[4],r[5]),fa(r[6],r[7])));
      zsum = fa(fa(fa(rz[0],rz[1]),fa(rz[2],rz[3])), fa(fa(rz[4],rz[5]),fa(rz[6],rz[7])));
      for(int i=56;i<63;i++){ wsum=fa(wsum,swv[wid][i]); zsum=fa(zsum,swz[wid][i]); }
    }
    float depv = fdv(zsum, wsum);
    if (isnan(depv)) depv = INFINITY;    // nan_to_num(nan=inf)
    float lo = fdec(((const u32*)scal)[2]);
    float hi = fdec(((const u32*)scal)[3]);
    depv = fminf(fmaxf(depv,lo),hi);     // clip to global all_d min/max
    out_depth[ray]=depv;
  }
}

extern "C" void kernel_launch(void* const* d_in, const int* in_sizes, int n_in,
                              void* d_out, int out_size, void* d_ws, size_t ws_size,
                              hipStream_t stream) {
  const float* planes = (const float*)d_in[0];
  const float* ro     = (const float*)d_in[1];
  const float* rdp    = (const float*)d_in[2];
  const float* hmin   = (const float*)d_in[3];
  const float* hmax   = (const float*)d_in[4];
  const float* jitter = (const float*)d_in[5];
  const float* uimp   = (const float*)d_in[6];
  const float* W1     = (const float*)d_in[7];
  const float* b1     = (const float*)d_in[8];
  const float* W2     = (const float*)d_in[9];
  const float* b2     = (const float*)d_in[10];
  const float* sb     = (const float*)d_in[11];
  const int*   hmk    = (const int*)d_in[12];
  float* out = (float*)d_out;
  char* ws = (char*)d_ws;

  size_t off=0;
  auto alloc=[&](size_t bytes){ size_t o=off; off=(off+bytes+255)&~(size_t)255; return o; };
  float* scal = (float*)(ws+alloc(64));
  float* W1t  = (float*)(ws+alloc(2048*4));
  float* pt   = (float*)(ws+alloc((size_t)12582912*4));
  float* dco  = (float*)(ws+alloc((size_t)NSAMP*4));
  float* dfi  = (float*)(ws+alloc((size_t)NSAMP*4));
  float* dnc  = (float*)(ws+alloc((size_t)NSAMP*4));
  float* dnf  = (float*)(ws+alloc((size_t)NSAMP*4));
  u16*   rgc  = (u16*)  (ws+alloc((size_t)NSAMP*32*2));
  u16*   rgf  = (u16*)  (ws+alloc((size_t)NSAMP*32*2));
  (void)in_sizes; (void)n_in; (void)out_size; (void)ws_size;

  float* out_rgb  = out;
  float* out_dep  = out + 262144;
  float* out_w    = out + 270336;
  float* out_psdf = out + 786432;

  k_init<<<dim3(1),dim3(256),0,stream>>>(hmin,hmax,W1,scal,W1t);
  k_tr<<<dim3(12288),dim3(256),0,stream>>>(planes, pt);
  k_eval<0><<<dim3(1024),dim3(256),0,stream>>>(pt,ro,rdp,hmin,hmax,jitter,hmk,W1t,b1,W2,b2,sb,scal,dco,dnc,rgc,out_psdf);
  k_imp<<<dim3(128),dim3(64),0,stream>>>(dco,dnc,uimp,dfi,scal);
  k_eval<1><<<dim3(1024),dim3(256),0,stream>>>(pt,ro,rdp,hmin,hmax,jitter,hmk,W1t,b1,W2,b2,sb,scal,dfi,dnf,rgf,out_psdf);
  k_final<<<dim3(2048),dim3(256),0,stream>>>(dco,dfi,dnc,dnf,rgc,rgf,scal,out_rgb,out_dep,out_w);
}

// Round 17
// 414.149 us; speedup vs baseline: 2.4526x; 1.0251x over previous
//
#include <hip/hip_runtime.h>
#include <hip/hip_bf16.h>
#include <math.h>
#include <stddef.h>

typedef unsigned int u32;
typedef unsigned short u16;
typedef unsigned long long u64;

#define NRAYS 8192      // N_BATCH * N_RAYS
#define NSAMP 262144    // NRAYS * 32

// ---- strict float32 ops (block FMA contraction, numpy-per-op rounding) ----
__device__ __forceinline__ float fa(float a,float b){ return __fadd_rn(a,b); }
__device__ __forceinline__ float fs(float a,float b){ return __fsub_rn(a,b); }
__device__ __forceinline__ float fm(float a,float b){ return __fmul_rn(a,b); }
__device__ __forceinline__ float fdv(float a,float b){ return __fdiv_rn(a,b); }

// ---- fast double exp: |rel err| < ~2^-45, branch-light (march + density path) ----
__device__ __forceinline__ double exp_d(double x){
  const double LOG2E  = 1.4426950408889634074;
  const double LN2_HI = 6.93147180369123816490e-01;
  const double LN2_LO = 1.90821492927058770002e-10;
  double kd = rint(x * LOG2E);
  if (kd >  200.0) return INFINITY;
  if (kd < -200.0) return 0.0;
  int k = (int)kd;
  double r = fma(-kd, LN2_HI, x);
  r = fma(-kd, LN2_LO, r);
  double p = 1.0/39916800.0;
  p = fma(p, r, 1.0/3628800.0);
  p = fma(p, r, 1.0/362880.0);
  p = fma(p, r, 1.0/40320.0);
  p = fma(p, r, 1.0/5040.0);
  p = fma(p, r, 1.0/720.0);
  p = fma(p, r, 1.0/120.0);
  p = fma(p, r, 1.0/24.0);
  p = fma(p, r, 1.0/6.0);
  p = fma(p, r, 0.5);
  p = fma(p, r, 1.0);
  p = fma(p, r, 1.0);
  u64 sb = ((u64)(k + 1023)) << 52;
  return p * __longlong_as_double((long long)sb);
}
__device__ __forceinline__ float exf(float x){ return (float)exp_d((double)x); }
__device__ __forceinline__ float sigm(float x){   // exact-path stepwise f32 sigmoid (density head)
  if (x >= 0.f){ float e = exf(-x); return fdv(1.f, fa(1.f, e)); }
  float e = exf(x); return fdv(e, fa(1.f, e));
}
// fast sigmoid for the rgb head only (abs tolerance 5.6e-2; bf16-quantized anyway)
__device__ __forceinline__ float sigm_fast(float x){
  return 1.f/(1.f + __expf(-x));
}
__device__ __forceinline__ u16 f2b(float f){
  u32 x = __float_as_uint(f);
  return (u16)((x + 0x7fffu + ((x>>16)&1u)) >> 16);   // RNE
}
// monotone float<->u32 key (handles negatives) for atomic min/max
__device__ __forceinline__ u32 fenc(float f){ u32 b=__float_as_uint(f); return (b&0x80000000u)? ~b : (b|0x80000000u); }
__device__ __forceinline__ float fdec(u32 k){ u32 b=(k&0x80000000u)? (k^0x80000000u) : ~k; return __uint_as_float(b); }

// ---------------- init: global min/max of hit depths, scalar slots, W1 transpose ----------------
__global__ void k_init(const float* __restrict__ hmin, const float* __restrict__ hmax,
                       const float* __restrict__ W1, float* __restrict__ scal,
                       float* __restrict__ W1t){
  __shared__ float smn[256], smx[256];
  int t = threadIdx.x;
  float mn = 1e30f, mx = -1e30f;
  for (int i=t;i<NRAYS;i+=256){ mn=fminf(mn,hmin[i]); mx=fmaxf(mx,hmax[i]); }
  smn[t]=mn; smx[t]=mx; __syncthreads();
  for(int s=128;s>0;s>>=1){
    if(t<s){ smn[t]=fminf(smn[t],smn[t+s]); smx[t]=fmaxf(smx[t],smx[t+s]); }
    __syncthreads();
  }
  if(t==0){
    scal[0]=smn[0]; scal[1]=smx[0];
    ((u32*)scal)[2]=0xFFFFFFFFu;  // dmin key (atomicMin on monotone key)
    ((u32*)scal)[3]=0u;           // dmax key (atomicMax)
  }
  for(int i=t;i<2048;i+=256){ int j=i>>5, c=i&31; W1t[i]=W1[c*64+j]; }  // W1t[j*32+c]
}

// ---------------- transpose planes (N,3,C,H,W) f32 -> (N*3,H,W,C) f32 ----------------
__global__ void __launch_bounds__(256) k_tr(const float* __restrict__ pl, float* __restrict__ pt){
  int t = blockIdx.x*256 + threadIdx.x;     // 0 .. 3145727
  int x  = t & 255;
  int c4 = ((t>>8)&7)<<2;
  int y  = (t>>11)&255;
  int np = t>>19;                            // 0..5
  const float* ip = pl + (((size_t)(np*32+c4))<<16) + (y<<8) + x;
  float4 o;
  o.x = ip[0];
  o.y = ip[65536];
  o.z = ip[131072];
  o.w = ip[196608];
  *reinterpret_cast<float4*>(pt + ((((size_t)(np<<8|y))<<8|x)<<5) + c4) = o;
}

// ---------------- point evaluation (sampling + decoder), strict f32 ----------------
// r16 wave-cooperative gather + PHASE-A COORD STAGING: each lane computes its own
// point's cx,cy,cz once (bit-identical r9 ops) and parks them in LDS; gather
// rounds read coords from LDS (no dependent global prologue per round) and issue
// only the 12 independent texel loads; unroll-2 lets rounds overlap in flight.
template<int PHASE>
__global__ void __launch_bounds__(256) k_eval(
  const float* __restrict__ pt, const float* __restrict__ ro, const float* __restrict__ rd,
  const float* __restrict__ hmin, const float* __restrict__ hmax,
  const float* __restrict__ jitter, const int* __restrict__ hitmask,
  const float* __restrict__ W1t, const float* __restrict__ b1,
  const float* __restrict__ W2, const float* __restrict__ b2,
  const float* __restrict__ sb, float* __restrict__ scal,
  float* __restrict__ dep, float* __restrict__ dens_out, u16* __restrict__ rgb_out,
  float* __restrict__ out_psdf)
{
  __shared__ float sfeat[4][64][33];   // stride 33: conflict-free b32 access
  __shared__ float scrd [4][3][64];    // staged cx,cy,cz (lane-stride-1, conflict-free)
  int tid = threadIdx.x;
  int wid = tid>>6, lane = tid&63;
  int blockbase = blockIdx.x*256;
  int idx = blockbase + tid;           // own point 0..262143
  int ray = idx >> 5;
  int s   = idx & 31;
  int n   = ray >> 12;
  int msk = hitmask[ray];

  // ---- Phase A: own-point depth (r9 exact), dep store, global min/max, coords ----
  float d;
  if (PHASE==0){
    float hmn = msk ? hmin[ray] : scal[0];
    float hmx = msk ? hmax[ray] : scal[1];
    float span = fs(hmx, hmn);
    float jit  = jitter[idx];
    float base = (float)((double)s * (1.0/31.0));   // np.linspace f64 arange*step -> f32 cast
    if (s==31) base = 1.0f;
    float t1 = fdv(fm(jit, span), 32.0f);
    d = fa(fm(fa(base, t1), span), hmn);
    dep[idx] = d;
    float dm=d, dM=d;
#pragma unroll
    for (int m=1;m<64;m<<=1){ dm=fminf(dm,__shfl_xor(dm,m)); dM=fmaxf(dM,__shfl_xor(dM,m)); }
    if ((tid & 63)==0){
      atomicMin(((u32*)scal)+2, fenc(dm));
      atomicMax(((u32*)scal)+3, fenc(dM));
    }
  } else {
    d = dep[idx];
  }

  float tsdf;
  {
    const float sc2 = (float)(2.0/6.0);
    float ox=ro[ray*3+0], oy=ro[ray*3+1], oz=ro[ray*3+2];
    float dx=rd[ray*3+0], dy=rd[ray*3+1], dz=rd[ray*3+2];
    float px = fa(ox, fm(d,dx)), py = fa(oy, fm(d,dy)), pz = fa(oz, fm(d,dz));
    float nrm = __fsqrt_rn(fa(fa(fm(px,px),fm(py,py)),fm(pz,pz)));
    tsdf = fs(nrm, 0.5f);
    scrd[wid][0][lane] = fm(px,sc2);
    scrd[wid][1][lane] = fm(py,sc2);
    scrd[wid][2][lane] = fm(pz,sc2);
  }
  __syncthreads();

  // ---- Phase B: cooperative gather, 8 rounds x 8 points, lane=(pg,q) ----
  int pg = lane >> 3;      // point within round
  int q  = lane & 7;       // 4-channel chunk
#pragma unroll 2
  for (int r=0;r<8;r++){
    int pidx = r*8 + pg;                 // point index within wave
    int n2   = ((blockbase + (wid<<6) + pidx) >> 17);   // batch of that point
    float cx = scrd[wid][0][pidx];
    float cy = scrd[wid][1][pidx];
    float cz = scrd[wid][2][pidx];

    float fchunk[4];
#pragma unroll
    for(int i=0;i<4;i++) fchunk[i]=0.f;

#pragma unroll
    for (int p=0;p<3;p++){
      float u = (p==2)?cz:cx;                  // plane0:(x,y) plane1:(x,z) plane2:(z,y)
      float v = (p==1)?cz:cy;
      float fx = fs(fm(fa(u,1.f),128.f),0.5f); // (u+1)*128-0.5 per-op
      float fy = fs(fm(fa(v,1.f),128.f),0.5f);
      float x0f = floorf(fx), y0f = floorf(fy);
      float wx = fs(fx,x0f), wy = fs(fy,y0f);
      float ax0 = fs(1.f,wx), ax1 = wx, ay0 = fs(1.f,wy), ay1 = wy;
      int x0, y0;
      { // saturating cast
        x0 = (x0f >= 2.1e9f) ? 2147483647 : ((x0f <= -2.1e9f) ? (-2147483647-1) : (int)x0f);
        y0 = (y0f >= 2.1e9f) ? 2147483647 : ((y0f <= -2.1e9f) ? (-2147483647-1) : (int)y0f);
      }
      int x1=x0+1, y1=y0+1;
      bool vx0 = (x0>=0 && x0<256), vx1 = (x1>=0 && x1<256);
      bool vy0 = (y0>=0 && y0<256), vy1 = (y1>=0 && y1<256);
      bool ok00 = vx0&&vy0, ok01 = vx1&&vy0, ok10 = vx0&&vy1, ok11 = vx1&&vy1;
      int cx0=min(max(x0,0),255), cx1=min(max(x1,0),255);
      int cy0=min(max(y0,0),255), cy1=min(max(y1,0),255);
      size_t pb = ((size_t)(n2*3+p))<<16;
      int qo = q<<2;   // chunk float offset within texel
      const float4* t00 = (const float4*)(pt + ((pb + (cy0<<8) + cx0)<<5) + qo);
      const float4* t01 = (const float4*)(pt + ((pb + (cy0<<8) + cx1)<<5) + qo);
      const float4* t10 = (const float4*)(pt + ((pb + (cy1<<8) + cx0)<<5) + qo);
      const float4* t11 = (const float4*)(pt + ((pb + (cy1<<8) + cx1)<<5) + qo);
      float4 v00 = *t00, v01 = *t01, v10 = *t10, v11 = *t11;
      float e0,e1,e2,e3, t_;
#define CORNER_SUM(FLD, OUTI) \
      e0 = ok00 ? v00.FLD : 0.f; e1 = ok01 ? v01.FLD : 0.f; \
      e2 = ok10 ? v10.FLD : 0.f; e3 = ok11 ? v11.FLD : 0.f; \
      t_ = fa(fa(fa(fm(fm(e0,ax0),ay0), fm(fm(e1,ax1),ay0)), fm(fm(e2,ax0),ay1)), fm(fm(e3,ax1),ay1)); \
      fchunk[OUTI] = fa(fchunk[OUTI], t_);
      CORNER_SUM(x,0) CORNER_SUM(y,1) CORNER_SUM(z,2) CORNER_SUM(w,3)
#undef CORNER_SUM
    }
#pragma unroll
    for(int i=0;i<4;i++)
      sfeat[wid][pidx][q*4+i] = fdv(fchunk[i], 3.0f);   // np.mean: (f0+f1)+f2 then /3
  }
  __syncthreads();

  // ---- Phase C: own feat from LDS (stride-33 -> 2-way alias, free) + r9 decoder ----
  float feat[32];
#pragma unroll
  for(int c=0;c<32;c++) feat[c] = sfeat[wid][lane][c];

  float o[33];
#pragma unroll
  for(int k=0;k<33;k++) o[k]=0.f;
#pragma unroll 2
  for(int j=0;j<64;j++){
    float a = 0.f;
#pragma unroll
    for(int c=0;c<32;c++) a = fmaf(feat[c], W1t[j*32+c], a);
    a = fa(a, b1[j]);
    // native-HW stable softplus: v_exp_f32 + v_log_f32 (r9-verified)
    float h = fa(fmaxf(a,0.f), __logf(fa(1.f, __expf(-fabsf(a)))));
#pragma unroll
    for(int k=0;k<33;k++) o[k] = fmaf(h, W2[j*33+k], o[k]);
  }
#pragma unroll
  for(int k=0;k<33;k++) o[k] = fa(o[k], b2[k]);

  float beta = fmaxf(sb[0], 0.002f);
  float raw = o[0];
  out_psdf[((size_t)n<<18) + ((size_t)PHASE<<17) + (size_t)(ray&4095)*32 + s] = raw;  // unmasked
  float sg = fa(raw, tsdf);
  float dens = msk ? fdv(sigm(fdv(-sg, beta)), beta) : 0.f;   // exact path (chaotic cdf chain)
  dens_out[idx]=dens;

  u16 rv[32];
#pragma unroll
  for(int c=0;c<32;c++){
    float r = msk ? fs(fm(sigm_fast(o[c+1]), 1.002f), 0.001f) : 0.f;  // fast path, abs tol 5.6e-2
    rv[c]=f2b(r);
  }
  uint4* op = (uint4*)(rgb_out + (size_t)idx*32);
#pragma unroll
  for(int q2=0;q2<4;q2++){
    uint4 w;
    w.x = (u32)rv[q2*8+0] | ((u32)rv[q2*8+1]<<16);
    w.y = (u32)rv[q2*8+2] | ((u32)rv[q2*8+3]<<16);
    w.z = (u32)rv[q2*8+4] | ((u32)rv[q2*8+5]<<16);
    w.w = (u32)rv[q2*8+6] | ((u32)rv[q2*8+7]<<16);
    op[q2]=w;
  }
}

// ---------------- coarse march + importance sampling (strict f32, thread per ray) ----------------
__global__ void __launch_bounds__(64) k_imp(
  const float* __restrict__ dc, const float* __restrict__ dens,
  const float* __restrict__ u_imp, float* __restrict__ df, float* __restrict__ scal)
{
  __shared__ float scdf[64][30];
  __shared__ float szm [64][30];
  int tid = threadIdx.x;
  int ray = blockIdx.x*64 + tid;   // 0..8191
  float w[31];
  float dprev = dc[ray*32+0];
  float sprev = dens[ray*32+0];
  float T = 1.f;
#pragma unroll
  for(int i=0;i<31;i++){
    float dn = dc[ray*32+i+1];
    float sn = dens[ray*32+i+1];
    if (i<30) szm[tid][i] = fm(0.5f, fa(dprev,dn));
    float delta = fs(dn,dprev);
    float dm = fm(0.5f, fa(sprev,sn));
    float al = fs(1.f, exf(-fm(dm,delta)));
    w[i] = fm(al,T);
    T = fm(T, fa(fs(1.f,al), 1e-10f));
    dprev=dn; sprev=sn;
  }
  // pdf weights: w_sm[j]=0.5*(m[j]+m[j+1])+0.01 (j=1..29), +EPS
  float pdfw[29];
#pragma unroll
  for(int i=0;i<29;i++){
    float m1 = fmaxf(w[i],w[i+1]), m2 = fmaxf(w[i+1],w[i+2]);
    pdfw[i] = fa(fa(fm(0.5f, fa(m1,m2)), 0.01f), 1e-5f);
  }
  // np.sum pairwise (n=29): 8 accumulators, 2 blocked adds, tree, 5 sequential tail
  float sum;
  {
    float r[8];
#pragma unroll
    for(int j=0;j<8;j++) r[j]=pdfw[j];
#pragma unroll
    for(int j=0;j<8;j++) r[j]=fa(r[j],pdfw[8+j]);
#pragma unroll
    for(int j=0;j<8;j++) r[j]=fa(r[j],pdfw[16+j]);
    sum = fa(fa(fa(r[0],r[1]),fa(r[2],r[3])), fa(fa(r[4],r[5]),fa(r[6],r[7])));
#pragma unroll
    for(int i=24;i<29;i++) sum = fa(sum, pdfw[i]);
  }
  // cdf: sequential cumsum of pdf (per-element f32 division)
  {
    float cacc = 0.f;
    scdf[tid][0] = 0.f;
#pragma unroll
    for(int i=1;i<30;i++){
      cacc = fa(cacc, fdv(pdfw[i-1], sum));
      scdf[tid][i] = cacc;
    }
  }

  float fmn=1e30f, fmx=-1e30f;
  for(int k=0;k<32;k++){
    float u = u_imp[ray*32+k];
    // np.searchsorted(cdf, u, 'right') = bisect_right (binary, regardless of monotonicity)
    int lo=0, hi=30;
    while(lo<hi){
      int mid=(lo+hi)>>1;
      if (scdf[tid][mid] <= u) lo = mid+1; else hi = mid;
    }
    int ind = lo;                 // in [1,30]
    int below = ind-1;            // in [0,29]
    int above = (ind>29)?29:ind;  // in [0,29]
    float cdf0 = scdf[tid][below];
    float cdf1 = scdf[tid][above];
    float b0   = szm [tid][below];
    float b1v  = szm [tid][above];
    float den = fs(cdf1,cdf0);
    if((double)den < 1e-5) den = 1.f;      // EPS compare in f64 (python const)
    float sres = fa(b0, fm(fdv(fs(u,cdf0),den), fs(b1v,b0)));
    df[ray*32+k]=sres;
    fmn=fminf(fmn,sres); fmx=fmaxf(fmx,sres);
  }
#pragma unroll
  for(int m=1;m<64;m<<=1){ fmn=fminf(fmn,__shfl_xor(fmn,m)); fmx=fmaxf(fmx,__shfl_xor(fmx,m)); }
  if(tid==0){
    atomicMin(((u32*)scal)+2, fenc(fmn));
    atomicMax(((u32*)scal)+3, fenc(fmx));
  }
}

// ---------------- stable sort (64) + final ray march, strict f32 (wave per ray) ----------------
__global__ void __launch_bounds__(256) k_final(
  const float* __restrict__ dc, const float* __restrict__ df,
  const float* __restrict__ densc, const float* __restrict__ densf,
  const u16* __restrict__ rgbc, const u16* __restrict__ rgbf,
  const float* __restrict__ scal,
  float* __restrict__ out_rgb, float* __restrict__ out_depth, float* __restrict__ out_w)
{
  __shared__ float ssd[4][64];
  __shared__ float ssn[4][64];
  __shared__ int   sp [4][64];
  __shared__ float swv[4][64];   // per-interval weight
  __shared__ float swz[4][64];   // per-interval weight*z_mid
  int wid = threadIdx.x>>6, lane = threadIdx.x&63;
  int ray = blockIdx.x*4 + wid;

  float myd = (lane<32)? dc[ray*32+lane]    : df[ray*32+lane-32];
  float myn = (lane<32)? densc[ray*32+lane] : densf[ray*32+lane-32];
  ssd[wid][lane]=myd; __syncthreads();
  int rk=0;
#pragma unroll 8
  for(int j=0;j<64;j++){
    float dj = ssd[wid][j];
    rk += (dj<myd || (dj==myd && j<lane)) ? 1:0;     // stable argsort rank
  }
  __syncthreads();
  ssd[wid][rk]=myd; ssn[wid][rk]=myn; sp[wid][rk]=lane;
  __syncthreads();

  float T=1.f, accr=0.f;
  int j0 = sp[wid][0];
  float cprev = 0.f;
  if (lane<32){
    const u16* cb = (j0<32)? (rgbc+((size_t)ray*32+j0)*32) : (rgbf+((size_t)ray*32+(j0-32))*32);
    cprev = __uint_as_float(((u32)cb[lane])<<16);
  }
  float d0 = ssd[wid][0], n0 = ssn[wid][0];
  for(int s2=0;s2<63;s2++){
    float d1 = ssd[wid][s2+1], n1 = ssn[wid][s2+1];
    float delta = fs(d1,d0);
    float dm = fm(0.5f, fa(n0,n1));
    float al = fs(1.f, exf(-fm(dm,delta)));
    float wv = fm(al,T);
    T = fm(T, fa(fs(1.f,al), 1e-10f));
    if (lane==s2){ swv[wid][s2]=wv; swz[wid][s2]=fm(wv, fm(0.5f, fa(d0,d1))); }
    int j1 = sp[wid][s2+1];
    float cnext = 0.f;
    if (lane<32){
      const u16* cb = (j1<32)? (rgbc+((size_t)ray*32+j1)*32) : (rgbf+((size_t)ray*32+(j1-32))*32);
      cnext = __uint_as_float(((u32)cb[lane])<<16);
    }
    // comp_rgb: strided axis-2 reduce -> SEQUENTIAL accumulation (numpy)
    accr = fa(accr, fm(wv, fm(0.5f, fa(cprev,cnext))));
    cprev=cnext; d0=d1; n0=n1;
  }
  __syncthreads();
  if(lane<63) out_w[(size_t)ray*63+lane]=swv[wid][lane];
  if(lane<32) out_rgb[(size_t)ray*32+lane]=fs(fm(accr,2.f),1.f);
  if(lane==0){
    // np.sum pairwise (n=63, contiguous): r[j]=sum_k a[8k+j] k=0..6; tree; tail 56..62
    float wsum, zsum;
    {
      float r[8], rz[8];
#pragma unroll
      for(int j=0;j<8;j++){ r[j]=swv[wid][j]; rz[j]=swz[wid][j]; }
      for(int i=8;i<56;i+=8)
#pragma unroll
        for(int j=0;j<8;j++){ r[j]=fa(r[j],swv[wid][i+j]); rz[j]=fa(rz[j],swz[wid][i+j]); }
      wsum = fa(fa(fa(r[0],r[1]),fa(r[2],r[3])), fa(fa(r[4],r[5]),fa(r[6],r[7])));
      zsum = fa(fa(fa(rz[0],rz[1]),fa(rz[2],rz[3])), fa(fa(rz[4],rz[5]),fa(rz[6],rz[7])));
      for(int i=56;i<63;i++){ wsum=fa(wsum,swv[wid][i]); zsum=fa(zsum,swz[wid][i]); }
    }
    float depv = fdv(zsum, wsum);
    if (isnan(depv)) depv = INFINITY;    // nan_to_num(nan=inf)
    float lo = fdec(((const u32*)scal)[2]);
    float hi = fdec(((const u32*)scal)[3]);
    depv = fminf(fmaxf(depv,lo),hi);     // clip to global all_d min/max
    out_depth[ray]=depv;
  }
}

extern "C" void kernel_launch(void* const* d_in, const int* in_sizes, int n_in,
                              void* d_out, int out_size, void* d_ws, size_t ws_size,
                              hipStream_t stream) {
  const float* planes = (const float*)d_in[0];
  const float* ro     = (const float*)d_in[1];
  const float* rdp    = (const float*)d_in[2];
  const float* hmin   = (const float*)d_in[3];
  const float* hmax   = (const float*)d_in[4];
  const float* jitter = (const float*)d_in[5];
  const float* uimp   = (const float*)d_in[6];
  const float* W1     = (const float*)d_in[7];
  const float* b1     = (const float*)d_in[8];
  const float* W2     = (const float*)d_in[9];
  const float* b2     = (const float*)d_in[10];
  const float* sb     = (const float*)d_in[11];
  const int*   hmk    = (const int*)d_in[12];
  float* out = (float*)d_out;
  char* ws = (char*)d_ws;

  size_t off=0;
  auto alloc=[&](size_t bytes){ size_t o=off; off=(off+bytes+255)&~(size_t)255; return o; };
  float* scal = (float*)(ws+alloc(64));
  float* W1t  = (float*)(ws+alloc(2048*4));
  float* pt   = (float*)(ws+alloc((size_t)12582912*4));
  float* dco  = (float*)(ws+alloc((size_t)NSAMP*4));
  float* dfi  = (float*)(ws+alloc((size_t)NSAMP*4));
  float* dnc  = (float*)(ws+alloc((size_t)NSAMP*4));
  float* dnf  = (float*)(ws+alloc((size_t)NSAMP*4));
  u16*   rgc  = (u16*)  (ws+alloc((size_t)NSAMP*32*2));
  u16*   rgf  = (u16*)  (ws+alloc((size_t)NSAMP*32*2));
  (void)in_sizes; (void)n_in; (void)out_size; (void)ws_size;

  float* out_rgb  = out;
  float* out_dep  = out + 262144;
  float* out_w    = out + 270336;
  float* out_psdf = out + 786432;

  k_init<<<dim3(1),dim3(256),0,stream>>>(hmin,hmax,W1,scal,W1t);
  k_tr<<<dim3(12288),dim3(256),0,stream>>>(planes, pt);
  k_eval<0><<<dim3(1024),dim3(256),0,stream>>>(pt,ro,rdp,hmin,hmax,jitter,hmk,W1t,b1,W2,b2,sb,scal,dco,dnc,rgc,out_psdf);
  k_imp<<<dim3(128),dim3(64),0,stream>>>(dco,dnc,uimp,dfi,scal);
  k_eval<1><<<dim3(1024),dim3(256),0,stream>>>(pt,ro,rdp,hmin,hmax,jitter,hmk,W1t,b1,W2,b2,sb,scal,dfi,dnf,rgf,out_psdf);
  k_final<<<dim3(2048),dim3(256),0,stream>>>(dco,dfi,dnc,dnf,rgc,rgf,scal,out_rgb,out_dep,out_w);
}

// Round 18
// 411.635 us; speedup vs baseline: 2.4676x; 1.0061x over previous
//
#include <hip/hip_runtime.h>
#include <hip/hip_bf16.h>
#include <math.h>
#include <stddef.h>

typedef unsigned int u32;
typedef unsigned short u16;
typedef unsigned long long u64;

#define NRAYS 8192      // N_BATCH * N_RAYS
#define NSAMP 262144    // NRAYS * 32

// ---- strict float32 ops (block FMA contraction, numpy-per-op rounding) ----
__device__ __forceinline__ float fa(float a,float b){ return __fadd_rn(a,b); }
__device__ __forceinline__ float fs(float a,float b){ return __fsub_rn(a,b); }
__device__ __forceinline__ float fm(float a,float b){ return __fmul_rn(a,b); }
__device__ __forceinline__ float fdv(float a,float b){ return __fdiv_rn(a,b); }

// ---- fast double exp: |rel err| < ~2^-45, branch-light (march + density path) ----
__device__ __forceinline__ double exp_d(double x){
  const double LOG2E  = 1.4426950408889634074;
  const double LN2_HI = 6.93147180369123816490e-01;
  const double LN2_LO = 1.90821492927058770002e-10;
  double kd = rint(x * LOG2E);
  if (kd >  200.0) return INFINITY;
  if (kd < -200.0) return 0.0;
  int k = (int)kd;
  double r = fma(-kd, LN2_HI, x);
  r = fma(-kd, LN2_LO, r);
  double p = 1.0/39916800.0;
  p = fma(p, r, 1.0/3628800.0);
  p = fma(p, r, 1.0/362880.0);
  p = fma(p, r, 1.0/40320.0);
  p = fma(p, r, 1.0/5040.0);
  p = fma(p, r, 1.0/720.0);
  p = fma(p, r, 1.0/120.0);
  p = fma(p, r, 1.0/24.0);
  p = fma(p, r, 1.0/6.0);
  p = fma(p, r, 0.5);
  p = fma(p, r, 1.0);
  p = fma(p, r, 1.0);
  u64 sb = ((u64)(k + 1023)) << 52;
  return p * __longlong_as_double((long long)sb);
}
__device__ __forceinline__ float exf(float x){ return (float)exp_d((double)x); }
__device__ __forceinline__ float sigm(float x){   // exact-path stepwise f32 sigmoid (density head)
  if (x >= 0.f){ float e = exf(-x); return fdv(1.f, fa(1.f, e)); }
  float e = exf(x); return fdv(e, fa(1.f, e));
}
// fast sigmoid for the rgb head only (abs tolerance 5.6e-2; bf16-quantized anyway)
__device__ __forceinline__ float sigm_fast(float x){
  return 1.f/(1.f + __expf(-x));
}
__device__ __forceinline__ u16 f2b(float f){
  u32 x = __float_as_uint(f);
  return (u16)((x + 0x7fffu + ((x>>16)&1u)) >> 16);   // RNE
}
// monotone float<->u32 key (handles negatives) for atomic min/max
__device__ __forceinline__ u32 fenc(float f){ u32 b=__float_as_uint(f); return (b&0x80000000u)? ~b : (b|0x80000000u); }
__device__ __forceinline__ float fdec(u32 k){ u32 b=(k&0x80000000u)? (k^0x80000000u) : ~k; return __uint_as_float(b); }

// ---------------- init: global min/max of hit depths, scalar slots, W1 transpose ----------------
__global__ void k_init(const float* __restrict__ hmin, const float* __restrict__ hmax,
                       const float* __restrict__ W1, float* __restrict__ scal,
                       float* __restrict__ W1t){
  __shared__ float smn[256], smx[256];
  int t = threadIdx.x;
  float mn = 1e30f, mx = -1e30f;
  for (int i=t;i<NRAYS;i+=256){ mn=fminf(mn,hmin[i]); mx=fmaxf(mx,hmax[i]); }
  smn[t]=mn; smx[t]=mx; __syncthreads();
  for(int s=128;s>0;s>>=1){
    if(t<s){ smn[t]=fminf(smn[t],smn[t+s]); smx[t]=fmaxf(smx[t],smx[t+s]); }
    __syncthreads();
  }
  if(t==0){
    scal[0]=smn[0]; scal[1]=smx[0];
    ((u32*)scal)[2]=0xFFFFFFFFu;  // dmin key (atomicMin on monotone key)
    ((u32*)scal)[3]=0u;           // dmax key (atomicMax)
  }
  for(int i=t;i<2048;i+=256){ int j=i>>5, c=i&31; W1t[i]=W1[c*64+j]; }  // W1t[j*32+c]
}

// ---------------- transpose planes (N,3,C,H,W) f32 -> (N*3,H,W,C) f32 ----------------
__global__ void __launch_bounds__(256) k_tr(const float* __restrict__ pl, float* __restrict__ pt){
  int t = blockIdx.x*256 + threadIdx.x;     // 0 .. 3145727
  int x  = t & 255;
  int c4 = ((t>>8)&7)<<2;
  int y  = (t>>11)&255;
  int np = t>>19;                            // 0..5
  const float* ip = pl + (((size_t)(np*32+c4))<<16) + (y<<8) + x;
  float4 o;
  o.x = ip[0];
  o.y = ip[65536];
  o.z = ip[131072];
  o.w = ip[196608];
  *reinterpret_cast<float4*>(pt + ((((size_t)(np<<8|y))<<8|x)<<5) + c4) = o;
}

// ---------------- point evaluation (sampling + decoder), strict f32 ----------------
// r16 wave-cooperative gather + PHASE-A COORD STAGING: each lane computes its own
// point's cx,cy,cz once (bit-identical r9 ops) and parks them in LDS; gather
// rounds read coords from LDS (no dependent global prologue per round) and issue
// only the 12 independent texel loads; unroll-2 lets rounds overlap in flight.
template<int PHASE>
__global__ void __launch_bounds__(256) k_eval(
  const float* __restrict__ pt, const float* __restrict__ ro, const float* __restrict__ rd,
  const float* __restrict__ hmin, const float* __restrict__ hmax,
  const float* __restrict__ jitter, const int* __restrict__ hitmask,
  const float* __restrict__ W1t, const float* __restrict__ b1,
  const float* __restrict__ W2, const float* __restrict__ b2,
  const float* __restrict__ sb, float* __restrict__ scal,
  float* __restrict__ dep, float* __restrict__ dens_out, u16* __restrict__ rgb_out,
  float* __restrict__ out_psdf)
{
  __shared__ float sfeat[4][64][33];   // stride 33: conflict-free b32 access
  __shared__ float scrd [4][3][64];    // staged cx,cy,cz (lane-stride-1, conflict-free)
  int tid = threadIdx.x;
  int wid = tid>>6, lane = tid&63;
  int blockbase = blockIdx.x*256;
  int idx = blockbase + tid;           // own point 0..262143
  int ray = idx >> 5;
  int s   = idx & 31;
  int n   = ray >> 12;
  int msk = hitmask[ray];

  // ---- Phase A: own-point depth (r9 exact), dep store, global min/max, coords ----
  float d;
  if (PHASE==0){
    float hmn = msk ? hmin[ray] : scal[0];
    float hmx = msk ? hmax[ray] : scal[1];
    float span = fs(hmx, hmn);
    float jit  = jitter[idx];
    float base = (float)((double)s * (1.0/31.0));   // np.linspace f64 arange*step -> f32 cast
    if (s==31) base = 1.0f;
    float t1 = fdv(fm(jit, span), 32.0f);
    d = fa(fm(fa(base, t1), span), hmn);
    dep[idx] = d;
    float dm=d, dM=d;
#pragma unroll
    for (int m=1;m<64;m<<=1){ dm=fminf(dm,__shfl_xor(dm,m)); dM=fmaxf(dM,__shfl_xor(dM,m)); }
    if ((tid & 63)==0){
      atomicMin(((u32*)scal)+2, fenc(dm));
      atomicMax(((u32*)scal)+3, fenc(dM));
    }
  } else {
    d = dep[idx];
  }

  float tsdf;
  {
    const float sc2 = (float)(2.0/6.0);
    float ox=ro[ray*3+0], oy=ro[ray*3+1], oz=ro[ray*3+2];
    float dx=rd[ray*3+0], dy=rd[ray*3+1], dz=rd[ray*3+2];
    float px = fa(ox, fm(d,dx)), py = fa(oy, fm(d,dy)), pz = fa(oz, fm(d,dz));
    float nrm = __fsqrt_rn(fa(fa(fm(px,px),fm(py,py)),fm(pz,pz)));
    tsdf = fs(nrm, 0.5f);
    scrd[wid][0][lane] = fm(px,sc2);
    scrd[wid][1][lane] = fm(py,sc2);
    scrd[wid][2][lane] = fm(pz,sc2);
  }
  __syncthreads();

  // ---- Phase B: cooperative gather, 8 rounds x 8 points, lane=(pg,q) ----
  int pg = lane >> 3;      // point within round
  int q  = lane & 7;       // 4-channel chunk
#pragma unroll 2
  for (int r=0;r<8;r++){
    int pidx = r*8 + pg;                 // point index within wave
    int n2   = ((blockbase + (wid<<6) + pidx) >> 17);   // batch of that point
    float cx = scrd[wid][0][pidx];
    float cy = scrd[wid][1][pidx];
    float cz = scrd[wid][2][pidx];

    float fchunk[4];
#pragma unroll
    for(int i=0;i<4;i++) fchunk[i]=0.f;

#pragma unroll
    for (int p=0;p<3;p++){
      float u = (p==2)?cz:cx;                  // plane0:(x,y) plane1:(x,z) plane2:(z,y)
      float v = (p==1)?cz:cy;
      float fx = fs(fm(fa(u,1.f),128.f),0.5f); // (u+1)*128-0.5 per-op
      float fy = fs(fm(fa(v,1.f),128.f),0.5f);
      float x0f = floorf(fx), y0f = floorf(fy);
      float wx = fs(fx,x0f), wy = fs(fy,y0f);
      float ax0 = fs(1.f,wx), ax1 = wx, ay0 = fs(1.f,wy), ay1 = wy;
      int x0, y0;
      { // saturating cast
        x0 = (x0f >= 2.1e9f) ? 2147483647 : ((x0f <= -2.1e9f) ? (-2147483647-1) : (int)x0f);
        y0 = (y0f >= 2.1e9f) ? 2147483647 : ((y0f <= -2.1e9f) ? (-2147483647-1) : (int)y0f);
      }
      int x1=x0+1, y1=y0+1;
      bool vx0 = (x0>=0 && x0<256), vx1 = (x1>=0 && x1<256);
      bool vy0 = (y0>=0 && y0<256), vy1 = (y1>=0 && y1<256);
      bool ok00 = vx0&&vy0, ok01 = vx1&&vy0, ok10 = vx0&&vy1, ok11 = vx1&&vy1;
      int cx0=min(max(x0,0),255), cx1=min(max(x1,0),255);
      int cy0=min(max(y0,0),255), cy1=min(max(y1,0),255);
      size_t pb = ((size_t)(n2*3+p))<<16;
      int qo = q<<2;   // chunk float offset within texel
      const float4* t00 = (const float4*)(pt + ((pb + (cy0<<8) + cx0)<<5) + qo);
      const float4* t01 = (const float4*)(pt + ((pb + (cy0<<8) + cx1)<<5) + qo);
      const float4* t10 = (const float4*)(pt + ((pb + (cy1<<8) + cx0)<<5) + qo);
      const float4* t11 = (const float4*)(pt + ((pb + (cy1<<8) + cx1)<<5) + qo);
      float4 v00 = *t00, v01 = *t01, v10 = *t10, v11 = *t11;
      float e0,e1,e2,e3, t_;
#define CORNER_SUM(FLD, OUTI) \
      e0 = ok00 ? v00.FLD : 0.f; e1 = ok01 ? v01.FLD : 0.f; \
      e2 = ok10 ? v10.FLD : 0.f; e3 = ok11 ? v11.FLD : 0.f; \
      t_ = fa(fa(fa(fm(fm(e0,ax0),ay0), fm(fm(e1,ax1),ay0)), fm(fm(e2,ax0),ay1)), fm(fm(e3,ax1),ay1)); \
      fchunk[OUTI] = fa(fchunk[OUTI], t_);
      CORNER_SUM(x,0) CORNER_SUM(y,1) CORNER_SUM(z,2) CORNER_SUM(w,3)
#undef CORNER_SUM
    }
#pragma unroll
    for(int i=0;i<4;i++)
      sfeat[wid][pidx][q*4+i] = fdv(fchunk[i], 3.0f);   // np.mean: (f0+f1)+f2 then /3
  }
  __syncthreads();

  // ---- Phase C: own feat from LDS (stride-33 -> 2-way alias, free) + r9 decoder ----
  float feat[32];
#pragma unroll
  for(int c=0;c<32;c++) feat[c] = sfeat[wid][lane][c];

  float o[33];
#pragma unroll
  for(int k=0;k<33;k++) o[k]=0.f;
#pragma unroll 2
  for(int j=0;j<64;j++){
    float a = 0.f;
#pragma unroll
    for(int c=0;c<32;c++) a = fmaf(feat[c], W1t[j*32+c], a);
    a = fa(a, b1[j]);
    // native-HW stable softplus: v_exp_f32 + v_log_f32 (r9-verified)
    float h = fa(fmaxf(a,0.f), __logf(fa(1.f, __expf(-fabsf(a)))));
#pragma unroll
    for(int k=0;k<33;k++) o[k] = fmaf(h, W2[j*33+k], o[k]);
  }
#pragma unroll
  for(int k=0;k<33;k++) o[k] = fa(o[k], b2[k]);

  float beta = fmaxf(sb[0], 0.002f);
  float raw = o[0];
  out_psdf[((size_t)n<<18) + ((size_t)PHASE<<17) + (size_t)(ray&4095)*32 + s] = raw;  // unmasked
  float sg = fa(raw, tsdf);
  float dens = msk ? fdv(sigm(fdv(-sg, beta)), beta) : 0.f;   // exact path (chaotic cdf chain)
  dens_out[idx]=dens;

  u16 rv[32];
#pragma unroll
  for(int c=0;c<32;c++){
    float r = msk ? fs(fm(sigm_fast(o[c+1]), 1.002f), 0.001f) : 0.f;  // fast path, abs tol 5.6e-2
    rv[c]=f2b(r);
  }
  uint4* op = (uint4*)(rgb_out + (size_t)idx*32);
#pragma unroll
  for(int q2=0;q2<4;q2++){
    uint4 w;
    w.x = (u32)rv[q2*8+0] | ((u32)rv[q2*8+1]<<16);
    w.y = (u32)rv[q2*8+2] | ((u32)rv[q2*8+3]<<16);
    w.z = (u32)rv[q2*8+4] | ((u32)rv[q2*8+5]<<16);
    w.w = (u32)rv[q2*8+6] | ((u32)rv[q2*8+7]<<16);
    op[q2]=w;
  }
}

// ---------------- coarse march + importance sampling (strict f32, thread per ray) ----------------
__global__ void __launch_bounds__(64) k_imp(
  const float* __restrict__ dc, const float* __restrict__ dens,
  const float* __restrict__ u_imp, float* __restrict__ df, float* __restrict__ scal)
{
  __shared__ float scdf[64][30];
  __shared__ float szm [64][30];
  int tid = threadIdx.x;
  int ray = blockIdx.x*64 + tid;   // 0..8191
  float w[31];
  float dprev = dc[ray*32+0];
  float sprev = dens[ray*32+0];
  float T = 1.f;
#pragma unroll
  for(int i=0;i<31;i++){
    float dn = dc[ray*32+i+1];
    float sn = dens[ray*32+i+1];
    if (i<30) szm[tid][i] = fm(0.5f, fa(dprev,dn));
    float delta = fs(dn,dprev);
    float dm = fm(0.5f, fa(sprev,sn));
    float al = fs(1.f, exf(-fm(dm,delta)));
    w[i] = fm(al,T);
    T = fm(T, fa(fs(1.f,al), 1e-10f));
    dprev=dn; sprev=sn;
  }
  // pdf weights: w_sm[j]=0.5*(m[j]+m[j+1])+0.01 (j=1..29), +EPS
  float pdfw[29];
#pragma unroll
  for(int i=0;i<29;i++){
    float m1 = fmaxf(w[i],w[i+1]), m2 = fmaxf(w[i+1],w[i+2]);
    pdfw[i] = fa(fa(fm(0.5f, fa(m1,m2)), 0.01f), 1e-5f);
  }
  // np.sum pairwise (n=29): 8 accumulators, 2 blocked adds, tree, 5 sequential tail
  float sum;
  {
    float r[8];
#pragma unroll
    for(int j=0;j<8;j++) r[j]=pdfw[j];
#pragma unroll
    for(int j=0;j<8;j++) r[j]=fa(r[j],pdfw[8+j]);
#pragma unroll
    for(int j=0;j<8;j++) r[j]=fa(r[j],pdfw[16+j]);
    sum = fa(fa(fa(r[0],r[1]),fa(r[2],r[3])), fa(fa(r[4],r[5]),fa(r[6],r[7])));
#pragma unroll
    for(int i=24;i<29;i++) sum = fa(sum, pdfw[i]);
  }
  // cdf: sequential cumsum of pdf (per-element f32 division)
  {
    float cacc = 0.f;
    scdf[tid][0] = 0.f;
#pragma unroll
    for(int i=1;i<30;i++){
      cacc = fa(cacc, fdv(pdfw[i-1], sum));
      scdf[tid][i] = cacc;
    }
  }

  float fmn=1e30f, fmx=-1e30f;
  for(int k=0;k<32;k++){
    float u = u_imp[ray*32+k];
    // np.searchsorted(cdf, u, 'right') = bisect_right (binary, regardless of monotonicity)
    int lo=0, hi=30;
    while(lo<hi){
      int mid=(lo+hi)>>1;
      if (scdf[tid][mid] <= u) lo = mid+1; else hi = mid;
    }
    int ind = lo;                 // in [1,30]
    int below = ind-1;            // in [0,29]
    int above = (ind>29)?29:ind;  // in [0,29]
    float cdf0 = scdf[tid][below];
    float cdf1 = scdf[tid][above];
    float b0   = szm [tid][below];
    float b1v  = szm [tid][above];
    float den = fs(cdf1,cdf0);
    if((double)den < 1e-5) den = 1.f;      // EPS compare in f64 (python const)
    float sres = fa(b0, fm(fdv(fs(u,cdf0),den), fs(b1v,b0)));
    df[ray*32+k]=sres;
    fmn=fminf(fmn,sres); fmx=fmaxf(fmx,sres);
  }
#pragma unroll
  for(int m=1;m<64;m<<=1){ fmn=fminf(fmn,__shfl_xor(fmn,m)); fmx=fmaxf(fmx,__shfl_xor(fmx,m)); }
  if(tid==0){
    atomicMin(((u32*)scal)+2, fenc(fmn));
    atomicMax(((u32*)scal)+3, fenc(fmx));
  }
}

// ---------------- stable sort (64) + final ray march, strict f32 (wave per ray) ----------------
__global__ void __launch_bounds__(256) k_final(
  const float* __restrict__ dc, const float* __restrict__ df,
  const float* __restrict__ densc, const float* __restrict__ densf,
  const u16* __restrict__ rgbc, const u16* __restrict__ rgbf,
  const float* __restrict__ scal,
  float* __restrict__ out_rgb, float* __restrict__ out_depth, float* __restrict__ out_w)
{
  __shared__ float ssd[4][64];
  __shared__ float ssn[4][64];
  __shared__ int   sp [4][64];
  __shared__ float swv[4][64];   // per-interval weight
  __shared__ float swz[4][64];   // per-interval weight*z_mid
  int wid = threadIdx.x>>6, lane = threadIdx.x&63;
  int ray = blockIdx.x*4 + wid;

  float myd = (lane<32)? dc[ray*32+lane]    : df[ray*32+lane-32];
  float myn = (lane<32)? densc[ray*32+lane] : densf[ray*32+lane-32];
  ssd[wid][lane]=myd; __syncthreads();
  int rk=0;
#pragma unroll 8
  for(int j=0;j<64;j++){
    float dj = ssd[wid][j];
    rk += (dj<myd || (dj==myd && j<lane)) ? 1:0;     // stable argsort rank
  }
  __syncthreads();
  ssd[wid][rk]=myd; ssn[wid][rk]=myn; sp[wid][rk]=lane;
  __syncthreads();

  float T=1.f, accr=0.f;
  int j0 = sp[wid][0];
  float cprev = 0.f;
  if (lane<32){
    const u16* cb = (j0<32)? (rgbc+((size_t)ray*32+j0)*32) : (rgbf+((size_t)ray*32+(j0-32))*32);
    cprev = __uint_as_float(((u32)cb[lane])<<16);
  }
  float d0 = ssd[wid][0], n0 = ssn[wid][0];
  for(int s2=0;s2<63;s2++){
    float d1 = ssd[wid][s2+1], n1 = ssn[wid][s2+1];
    float delta = fs(d1,d0);
    float dm = fm(0.5f, fa(n0,n1));
    float al = fs(1.f, exf(-fm(dm,delta)));
    float wv = fm(al,T);
    T = fm(T, fa(fs(1.f,al), 1e-10f));
    if (lane==s2){ swv[wid][s2]=wv; swz[wid][s2]=fm(wv, fm(0.5f, fa(d0,d1))); }
    int j1 = sp[wid][s2+1];
    float cnext = 0.f;
    if (lane<32){
      const u16* cb = (j1<32)? (rgbc+((size_t)ray*32+j1)*32) : (rgbf+((size_t)ray*32+(j1-32))*32);
      cnext = __uint_as_float(((u32)cb[lane])<<16);
    }
    // comp_rgb: strided axis-2 reduce -> SEQUENTIAL accumulation (numpy)
    accr = fa(accr, fm(wv, fm(0.5f, fa(cprev,cnext))));
    cprev=cnext; d0=d1; n0=n1;
  }
  __syncthreads();
  if(lane<63) out_w[(size_t)ray*63+lane]=swv[wid][lane];
  if(lane<32) out_rgb[(size_t)ray*32+lane]=fs(fm(accr,2.f),1.f);
  if(lane==0){
    // np.sum pairwise (n=63, contiguous): r[j]=sum_k a[8k+j] k=0..6; tree; tail 56..62
    float wsum, zsum;
    {
      float r[8], rz[8];
#pragma unroll
      for(int j=0;j<8;j++){ r[j]=swv[wid][j]; rz[j]=swz[wid][j]; }
      for(int i=8;i<56;i+=8)
#pragma unroll
        for(int j=0;j<8;j++){ r[j]=fa(r[j],swv[wid][i+j]); rz[j]=fa(rz[j],swz[wid][i+j]); }
      wsum = fa(fa(fa(r[0],r[1]),fa(r[2],r[3])), fa(fa(r[4],r[5]),fa(r[6],r[7])));
      zsum = fa(fa(fa(rz[0],rz[1]),fa(rz[2],rz[3])), fa(fa(rz[4],rz[5]),fa(rz[6],rz[7])));
      for(int i=56;i<63;i++){ wsum=fa(wsum,swv[wid][i]); zsum=fa(zsum,swz[wid][i]); }
    }
    float depv = fdv(zsum, wsum);
    if (isnan(depv)) depv = INFINITY;    // nan_to_num(nan=inf)
    float lo = fdec(((const u32*)scal)[2]);
    float hi = fdec(((const u32*)scal)[3]);
    depv = fminf(fmaxf(depv,lo),hi);     // clip to global all_d min/max
    out_depth[ray]=depv;
  }
}

extern "C" void kernel_launch(void* const* d_in, const int* in_sizes, int n_in,
                              void* d_out, int out_size, void* d_ws, size_t ws_size,
                              hipStream_t stream) {
  const float* planes = (const float*)d_in[0];
  const float* ro     = (const float*)d_in[1];
  const float* rdp    = (const float*)d_in[2];
  const float* hmin   = (const float*)d_in[3];
  const float* hmax   = (const float*)d_in[4];
  const float* jitter = (const float*)d_in[5];
  const float* uimp   = (const float*)d_in[6];
  const float* W1     = (const float*)d_in[7];
  const float* b1     = (const float*)d_in[8];
  const float* W2     = (const float*)d_in[9];
  const float* b2     = (const float*)d_in[10];
  const float* sb     = (const float*)d_in[11];
  const int*   hmk    = (const int*)d_in[12];
  float* out = (float*)d_out;
  char* ws = (char*)d_ws;

  size_t off=0;
  auto alloc=[&](size_t bytes){ size_t o=off; off=(off+bytes+255)&~(size_t)255; return o; };
  float* scal = (float*)(ws+alloc(64));
  float* W1t  = (float*)(ws+alloc(2048*4));
  float* pt   = (float*)(ws+alloc((size_t)12582912*4));
  float* dco  = (float*)(ws+alloc((size_t)NSAMP*4));
  float* dfi  = (float*)(ws+alloc((size_t)NSAMP*4));
  float* dnc  = (float*)(ws+alloc((size_t)NSAMP*4));
  float* dnf  = (float*)(ws+alloc((size_t)NSAMP*4));
  u16*   rgc  = (u16*)  (ws+alloc((size_t)NSAMP*32*2));
  u16*   rgf  = (u16*)  (ws+alloc((size_t)NSAMP*32*2));
  (void)in_sizes; (void)n_in; (void)out_size; (void)ws_size;

  float* out_rgb  = out;
  float* out_dep  = out + 262144;
  float* out_w    = out + 270336;
  float* out_psdf = out + 786432;

  k_init<<<dim3(1),dim3(256),0,stream>>>(hmin,hmax,W1,scal,W1t);
  k_tr<<<dim3(12288),dim3(256),0,stream>>>(planes, pt);
  k_eval<0><<<dim3(1024),dim3(256),0,stream>>>(pt,ro,rdp,hmin,hmax,jitter,hmk,W1t,b1,W2,b2,sb,scal,dco,dnc,rgc,out_psdf);
  k_imp<<<dim3(128),dim3(64),0,stream>>>(dco,dnc,uimp,dfi,scal);
  k_eval<1><<<dim3(1024),dim3(256),0,stream>>>(pt,ro,rdp,hmin,hmax,jitter,hmk,W1t,b1,W2,b2,sb,scal,dfi,dnf,rgf,out_psdf);
  k_final<<<dim3(2048),dim3(256),0,stream>>>(dco,dfi,dnc,dnf,rgc,rgf,scal,out_rgb,out_dep,out_w);
}